// Round 1
// baseline (4139.799 us; speedup 1.0000x reference)
//
#include <hip/hip_runtime.h>
#include <math.h>

#define B_   4
#define N_   4096
#define K_   16
#define DP_  128
#define DM_  256
#define NPTS (B_ * N_)

// ---------------- KNN: brute force, 1 thread per point, sorted top-16 ----------------
__global__ __launch_bounds__(256) void knn_kernel(const float* __restrict__ xyz,
                                                  int* __restrict__ knn_idx)
{
    const int b = blockIdx.y;
    const int n = blockIdx.x * 256 + threadIdx.x;
    const float* xb = xyz + (size_t)b * N_ * 3;
    const float xn0 = xb[n * 3 + 0], xn1 = xb[n * 3 + 1], xn2 = xb[n * 3 + 2];
    const float sqn = xn0 * xn0 + xn1 * xn1 + xn2 * xn2;

    float bd[16];
    int   bi[16];
#pragma unroll
    for (int i = 0; i < 16; ++i) { bd[i] = 3.0e38f; bi[i] = 0x7fffffff; }

    __shared__ float sx0[256], sx1[256], sx2[256], ssq[256];

    for (int m0 = 0; m0 < N_; m0 += 256) {
        __syncthreads();
        {
            const int t = threadIdx.x;
            const float a0 = xb[(m0 + t) * 3 + 0];
            const float a1 = xb[(m0 + t) * 3 + 1];
            const float a2 = xb[(m0 + t) * 3 + 2];
            sx0[t] = a0; sx1[t] = a1; sx2[t] = a2;
            ssq[t] = a0 * a0 + a1 * a1 + a2 * a2;
        }
        __syncthreads();
        for (int mm = 0; mm < 256; ++mm) {
            // same formula as reference: sq_n + sq_m - 2*dot
            const float dot = xn0 * sx0[mm] + xn1 * sx1[mm] + xn2 * sx2[mm];
            const float d = sqn + ssq[mm] - 2.0f * dot;
            const int gi = m0 + mm;
            if (d < bd[15] || (d == bd[15] && gi < bi[15])) {
                float cd = d; int ci = gi;
#pragma unroll
                for (int j = 0; j < 16; ++j) {   // static-index swap chain (stays in VGPRs)
                    const bool less = (cd < bd[j]) || (cd == bd[j] && ci < bi[j]);
                    const float td = bd[j]; const int ti = bi[j];
                    if (less) { bd[j] = cd; bi[j] = ci; cd = td; ci = ti; }
                }
            }
        }
    }
    int* o = knn_idx + (size_t)(b * N_ + n) * K_;
#pragma unroll
    for (int i = 0; i < 16; ++i) o[i] = b * N_ + bi[i];   // store as global point id
}

// ---------------- fp32 tiled GEMM: C[M,N] = A[M,K] @ W(K,N or N,K if transB) + bias + addC ----------------
__global__ __launch_bounds__(256) void gemm_kernel(const float* __restrict__ A,
                                                   const float* __restrict__ W,
                                                   const float* __restrict__ bias,
                                                   const float* __restrict__ addC,
                                                   float* __restrict__ C,
                                                   int M, int N, int K, int transB)
{
    __shared__ float As[16][65];
    __shared__ float Ws[16][65];
    const int m0 = blockIdx.y * 64, n0 = blockIdx.x * 64;
    const int tid = threadIdx.x;
    const int tx = tid & 15, ty = tid >> 4;
    float acc[4][4] = {};

    for (int k0 = 0; k0 < K; k0 += 16) {
#pragma unroll
        for (int i = 0; i < 4; ++i) {
            const int lin = tid + i * 256;
            const int kk = lin & 15, mm = lin >> 4;
            As[kk][mm] = A[(size_t)(m0 + mm) * K + k0 + kk];
        }
#pragma unroll
        for (int i = 0; i < 4; ++i) {
            const int lin = tid + i * 256;
            const int nn = lin & 63, kk = lin >> 6;
            Ws[kk][nn] = transB ? W[(size_t)(n0 + nn) * K + k0 + kk]
                                : W[(size_t)(k0 + kk) * N + n0 + nn];
        }
        __syncthreads();
#pragma unroll
        for (int kk = 0; kk < 16; ++kk) {
            float a[4], b[4];
#pragma unroll
            for (int i = 0; i < 4; ++i) a[i] = As[kk][ty + 16 * i];
#pragma unroll
            for (int j = 0; j < 4; ++j) b[j] = Ws[kk][tx + 16 * j];
#pragma unroll
            for (int i = 0; i < 4; ++i)
#pragma unroll
                for (int j = 0; j < 4; ++j) acc[i][j] = fmaf(a[i], b[j], acc[i][j]);
        }
        __syncthreads();
    }
#pragma unroll
    for (int i = 0; i < 4; ++i) {
        const int m = m0 + ty + 16 * i;
#pragma unroll
        for (int j = 0; j < 4; ++j) {
            const int n = n0 + tx + 16 * j;
            float v = acc[i][j];
            if (bias) v += bias[n];
            if (addC) v += addC[(size_t)m * N + n];
            C[(size_t)m * N + n] = v;
        }
    }
}

// ---------------- fused per-point attention (gathers + h + logits + softmax + rbar/hbar) ----------------
__global__ __launch_bounds__(256) void attn_kernel(
    const float* __restrict__ xyz, const float* __restrict__ qa,
    const float* __restrict__ ka,  const float* __restrict__ va,
    const float* __restrict__ qpa, const int* __restrict__ knn_idx,
    const float* __restrict__ fd1_w, const float* __restrict__ fd1_b,
    const float* __restrict__ fd2_b,
    float* __restrict__ rbar, float* __restrict__ hbar)
{
    const int n = blockIdx.x;          // global point id
    const int tid = threadIdx.x;
    __shared__ float sq[256], sqp[256];
    __shared__ float sh[16][256];
    __shared__ float slog[16];
    __shared__ int   sidx[16];
    __shared__ float sd0[16], sd1[16], sd2[16];
    __shared__ float sqb;

    sq[tid]  = qa[(size_t)n * DM_ + tid];
    sqp[tid] = qpa[(size_t)n * DM_ + tid];
    if (tid < 16) {
        const int gi = knn_idx[n * K_ + tid];
        sidx[tid] = gi;
        sd0[tid] = xyz[(size_t)n * 3 + 0] - xyz[(size_t)gi * 3 + 0];
        sd1[tid] = xyz[(size_t)n * 3 + 1] - xyz[(size_t)gi * 3 + 1];
        sd2[tid] = xyz[(size_t)n * 3 + 2] - xyz[(size_t)gi * 3 + 2];
    }
    __syncthreads();

    {   // h_k[c] = relu(delta_k . fd1_w[:,c] + fd1_b[c]), c = tid
        const float w0 = fd1_w[tid], w1 = fd1_w[DM_ + tid], w2 = fd1_w[2 * DM_ + tid];
        const float bb = fd1_b[tid];
#pragma unroll
        for (int k = 0; k < 16; ++k) {
            const float hv = sd0[k] * w0 + sd1[k] * w1 + sd2[k] * w2 + bb;
            sh[k][tid] = hv > 0.0f ? hv : 0.0f;
        }
    }
    __syncthreads();

    const int wave = tid >> 6, lane = tid & 63;
#pragma unroll
    for (int kk = 0; kk < 4; ++kk) {   // each wave handles 4 neighbors
        const int k = wave * 4 + kk;
        const int gi = sidx[k];
        float t = 0.0f;
#pragma unroll
        for (int j4 = 0; j4 < 4; ++j4) {
            const int j = lane + 64 * j4;
            t = fmaf(sq[j], ka[(size_t)gi * DM_ + j], t);   // q . kf_k
            t = fmaf(sh[k][j], sqp[j], t);                  // h_k . (fd2 @ q)
        }
#pragma unroll
        for (int off = 32; off > 0; off >>= 1) t += __shfl_down(t, off);
        if (lane == 0) slog[k] = t;
    }
    if (wave == 0) {   // qb = q . fd2_b (part of q.pos_k, constant over k)
        float t = 0.0f;
#pragma unroll
        for (int j4 = 0; j4 < 4; ++j4) {
            const int j = lane + 64 * j4;
            t = fmaf(sq[j], fd2_b[j], t);
        }
#pragma unroll
        for (int off = 32; off > 0; off >>= 1) t += __shfl_down(t, off);
        if (lane == 0) sqb = t;
    }
    __syncthreads();

    float att[16];
    {
        const float qb = sqb;
        float mx = -3.0e38f;
#pragma unroll
        for (int k = 0; k < 16; ++k) {
            const float l = (slog[k] + qb) * (1.0f / 16.0f);   // / sqrt(DM)
            att[k] = l; mx = fmaxf(mx, l);
        }
        float s = 0.0f;
#pragma unroll
        for (int k = 0; k < 16; ++k) { att[k] = __expf(att[k] - mx); s += att[k]; }
        const float inv = 1.0f / s;
#pragma unroll
        for (int k = 0; k < 16; ++k) att[k] *= inv;
    }

    float rb = 0.0f, hb = 0.0f;
#pragma unroll
    for (int k = 0; k < 16; ++k) {
        rb = fmaf(att[k], va[(size_t)sidx[k] * DM_ + tid], rb);   // sum attn*vf
        hb = fmaf(att[k], sh[k][tid], hb);                        // sum attn*h
    }
    rbar[(size_t)n * DM_ + tid] = rb;
    hbar[(size_t)n * DM_ + tid] = hb;
}

// ---------------- transpose [B*N,DP] -> [B,DP,N] ----------------
__global__ __launch_bounds__(256) void transpose_kernel(const float* __restrict__ in,
                                                        float* __restrict__ out)
{
    __shared__ float t[32][33];
    const int b = blockIdx.z;
    const int n0 = blockIdx.x * 32, d0 = blockIdx.y * 32;
    const int lx = threadIdx.x, ly = threadIdx.y;   // 32 x 8
#pragma unroll
    for (int i = 0; i < 32; i += 8)
        t[ly + i][lx] = in[(size_t)(b * N_ + n0 + ly + i) * DP_ + d0 + lx];
    __syncthreads();
#pragma unroll
    for (int i = 0; i < 32; i += 8)
        out[(size_t)(b * DP_ + d0 + ly + i) * N_ + n0 + lx] = t[lx][ly + i];
}

extern "C" void kernel_launch(void* const* d_in, const int* in_sizes, int n_in,
                              void* d_out, int out_size, void* d_ws, size_t ws_size,
                              hipStream_t stream)
{
    const float* features = (const float*)d_in[0];
    const float* xyz   = (const float*)d_in[1];
    const float* fc1_w = (const float*)d_in[2];
    const float* fc1_b = (const float*)d_in[3];
    const float* fc2_w = (const float*)d_in[4];
    const float* fc2_b = (const float*)d_in[5];
    const float* fd1_w = (const float*)d_in[6];
    const float* fd1_b = (const float*)d_in[7];
    const float* fd2_w = (const float*)d_in[8];
    const float* fd2_b = (const float*)d_in[9];
    const float* wq    = (const float*)d_in[10];
    const float* wk    = (const float*)d_in[11];
    const float* wv    = (const float*)d_in[12];
    float* out = (float*)d_out;

    const size_t MAT = (size_t)NPTS * DM_;   // 4,194,304 floats
    float* ws   = (float*)d_ws;
    float* x    = ws + 0 * MAT;              // fc1 output; buffer reused for hbar
    float* q    = ws + 1 * MAT;
    float* kbuf = ws + 2 * MAT;              // keys; buffer reused for outc
    float* v    = ws + 3 * MAT;
    float* qp   = ws + 4 * MAT;              // QP = Q @ fd2^T; buffer reused for res
    float* rbar = ws + 5 * MAT;
    int*   idx  = (int*)(ws + 6 * MAT);
    float* hbar = x;                         // x dead after v-GEMM
    float* res  = qp;                        // qp dead after attn
    float* outc = kbuf;                      // kbuf dead after attn

    const dim3 blk(256);
    knn_kernel<<<dim3(N_ / 256, B_), blk, 0, stream>>>(xyz, idx);
    // x = features @ fc1_w + fc1_b
    gemm_kernel<<<dim3(DM_ / 64, NPTS / 64), blk, 0, stream>>>(features, fc1_w, fc1_b, nullptr, x, NPTS, DM_, DP_, 0);
    // q/k/v
    gemm_kernel<<<dim3(DM_ / 64, NPTS / 64), blk, 0, stream>>>(x, wq, nullptr, nullptr, q,    NPTS, DM_, DM_, 0);
    gemm_kernel<<<dim3(DM_ / 64, NPTS / 64), blk, 0, stream>>>(x, wk, nullptr, nullptr, kbuf, NPTS, DM_, DM_, 0);
    gemm_kernel<<<dim3(DM_ / 64, NPTS / 64), blk, 0, stream>>>(x, wv, nullptr, nullptr, v,    NPTS, DM_, DM_, 0);
    // QP = Q @ fd2_w^T   (so q.pos_k = h_k . qp + q.fd2_b)
    gemm_kernel<<<dim3(DM_ / 64, NPTS / 64), blk, 0, stream>>>(q, fd2_w, nullptr, nullptr, qp, NPTS, DM_, DM_, 1);
    // fused attention -> rbar (= sum attn*vf), hbar (= sum attn*h)
    attn_kernel<<<dim3(NPTS), blk, 0, stream>>>(xyz, q, kbuf, v, qp, idx, fd1_w, fd1_b, fd2_b, rbar, hbar);
    // res = hbar @ fd2_w + fd2_b + rbar
    gemm_kernel<<<dim3(DM_ / 64, NPTS / 64), blk, 0, stream>>>(hbar, fd2_w, fd2_b, rbar, res, NPTS, DM_, DM_, 0);
    // outc = res @ fc2_w + fc2_b + features
    gemm_kernel<<<dim3(DP_ / 64, NPTS / 64), blk, 0, stream>>>(res, fc2_w, fc2_b, features, outc, NPTS, DP_, DM_, 0);
    // transpose to [B, DP, N]
    transpose_kernel<<<dim3(N_ / 32, DP_ / 32, B_), dim3(32, 8), 0, stream>>>(outc, out);

    (void)in_sizes; (void)n_in; (void)out_size; (void)ws_size;
}

// Round 2
// 1317.211 us; speedup vs baseline: 3.1429x; 3.1429x over previous
//
#include <hip/hip_runtime.h>
#include <math.h>

#define B_   4
#define N_   4096
#define K_   16
#define DP_  128
#define DM_  256
#define NPTS (B_ * N_)
#define SEG_ 16
#define CAND_ (N_ / SEG_)   // 256 candidates per segment

// ---------------- KNN phase 1: per (point, segment) sorted top-16 ----------------
// Partials stored transposed: part_d[(s*16+j)*NPTS + p] for coalesced write+read.
__global__ __launch_bounds__(256) void knn_part_kernel(const float* __restrict__ xyz,
                                                       float* __restrict__ part_d,
                                                       int* __restrict__ part_i)
{
    const int b = blockIdx.z;
    const int s = blockIdx.y;
    const int n = blockIdx.x * 256 + threadIdx.x;
    const float* xb = xyz + (size_t)b * N_ * 3;
    const float xn0 = xb[n * 3 + 0], xn1 = xb[n * 3 + 1], xn2 = xb[n * 3 + 2];
    const float sqn = xn0 * xn0 + xn1 * xn1 + xn2 * xn2;

    __shared__ float sx0[CAND_], sx1[CAND_], sx2[CAND_], ssq[CAND_];
    {
        const int t = threadIdx.x;           // CAND_ == 256 == blockDim.x
        const int m = s * CAND_ + t;
        const float a0 = xb[m * 3 + 0];
        const float a1 = xb[m * 3 + 1];
        const float a2 = xb[m * 3 + 2];
        sx0[t] = a0; sx1[t] = a1; sx2[t] = a2;
        ssq[t] = a0 * a0 + a1 * a1 + a2 * a2;
    }
    __syncthreads();

    float bd[16];
    int   bi[16];
#pragma unroll
    for (int i = 0; i < 16; ++i) { bd[i] = 3.0e38f; bi[i] = 0x7fffffff; }

    for (int mm = 0; mm < CAND_; ++mm) {
        // same formula as reference: sq_n + sq_m - 2*dot
        const float dot = xn0 * sx0[mm] + xn1 * sx1[mm] + xn2 * sx2[mm];
        const float d = sqn + ssq[mm] - 2.0f * dot;
        const int gi = s * CAND_ + mm;       // within-batch index
        if (d < bd[15] || (d == bd[15] && gi < bi[15])) {
            float cd = d; int ci = gi;
#pragma unroll
            for (int j = 0; j < 16; ++j) {   // static-index swap chain (stays in VGPRs)
                const bool less = (cd < bd[j]) || (cd == bd[j] && ci < bi[j]);
                const float td = bd[j]; const int ti = bi[j];
                if (less) { bd[j] = cd; bi[j] = ci; cd = td; ci = ti; }
            }
        }
    }

    const int p = b * N_ + n;                // global point id
#pragma unroll
    for (int j = 0; j < 16; ++j) {
        part_d[(size_t)(s * 16 + j) * NPTS + p] = bd[j];
        part_i[(size_t)(s * 16 + j) * NPTS + p] = bi[j];
    }
}

// ---------------- KNN phase 2: merge 16 sorted 16-lists -> final top-16 ----------------
__global__ __launch_bounds__(256) void knn_merge_kernel(const float* __restrict__ part_d,
                                                        const int* __restrict__ part_i,
                                                        int* __restrict__ knn_idx)
{
    const int p = blockIdx.x * 256 + threadIdx.x;   // global point id
    const int b = p >> 12;                           // p / N_

    float bd[16];
    int   bi[16];
#pragma unroll
    for (int i = 0; i < 16; ++i) { bd[i] = 3.0e38f; bi[i] = 0x7fffffff; }

    for (int s = 0; s < SEG_; ++s) {
        for (int j = 0; j < 16; ++j) {
            const float d = part_d[(size_t)(s * 16 + j) * NPTS + p];
            const int  gi = part_i[(size_t)(s * 16 + j) * NPTS + p];
            if (d < bd[15] || (d == bd[15] && gi < bi[15])) {
                float cd = d; int ci = gi;
#pragma unroll
                for (int q = 0; q < 16; ++q) {
                    const bool less = (cd < bd[q]) || (cd == bd[q] && ci < bi[q]);
                    const float td = bd[q]; const int ti = bi[q];
                    if (less) { bd[q] = cd; bi[q] = ci; cd = td; ci = ti; }
                }
            } else {
                break;   // segment list is sorted: rest of this segment can't qualify
            }
        }
    }

    int* o = knn_idx + (size_t)p * K_;
#pragma unroll
    for (int i = 0; i < 16; ++i) o[i] = b * N_ + bi[i];   // store as global point id
}

// ---------------- fp32 tiled GEMM: C[M,N] = A[M,K] @ W(K,N or N,K if transB) + bias + addC ----------------
__global__ __launch_bounds__(256) void gemm_kernel(const float* __restrict__ A,
                                                   const float* __restrict__ W,
                                                   const float* __restrict__ bias,
                                                   const float* __restrict__ addC,
                                                   float* __restrict__ C,
                                                   int M, int N, int K, int transB)
{
    __shared__ float As[16][65];
    __shared__ float Ws[16][65];
    const int m0 = blockIdx.y * 64, n0 = blockIdx.x * 64;
    const int tid = threadIdx.x;
    const int tx = tid & 15, ty = tid >> 4;
    float acc[4][4] = {};

    for (int k0 = 0; k0 < K; k0 += 16) {
#pragma unroll
        for (int i = 0; i < 4; ++i) {
            const int lin = tid + i * 256;
            const int kk = lin & 15, mm = lin >> 4;
            As[kk][mm] = A[(size_t)(m0 + mm) * K + k0 + kk];
        }
#pragma unroll
        for (int i = 0; i < 4; ++i) {
            const int lin = tid + i * 256;
            const int nn = lin & 63, kk = lin >> 6;
            Ws[kk][nn] = transB ? W[(size_t)(n0 + nn) * K + k0 + kk]
                                : W[(size_t)(k0 + kk) * N + n0 + nn];
        }
        __syncthreads();
#pragma unroll
        for (int kk = 0; kk < 16; ++kk) {
            float a[4], b[4];
#pragma unroll
            for (int i = 0; i < 4; ++i) a[i] = As[kk][ty + 16 * i];
#pragma unroll
            for (int j = 0; j < 4; ++j) b[j] = Ws[kk][tx + 16 * j];
#pragma unroll
            for (int i = 0; i < 4; ++i)
#pragma unroll
                for (int j = 0; j < 4; ++j) acc[i][j] = fmaf(a[i], b[j], acc[i][j]);
        }
        __syncthreads();
    }
#pragma unroll
    for (int i = 0; i < 4; ++i) {
        const int m = m0 + ty + 16 * i;
#pragma unroll
        for (int j = 0; j < 4; ++j) {
            const int n = n0 + tx + 16 * j;
            float v = acc[i][j];
            if (bias) v += bias[n];
            if (addC) v += addC[(size_t)m * N + n];
            C[(size_t)m * N + n] = v;
        }
    }
}

// ---------------- fused per-point attention (gathers + h + logits + softmax + rbar/hbar) ----------------
__global__ __launch_bounds__(256) void attn_kernel(
    const float* __restrict__ xyz, const float* __restrict__ qa,
    const float* __restrict__ ka,  const float* __restrict__ va,
    const float* __restrict__ qpa, const int* __restrict__ knn_idx,
    const float* __restrict__ fd1_w, const float* __restrict__ fd1_b,
    const float* __restrict__ fd2_b,
    float* __restrict__ rbar, float* __restrict__ hbar)
{
    const int n = blockIdx.x;          // global point id
    const int tid = threadIdx.x;
    __shared__ float sq[256], sqp[256];
    __shared__ float sh[16][256];
    __shared__ float slog[16];
    __shared__ int   sidx[16];
    __shared__ float sd0[16], sd1[16], sd2[16];
    __shared__ float sqb;

    sq[tid]  = qa[(size_t)n * DM_ + tid];
    sqp[tid] = qpa[(size_t)n * DM_ + tid];
    if (tid < 16) {
        const int gi = knn_idx[n * K_ + tid];
        sidx[tid] = gi;
        sd0[tid] = xyz[(size_t)n * 3 + 0] - xyz[(size_t)gi * 3 + 0];
        sd1[tid] = xyz[(size_t)n * 3 + 1] - xyz[(size_t)gi * 3 + 1];
        sd2[tid] = xyz[(size_t)n * 3 + 2] - xyz[(size_t)gi * 3 + 2];
    }
    __syncthreads();

    {   // h_k[c] = relu(delta_k . fd1_w[:,c] + fd1_b[c]), c = tid
        const float w0 = fd1_w[tid], w1 = fd1_w[DM_ + tid], w2 = fd1_w[2 * DM_ + tid];
        const float bb = fd1_b[tid];
#pragma unroll
        for (int k = 0; k < 16; ++k) {
            const float hv = sd0[k] * w0 + sd1[k] * w1 + sd2[k] * w2 + bb;
            sh[k][tid] = hv > 0.0f ? hv : 0.0f;
        }
    }
    __syncthreads();

    const int wave = tid >> 6, lane = tid & 63;
#pragma unroll
    for (int kk = 0; kk < 4; ++kk) {   // each wave handles 4 neighbors
        const int k = wave * 4 + kk;
        const int gi = sidx[k];
        float t = 0.0f;
#pragma unroll
        for (int j4 = 0; j4 < 4; ++j4) {
            const int j = lane + 64 * j4;
            t = fmaf(sq[j], ka[(size_t)gi * DM_ + j], t);   // q . kf_k
            t = fmaf(sh[k][j], sqp[j], t);                  // h_k . (fd2 @ q)
        }
#pragma unroll
        for (int off = 32; off > 0; off >>= 1) t += __shfl_down(t, off);
        if (lane == 0) slog[k] = t;
    }
    if (wave == 0) {   // qb = q . fd2_b (part of q.pos_k, constant over k)
        float t = 0.0f;
#pragma unroll
        for (int j4 = 0; j4 < 4; ++j4) {
            const int j = lane + 64 * j4;
            t = fmaf(sq[j], fd2_b[j], t);
        }
#pragma unroll
        for (int off = 32; off > 0; off >>= 1) t += __shfl_down(t, off);
        if (lane == 0) sqb = t;
    }
    __syncthreads();

    float att[16];
    {
        const float qb = sqb;
        float mx = -3.0e38f;
#pragma unroll
        for (int k = 0; k < 16; ++k) {
            const float l = (slog[k] + qb) * (1.0f / 16.0f);   // / sqrt(DM)
            att[k] = l; mx = fmaxf(mx, l);
        }
        float s = 0.0f;
#pragma unroll
        for (int k = 0; k < 16; ++k) { att[k] = __expf(att[k] - mx); s += att[k]; }
        const float inv = 1.0f / s;
#pragma unroll
        for (int k = 0; k < 16; ++k) att[k] *= inv;
    }

    float rb = 0.0f, hb = 0.0f;
#pragma unroll
    for (int k = 0; k < 16; ++k) {
        rb = fmaf(att[k], va[(size_t)sidx[k] * DM_ + tid], rb);   // sum attn*vf
        hb = fmaf(att[k], sh[k][tid], hb);                        // sum attn*h
    }
    rbar[(size_t)n * DM_ + tid] = rb;
    hbar[(size_t)n * DM_ + tid] = hb;
}

// ---------------- transpose [B*N,DP] -> [B,DP,N] ----------------
__global__ __launch_bounds__(256) void transpose_kernel(const float* __restrict__ in,
                                                        float* __restrict__ out)
{
    __shared__ float t[32][33];
    const int b = blockIdx.z;
    const int n0 = blockIdx.x * 32, d0 = blockIdx.y * 32;
    const int lx = threadIdx.x, ly = threadIdx.y;   // 32 x 8
#pragma unroll
    for (int i = 0; i < 32; i += 8)
        t[ly + i][lx] = in[(size_t)(b * N_ + n0 + ly + i) * DP_ + d0 + lx];
    __syncthreads();
#pragma unroll
    for (int i = 0; i < 32; i += 8)
        out[(size_t)(b * DP_ + d0 + ly + i) * N_ + n0 + lx] = t[lx][ly + i];
}

extern "C" void kernel_launch(void* const* d_in, const int* in_sizes, int n_in,
                              void* d_out, int out_size, void* d_ws, size_t ws_size,
                              hipStream_t stream)
{
    const float* features = (const float*)d_in[0];
    const float* xyz   = (const float*)d_in[1];
    const float* fc1_w = (const float*)d_in[2];
    const float* fc1_b = (const float*)d_in[3];
    const float* fc2_w = (const float*)d_in[4];
    const float* fc2_b = (const float*)d_in[5];
    const float* fd1_w = (const float*)d_in[6];
    const float* fd1_b = (const float*)d_in[7];
    const float* fd2_w = (const float*)d_in[8];
    const float* fd2_b = (const float*)d_in[9];
    const float* wq    = (const float*)d_in[10];
    const float* wk    = (const float*)d_in[11];
    const float* wv    = (const float*)d_in[12];
    float* out = (float*)d_out;

    const size_t MAT = (size_t)NPTS * DM_;   // 4,194,304 floats
    float* ws   = (float*)d_ws;
    float* x    = ws + 0 * MAT;              // fc1 output; overlaid by part_d before fc1
    float* q    = ws + 1 * MAT;              // overlaid by part_i before q-GEMM
    float* kbuf = ws + 2 * MAT;              // keys; buffer reused for outc
    float* v    = ws + 3 * MAT;
    float* qp   = ws + 4 * MAT;              // QP = Q @ fd2^T; buffer reused for res
    float* rbar = ws + 5 * MAT;
    int*   idx  = (int*)(ws + 6 * MAT);
    float* part_d = x;                       // SEG_*16*NPTS = MAT floats, dead after merge
    int*   part_i = (int*)q;                 // MAT ints, dead after merge
    float* hbar = x;                         // x dead after v-GEMM
    float* res  = qp;                        // qp dead after attn
    float* outc = kbuf;                      // kbuf dead after attn

    const dim3 blk(256);
    // KNN: segmented partial top-16 (1024 blocks) + per-point merge
    knn_part_kernel<<<dim3(N_ / 256, SEG_, B_), blk, 0, stream>>>(xyz, part_d, part_i);
    knn_merge_kernel<<<dim3(NPTS / 256), blk, 0, stream>>>(part_d, part_i, idx);
    // x = features @ fc1_w + fc1_b
    gemm_kernel<<<dim3(DM_ / 64, NPTS / 64), blk, 0, stream>>>(features, fc1_w, fc1_b, nullptr, x, NPTS, DM_, DP_, 0);
    // q/k/v
    gemm_kernel<<<dim3(DM_ / 64, NPTS / 64), blk, 0, stream>>>(x, wq, nullptr, nullptr, q,    NPTS, DM_, DM_, 0);
    gemm_kernel<<<dim3(DM_ / 64, NPTS / 64), blk, 0, stream>>>(x, wk, nullptr, nullptr, kbuf, NPTS, DM_, DM_, 0);
    gemm_kernel<<<dim3(DM_ / 64, NPTS / 64), blk, 0, stream>>>(x, wv, nullptr, nullptr, v,    NPTS, DM_, DM_, 0);
    // QP = Q @ fd2_w^T   (so q.pos_k = h_k . qp + q.fd2_b)
    gemm_kernel<<<dim3(DM_ / 64, NPTS / 64), blk, 0, stream>>>(q, fd2_w, nullptr, nullptr, qp, NPTS, DM_, DM_, 1);
    // fused attention -> rbar (= sum attn*vf), hbar (= sum attn*h)
    attn_kernel<<<dim3(NPTS), blk, 0, stream>>>(xyz, q, kbuf, v, qp, idx, fd1_w, fd1_b, fd2_b, rbar, hbar);
    // res = hbar @ fd2_w + fd2_b + rbar
    gemm_kernel<<<dim3(DM_ / 64, NPTS / 64), blk, 0, stream>>>(hbar, fd2_w, fd2_b, rbar, res, NPTS, DM_, DM_, 0);
    // outc = res @ fc2_w + fc2_b + features
    gemm_kernel<<<dim3(DP_ / 64, NPTS / 64), blk, 0, stream>>>(res, fc2_w, fc2_b, features, outc, NPTS, DP_, DM_, 0);
    // transpose to [B, DP, N]
    transpose_kernel<<<dim3(N_ / 32, DP_ / 32, B_), dim3(32, 8), 0, stream>>>(outc, out);

    (void)in_sizes; (void)n_in; (void)out_size; (void)ws_size;
}

// Round 3
// 656.005 us; speedup vs baseline: 6.3106x; 2.0079x over previous
//
#include <hip/hip_runtime.h>
#include <hip/hip_bf16.h>
#include <math.h>

#define B_   4
#define N_   4096
#define K_   16
#define DP_  128
#define DM_  256
#define NPTS (B_ * N_)
#define SEG_ 16
#define CAND_ (N_ / SEG_)   // 256 candidates per segment

typedef unsigned long long u64;
typedef __attribute__((ext_vector_type(8))) short short8;
typedef __attribute__((ext_vector_type(4))) float floatx4;

// ---------------- KNN phase 1: per (point, segment) sorted top-16 ----------------
// (d, idx) packed into one u64: monotonic float-ordered key in high 32, idx low 32.
// __launch_bounds__(256,2): cap VGPR at 256 so the 16xu64 list stays in arch VGPRs
// (round-2 allocated only 32 VGPRs -> array demotion -> ~6x VALU inst bloat).
__global__ __launch_bounds__(256, 2) void knn_part_kernel(const float* __restrict__ xyz,
                                                          u64* __restrict__ part)
{
    const int b = blockIdx.z;
    const int s = blockIdx.y;
    const int n = blockIdx.x * 256 + threadIdx.x;
    const float* xb = xyz + (size_t)b * N_ * 3;
    const float xn0 = xb[n * 3 + 0], xn1 = xb[n * 3 + 1], xn2 = xb[n * 3 + 2];
    const float sqn = xn0 * xn0 + xn1 * xn1 + xn2 * xn2;

    __shared__ float sx0[CAND_], sx1[CAND_], sx2[CAND_], ssq[CAND_];
    {
        const int t = threadIdx.x;           // CAND_ == 256 == blockDim.x
        const int m = s * CAND_ + t;
        const float a0 = xb[m * 3 + 0];
        const float a1 = xb[m * 3 + 1];
        const float a2 = xb[m * 3 + 2];
        sx0[t] = a0; sx1[t] = a1; sx2[t] = a2;
        ssq[t] = a0 * a0 + a1 * a1 + a2 * a2;
    }
    __syncthreads();

    u64 bl[16];
#pragma unroll
    for (int i = 0; i < 16; ++i) bl[i] = ~0ull;

    for (int mm = 0; mm < CAND_; ++mm) {
        // same formula as reference: sq_n + sq_m - 2*dot
        const float dot = xn0 * sx0[mm] + xn1 * sx1[mm] + xn2 * sx2[mm];
        const float d = sqn + ssq[mm] - 2.0f * dot;
        const int ib = __float_as_int(d);
        const unsigned key = (unsigned)ib ^ (unsigned)((ib >> 31) | 0x80000000);
        u64 cand = ((u64)key << 32) | (unsigned)(s * CAND_ + mm);
        if (cand < bl[15]) {
#pragma unroll
            for (int j = 0; j < 16; ++j) {   // branchless compare-exchange chain
                const bool lt = cand < bl[j];
                const u64 t = bl[j];
                bl[j] = lt ? cand : bl[j];
                cand  = lt ? t    : cand;
            }
        }
    }

    const int p = b * N_ + n;                // global point id
#pragma unroll
    for (int j = 0; j < 16; ++j)
        part[(size_t)(s * 16 + j) * NPTS + p] = bl[j];
}

// ---------------- KNN phase 2: merge 16 sorted 16-lists -> final top-16 ----------------
__global__ __launch_bounds__(256, 2) void knn_merge_kernel(const u64* __restrict__ part,
                                                           int* __restrict__ knn_idx)
{
    const int p = blockIdx.x * 256 + threadIdx.x;   // global point id
    const int b = p >> 12;                           // p / N_

    u64 bl[16];
#pragma unroll
    for (int i = 0; i < 16; ++i) bl[i] = ~0ull;

    for (int s = 0; s < SEG_; ++s) {
        for (int j = 0; j < 16; ++j) {
            u64 cand = part[(size_t)(s * 16 + j) * NPTS + p];
            if (cand < bl[15]) {
#pragma unroll
                for (int q = 0; q < 16; ++q) {
                    const bool lt = cand < bl[q];
                    const u64 t = bl[q];
                    bl[q] = lt ? cand : bl[q];
                    cand  = lt ? t    : cand;
                }
            } else {
                break;   // segment list is sorted: rest of this segment can't qualify
            }
        }
    }

    int* o = knn_idx + (size_t)p * K_;
#pragma unroll
    for (int i = 0; i < 16; ++i) o[i] = b * N_ + (int)(bl[i] & 0xffffffffu);
}

// ---------------- bf16 MFMA GEMM: C[M,N] = A[M,K] @ Bt[N,K]^T (+bias +addC) ----------------
// 128x128 tile, BK=32, 4 waves (2x2), each wave 4x4 frags of mfma_f32_16x16x32_bf16.
// A-frag: lane m=l&15, k=(l>>4)*8+j contiguous; B-frag symmetric; C/D: col=l&15, row=(l>>4)*4+r.
__global__ __launch_bounds__(256) void gemm_bf16_kernel(
    const __hip_bfloat16* __restrict__ A,   // [M][K] bf16
    const __hip_bfloat16* __restrict__ Bt,  // [N][K] bf16
    const float* __restrict__ bias,         // [N] or null
    const float* __restrict__ addC,         // [M][N] fp32 or null
    float* __restrict__ Cf,                 // [M][N] fp32 or null
    __hip_bfloat16* __restrict__ Cb,        // [M][N] bf16 or null
    int M, int N, int K)
{
    __shared__ __align__(16) __hip_bfloat16 As[128 * 32];
    __shared__ __align__(16) __hip_bfloat16 Bs[128 * 32];
    const int tid = threadIdx.x;
    const int m0 = blockIdx.y * 128, n0 = blockIdx.x * 128;
    const int w = tid >> 6, l = tid & 63;
    const int wm = (w >> 1) * 64, wn = (w & 1) * 64;
    const int fm = l & 15, kq = l >> 4;

    floatx4 acc[4][4];
#pragma unroll
    for (int i = 0; i < 4; ++i)
#pragma unroll
        for (int j = 0; j < 4; ++j)
            acc[i][j] = (floatx4){0.0f, 0.0f, 0.0f, 0.0f};

    for (int k0 = 0; k0 < K; k0 += 32) {
        __syncthreads();
#pragma unroll
        for (int c = 0; c < 2; ++c) {        // stage A,B tiles: 2x16B each per thread
            const int li = tid + c * 256;
            const int row = li >> 2, part = li & 3;
            *(uint4*)&As[row * 32 + part * 8] =
                *(const uint4*)&A[(size_t)(m0 + row) * K + k0 + part * 8];
            *(uint4*)&Bs[row * 32 + part * 8] =
                *(const uint4*)&Bt[(size_t)(n0 + row) * K + k0 + part * 8];
        }
        __syncthreads();
        short8 af[4], bf[4];
#pragma unroll
        for (int i = 0; i < 4; ++i)
            af[i] = *(const short8*)&As[(wm + i * 16 + fm) * 32 + kq * 8];
#pragma unroll
        for (int j = 0; j < 4; ++j)
            bf[j] = *(const short8*)&Bs[(wn + j * 16 + fm) * 32 + kq * 8];
#pragma unroll
        for (int i = 0; i < 4; ++i)
#pragma unroll
            for (int j = 0; j < 4; ++j)
                acc[i][j] = __builtin_amdgcn_mfma_f32_16x16x32_bf16(af[i], bf[j], acc[i][j], 0, 0, 0);
    }

#pragma unroll
    for (int i = 0; i < 4; ++i) {
#pragma unroll
        for (int j = 0; j < 4; ++j) {
            const int col = n0 + wn + j * 16 + fm;
            const int rowb = m0 + wm + i * 16 + kq * 4;
#pragma unroll
            for (int r = 0; r < 4; ++r) {
                const int m = rowb + r;
                float v = acc[i][j][r];
                if (bias) v += bias[col];
                if (addC) v += addC[(size_t)m * N + col];
                if (Cf) Cf[(size_t)m * N + col] = v;
                if (Cb) Cb[(size_t)m * N + col] = __float2bfloat16(v);
            }
        }
    }
}

// ---------------- weight transpose-cast: out[C][R] bf16 = in[R][C] fp32 ----------------
__global__ void castT_kernel(const float* __restrict__ in, __hip_bfloat16* __restrict__ out,
                             int R, int C)
{
    __shared__ float t[32][33];
    const int r0 = blockIdx.y * 32, c0 = blockIdx.x * 32;
    const int lx = threadIdx.x, ly = threadIdx.y;   // 32 x 8
#pragma unroll
    for (int i = 0; i < 32; i += 8)
        t[ly + i][lx] = in[(size_t)(r0 + ly + i) * C + c0 + lx];
    __syncthreads();
#pragma unroll
    for (int i = 0; i < 32; i += 8)
        out[(size_t)(c0 + ly + i) * R + r0 + lx] = __float2bfloat16(t[lx][ly + i]);
}

// ---------------- straight cast fp32 -> bf16 ----------------
__global__ void cast_bf16_kernel(const float* __restrict__ in, __hip_bfloat16* __restrict__ out,
                                 int n)
{
    const int i = blockIdx.x * 256 + threadIdx.x;
    if (i < n) out[i] = __float2bfloat16(in[i]);
}

// ---------------- fused per-point attention (bf16 gathers, fp32 math) ----------------
__global__ __launch_bounds__(256) void attn_kernel(
    const float* __restrict__ xyz,
    const __hip_bfloat16* __restrict__ qa,  const __hip_bfloat16* __restrict__ ka,
    const __hip_bfloat16* __restrict__ va,  const __hip_bfloat16* __restrict__ qpa,
    const int* __restrict__ knn_idx,
    const float* __restrict__ fd1_w, const float* __restrict__ fd1_b,
    const float* __restrict__ fd2_b,
    float* __restrict__ rbar, __hip_bfloat16* __restrict__ hbarb)
{
    const int n = blockIdx.x;          // global point id
    const int tid = threadIdx.x;
    __shared__ float sq[256], sqp[256];
    __shared__ float sh[16][256];
    __shared__ float slog[16];
    __shared__ int   sidx[16];
    __shared__ float sd0[16], sd1[16], sd2[16];
    __shared__ float sqb;

    sq[tid]  = __bfloat162float(qa[(size_t)n * DM_ + tid]);
    sqp[tid] = __bfloat162float(qpa[(size_t)n * DM_ + tid]);
    if (tid < 16) {
        const int gi = knn_idx[n * K_ + tid];
        sidx[tid] = gi;
        sd0[tid] = xyz[(size_t)n * 3 + 0] - xyz[(size_t)gi * 3 + 0];
        sd1[tid] = xyz[(size_t)n * 3 + 1] - xyz[(size_t)gi * 3 + 1];
        sd2[tid] = xyz[(size_t)n * 3 + 2] - xyz[(size_t)gi * 3 + 2];
    }
    __syncthreads();

    {   // h_k[c] = relu(delta_k . fd1_w[:,c] + fd1_b[c]), c = tid
        const float w0 = fd1_w[tid], w1 = fd1_w[DM_ + tid], w2 = fd1_w[2 * DM_ + tid];
        const float bb = fd1_b[tid];
#pragma unroll
        for (int k = 0; k < 16; ++k) {
            const float hv = sd0[k] * w0 + sd1[k] * w1 + sd2[k] * w2 + bb;
            sh[k][tid] = hv > 0.0f ? hv : 0.0f;
        }
    }
    __syncthreads();

    const int wave = tid >> 6, lane = tid & 63;
#pragma unroll
    for (int kk = 0; kk < 4; ++kk) {   // each wave handles 4 neighbors
        const int k = wave * 4 + kk;
        const int gi = sidx[k];
        float t = 0.0f;
#pragma unroll
        for (int j4 = 0; j4 < 4; ++j4) {
            const int j = lane + 64 * j4;
            t = fmaf(sq[j], __bfloat162float(ka[(size_t)gi * DM_ + j]), t);  // q . kf_k
            t = fmaf(sh[k][j], sqp[j], t);                                    // h_k . (fd2 @ q)
        }
#pragma unroll
        for (int off = 32; off > 0; off >>= 1) t += __shfl_down(t, off);
        if (lane == 0) slog[k] = t;
    }
    if (wave == 0) {   // qb = q . fd2_b (part of q.pos_k, constant over k)
        float t = 0.0f;
#pragma unroll
        for (int j4 = 0; j4 < 4; ++j4) {
            const int j = lane + 64 * j4;
            t = fmaf(sq[j], fd2_b[j], t);
        }
#pragma unroll
        for (int off = 32; off > 0; off >>= 1) t += __shfl_down(t, off);
        if (lane == 0) sqb = t;
    }
    __syncthreads();

    float att[16];
    {
        const float qb = sqb;
        float mx = -3.0e38f;
#pragma unroll
        for (int k = 0; k < 16; ++k) {
            const float lg = (slog[k] + qb) * (1.0f / 16.0f);   // / sqrt(DM)
            att[k] = lg; mx = fmaxf(mx, lg);
        }
        float s = 0.0f;
#pragma unroll
        for (int k = 0; k < 16; ++k) { att[k] = __expf(att[k] - mx); s += att[k]; }
        const float inv = 1.0f / s;
#pragma unroll
        for (int k = 0; k < 16; ++k) att[k] *= inv;
    }

    float rb = 0.0f, hb = 0.0f;
#pragma unroll
    for (int k = 0; k < 16; ++k) {
        rb = fmaf(att[k], __bfloat162float(va[(size_t)sidx[k] * DM_ + tid]), rb);
        hb = fmaf(att[k], sh[k][tid], hb);
    }
    rbar[(size_t)n * DM_ + tid] = rb;
    hbarb[(size_t)n * DM_ + tid] = __float2bfloat16(hb);
}

// ---------------- transpose [B*N,DP] -> [B,DP,N] ----------------
__global__ __launch_bounds__(256) void transpose_kernel(const float* __restrict__ in,
                                                        float* __restrict__ out)
{
    __shared__ float t[32][33];
    const int b = blockIdx.z;
    const int n0 = blockIdx.x * 32, d0 = blockIdx.y * 32;
    const int lx = threadIdx.x, ly = threadIdx.y;   // 32 x 8
#pragma unroll
    for (int i = 0; i < 32; i += 8)
        t[ly + i][lx] = in[(size_t)(b * N_ + n0 + ly + i) * DP_ + d0 + lx];
    __syncthreads();
#pragma unroll
    for (int i = 0; i < 32; i += 8)
        out[(size_t)(b * DP_ + d0 + ly + i) * N_ + n0 + lx] = t[lx][ly + i];
}

extern "C" void kernel_launch(void* const* d_in, const int* in_sizes, int n_in,
                              void* d_out, int out_size, void* d_ws, size_t ws_size,
                              hipStream_t stream)
{
    const float* features = (const float*)d_in[0];
    const float* xyz   = (const float*)d_in[1];
    const float* fc1_w = (const float*)d_in[2];
    const float* fc1_b = (const float*)d_in[3];
    const float* fc2_w = (const float*)d_in[4];
    const float* fc2_b = (const float*)d_in[5];
    const float* fd1_w = (const float*)d_in[6];
    const float* fd1_b = (const float*)d_in[7];
    const float* fd2_w = (const float*)d_in[8];
    const float* fd2_b = (const float*)d_in[9];
    const float* wq    = (const float*)d_in[10];
    const float* wk    = (const float*)d_in[11];
    const float* wv    = (const float*)d_in[12];
    float* out = (float*)d_out;

    char* base = (char*)d_ws;
    const size_t MB = 1024 * 1024;
    // layout (bytes): part[0,32M) -> after merge: rbar[0,16M) hbarb[16M,24M) resb[24M,32M)
    u64*   part  = (u64*)  (base + 0);
    float* rbar  = (float*)(base + 0);
    __hip_bfloat16* hbarb = (__hip_bfloat16*)(base + 16 * MB);
    __hip_bfloat16* resb  = (__hip_bfloat16*)(base + 24 * MB);
    __hip_bfloat16* featb = (__hip_bfloat16*)(base + 32 * MB);   // 4 MB
    __hip_bfloat16* xb    = (__hip_bfloat16*)(base + 36 * MB);   // 8 MB
    __hip_bfloat16* qb    = (__hip_bfloat16*)(base + 44 * MB);   // 8 MB
    __hip_bfloat16* kb    = (__hip_bfloat16*)(base + 52 * MB);   // 8 MB
    __hip_bfloat16* vb    = (__hip_bfloat16*)(base + 60 * MB);   // 8 MB
    __hip_bfloat16* qpb   = (__hip_bfloat16*)(base + 68 * MB);   // 8 MB
    float* outc  = (float*)(base + 76 * MB);                     // 16 MB
    char*  wreg  = base + 92 * MB;                               // 768 KB of bf16 weights
    __hip_bfloat16* wqT  = (__hip_bfloat16*)(wreg + 0);
    __hip_bfloat16* wkT  = (__hip_bfloat16*)(wreg + 131072);
    __hip_bfloat16* wvT  = (__hip_bfloat16*)(wreg + 262144);
    __hip_bfloat16* fd2c = (__hip_bfloat16*)(wreg + 393216);     // fd2_w as-is (for QP = Q@fd2^T)
    __hip_bfloat16* fd2T = (__hip_bfloat16*)(wreg + 524288);
    __hip_bfloat16* fc1T = (__hip_bfloat16*)(wreg + 655360);
    __hip_bfloat16* fc2T = (__hip_bfloat16*)(wreg + 720896);
    int* idx = (int*)(base + 93 * MB);                           // 1 MB

    const dim3 blk(256);
    const dim3 tblk(32, 8);

    // weight + feature casts (independent of KNN)
    castT_kernel<<<dim3(8, 8), tblk, 0, stream>>>(wq, wqT, DM_, DM_);
    castT_kernel<<<dim3(8, 8), tblk, 0, stream>>>(wk, wkT, DM_, DM_);
    castT_kernel<<<dim3(8, 8), tblk, 0, stream>>>(wv, wvT, DM_, DM_);
    castT_kernel<<<dim3(8, 8), tblk, 0, stream>>>(fd2_w, fd2T, DM_, DM_);
    castT_kernel<<<dim3(8, 4), tblk, 0, stream>>>(fc1_w, fc1T, DP_, DM_);
    castT_kernel<<<dim3(4, 8), tblk, 0, stream>>>(fc2_w, fc2T, DM_, DP_);
    cast_bf16_kernel<<<dim3((DM_ * DM_) / 256), blk, 0, stream>>>(fd2_w, fd2c, DM_ * DM_);
    cast_bf16_kernel<<<dim3((NPTS * DP_) / 256), blk, 0, stream>>>(features, featb, NPTS * DP_);

    // KNN
    knn_part_kernel<<<dim3(N_ / 256, SEG_, B_), blk, 0, stream>>>(xyz, part);
    knn_merge_kernel<<<dim3(NPTS / 256), blk, 0, stream>>>(part, idx);

    // GEMM stack (bf16 MFMA)
    // x = features @ fc1_w + fc1_b          -> xb (bf16 only)
    gemm_bf16_kernel<<<dim3(DM_ / 128, NPTS / 128), blk, 0, stream>>>(
        featb, fc1T, fc1_b, nullptr, nullptr, xb, NPTS, DM_, DP_);
    // q/k/v (bf16 outputs)
    gemm_bf16_kernel<<<dim3(DM_ / 128, NPTS / 128), blk, 0, stream>>>(
        xb, wqT, nullptr, nullptr, nullptr, qb, NPTS, DM_, DM_);
    gemm_bf16_kernel<<<dim3(DM_ / 128, NPTS / 128), blk, 0, stream>>>(
        xb, wkT, nullptr, nullptr, nullptr, kb, NPTS, DM_, DM_);
    gemm_bf16_kernel<<<dim3(DM_ / 128, NPTS / 128), blk, 0, stream>>>(
        xb, wvT, nullptr, nullptr, nullptr, vb, NPTS, DM_, DM_);
    // QP = Q @ fd2_w^T  (Bt[n][k] = fd2_w[n][k] = fd2c)
    gemm_bf16_kernel<<<dim3(DM_ / 128, NPTS / 128), blk, 0, stream>>>(
        qb, fd2c, nullptr, nullptr, nullptr, qpb, NPTS, DM_, DM_);

    // fused attention -> rbar (fp32), hbarb (bf16)
    attn_kernel<<<dim3(NPTS), blk, 0, stream>>>(xyz, qb, kb, vb, qpb, idx,
                                                fd1_w, fd1_b, fd2_b, rbar, hbarb);

    // res = hbar @ fd2_w + fd2_b + rbar     -> resb (bf16)
    gemm_bf16_kernel<<<dim3(DM_ / 128, NPTS / 128), blk, 0, stream>>>(
        hbarb, fd2T, fd2_b, rbar, nullptr, resb, NPTS, DM_, DM_);
    // outc = res @ fc2_w + fc2_b + features (fp32)
    gemm_bf16_kernel<<<dim3(DP_ / 128, NPTS / 128), blk, 0, stream>>>(
        resb, fc2T, fc2_b, features, outc, nullptr, NPTS, DP_, DM_);

    // transpose to [B, DP, N]
    transpose_kernel<<<dim3(N_ / 32, DP_ / 32, B_), tblk, 0, stream>>>(outc, out);

    (void)in_sizes; (void)n_in; (void)out_size; (void)ws_size;
}

// Round 4
// 559.664 us; speedup vs baseline: 7.3969x; 1.1721x over previous
//
#include <hip/hip_runtime.h>
#include <hip/hip_bf16.h>
#include <math.h>

#define B_   4
#define N_   4096
#define K_   16
#define DP_  128
#define DM_  256
#define NPTS (B_ * N_)
#define SEG_ 16
#define CAND_ (N_ / SEG_)   // 256 candidates per segment

typedef unsigned long long u64;
typedef __attribute__((ext_vector_type(8))) short short8;
typedef __attribute__((ext_vector_type(4))) float floatx4;

static __device__ __forceinline__ float bf2f(unsigned short u) {
    return __uint_as_float((unsigned)u << 16);
}

// ---------------- KNN phase 1: per (point, segment) sorted top-16 ----------------
// (d, idx) packed into one u64. Chain is UNCONDITIONAL: with 64 divergent lanes the
// guarded chain executed ~every iteration anyway; straight-line code regallocs better.
__global__ __launch_bounds__(256, 1) void knn_part_kernel(const float* __restrict__ xyz,
                                                          u64* __restrict__ part)
{
    const int b = blockIdx.z;
    const int s = blockIdx.y;
    const int n = blockIdx.x * 256 + threadIdx.x;
    const float* xb = xyz + (size_t)b * N_ * 3;
    const float xn0 = xb[n * 3 + 0], xn1 = xb[n * 3 + 1], xn2 = xb[n * 3 + 2];
    const float sqn = xn0 * xn0 + xn1 * xn1 + xn2 * xn2;

    __shared__ float sx0[CAND_], sx1[CAND_], sx2[CAND_], ssq[CAND_];
    {
        const int t = threadIdx.x;           // CAND_ == 256 == blockDim.x
        const int m = s * CAND_ + t;
        const float a0 = xb[m * 3 + 0];
        const float a1 = xb[m * 3 + 1];
        const float a2 = xb[m * 3 + 2];
        sx0[t] = a0; sx1[t] = a1; sx2[t] = a2;
        ssq[t] = a0 * a0 + a1 * a1 + a2 * a2;
    }
    __syncthreads();

    u64 bl0 = ~0ull, bl1 = ~0ull, bl2 = ~0ull, bl3 = ~0ull,
        bl4 = ~0ull, bl5 = ~0ull, bl6 = ~0ull, bl7 = ~0ull,
        bl8 = ~0ull, bl9 = ~0ull, blA = ~0ull, blB = ~0ull,
        blC = ~0ull, blD = ~0ull, blE = ~0ull, blF = ~0ull;

#define CEX(R) { const bool lt = cand < R; const u64 t = R; R = lt ? cand : R; cand = lt ? t : cand; }
    for (int mm = 0; mm < CAND_; ++mm) {
        // same formula as reference: sq_n + sq_m - 2*dot
        const float dot = xn0 * sx0[mm] + xn1 * sx1[mm] + xn2 * sx2[mm];
        const float d = sqn + ssq[mm] - 2.0f * dot;
        const int ib = __float_as_int(d);
        const unsigned key = (unsigned)ib ^ (unsigned)((ib >> 31) | 0x80000000);
        u64 cand = ((u64)key << 32) | (unsigned)(s * CAND_ + mm);
        CEX(bl0) CEX(bl1) CEX(bl2) CEX(bl3) CEX(bl4) CEX(bl5) CEX(bl6) CEX(bl7)
        CEX(bl8) CEX(bl9) CEX(blA) CEX(blB) CEX(blC) CEX(blD) CEX(blE) CEX(blF)
    }
#undef CEX

    const int p = b * N_ + n;                // global point id
    u64* o = part + p;
    o[(size_t)(s * 16 + 0) * NPTS] = bl0;  o[(size_t)(s * 16 + 1) * NPTS] = bl1;
    o[(size_t)(s * 16 + 2) * NPTS] = bl2;  o[(size_t)(s * 16 + 3) * NPTS] = bl3;
    o[(size_t)(s * 16 + 4) * NPTS] = bl4;  o[(size_t)(s * 16 + 5) * NPTS] = bl5;
    o[(size_t)(s * 16 + 6) * NPTS] = bl6;  o[(size_t)(s * 16 + 7) * NPTS] = bl7;
    o[(size_t)(s * 16 + 8) * NPTS] = bl8;  o[(size_t)(s * 16 + 9) * NPTS] = bl9;
    o[(size_t)(s * 16 + 10) * NPTS] = blA; o[(size_t)(s * 16 + 11) * NPTS] = blB;
    o[(size_t)(s * 16 + 12) * NPTS] = blC; o[(size_t)(s * 16 + 13) * NPTS] = blD;
    o[(size_t)(s * 16 + 14) * NPTS] = blE; o[(size_t)(s * 16 + 15) * NPTS] = blF;
}

// ---------------- KNN merge stage A: 4 segments -> 1 sorted 16-list (x4 groups) ----------------
__global__ __launch_bounds__(256, 1) void knn_merge4_kernel(const u64* __restrict__ part,
                                                            u64* __restrict__ m4)
{
    const int g = blockIdx.x >> 6;                           // segment group 0..3
    const int p = (blockIdx.x & 63) * 256 + threadIdx.x;     // global point id

    u64 bl[16];
#pragma unroll
    for (int i = 0; i < 16; ++i) bl[i] = ~0ull;

    for (int s = g * 4; s < g * 4 + 4; ++s) {
        for (int j = 0; j < 16; ++j) {
            u64 cand = part[(size_t)(s * 16 + j) * NPTS + p];
            if (cand < bl[15]) {
#pragma unroll
                for (int q = 0; q < 16; ++q) {
                    const bool lt = cand < bl[q];
                    const u64 t = bl[q];
                    bl[q] = lt ? cand : bl[q];
                    cand  = lt ? t    : cand;
                }
            } else break;   // segment list sorted: rest can't qualify
        }
    }
#pragma unroll
    for (int j = 0; j < 16; ++j)
        m4[(size_t)(g * 16 + j) * NPTS + p] = bl[j];
}

// ---------------- KNN merge stage B: 4 sorted lists -> final top-16 indices ----------------
__global__ __launch_bounds__(256, 1) void knn_mergeB_kernel(const u64* __restrict__ m4,
                                                            int* __restrict__ knn_idx)
{
    const int p = blockIdx.x * 256 + threadIdx.x;   // global point id
    const int b = p >> 12;                           // p / N_

    u64 bl[16];
#pragma unroll
    for (int i = 0; i < 16; ++i) bl[i] = ~0ull;

    for (int g = 0; g < 4; ++g) {
        for (int j = 0; j < 16; ++j) {
            u64 cand = m4[(size_t)(g * 16 + j) * NPTS + p];
            if (cand < bl[15]) {
#pragma unroll
                for (int q = 0; q < 16; ++q) {
                    const bool lt = cand < bl[q];
                    const u64 t = bl[q];
                    bl[q] = lt ? cand : bl[q];
                    cand  = lt ? t    : cand;
                }
            } else break;
        }
    }

    int* o = knn_idx + (size_t)p * K_;
#pragma unroll
    for (int i = 0; i < 16; ++i) o[i] = b * N_ + (int)(bl[i] & 0xffffffffu);
}

// ---------------- bf16 MFMA GEMM: C[M,N] = A[M,K] @ Bt[N,K]^T (+bias +addC) ----------------
__global__ __launch_bounds__(256) void gemm_bf16_kernel(
    const __hip_bfloat16* __restrict__ A,   // [M][K] bf16
    const __hip_bfloat16* __restrict__ Bt,  // [N][K] bf16
    const float* __restrict__ bias,         // [N] or null
    const float* __restrict__ addC,         // [M][N] fp32 or null
    float* __restrict__ Cf,                 // [M][N] fp32 or null
    __hip_bfloat16* __restrict__ Cb,        // [M][N] bf16 or null
    int M, int N, int K)
{
    __shared__ __align__(16) __hip_bfloat16 As[128 * 32];
    __shared__ __align__(16) __hip_bfloat16 Bs[128 * 32];
    const int tid = threadIdx.x;
    const int m0 = blockIdx.y * 128, n0 = blockIdx.x * 128;
    const int w = tid >> 6, l = tid & 63;
    const int wm = (w >> 1) * 64, wn = (w & 1) * 64;
    const int fm = l & 15, kq = l >> 4;

    floatx4 acc[4][4];
#pragma unroll
    for (int i = 0; i < 4; ++i)
#pragma unroll
        for (int j = 0; j < 4; ++j)
            acc[i][j] = (floatx4){0.0f, 0.0f, 0.0f, 0.0f};

    for (int k0 = 0; k0 < K; k0 += 32) {
        __syncthreads();
#pragma unroll
        for (int c = 0; c < 2; ++c) {        // stage A,B tiles: 2x16B each per thread
            const int li = tid + c * 256;
            const int row = li >> 2, part = li & 3;
            *(uint4*)&As[row * 32 + part * 8] =
                *(const uint4*)&A[(size_t)(m0 + row) * K + k0 + part * 8];
            *(uint4*)&Bs[row * 32 + part * 8] =
                *(const uint4*)&Bt[(size_t)(n0 + row) * K + k0 + part * 8];
        }
        __syncthreads();
        short8 af[4], bf[4];
#pragma unroll
        for (int i = 0; i < 4; ++i)
            af[i] = *(const short8*)&As[(wm + i * 16 + fm) * 32 + kq * 8];
#pragma unroll
        for (int j = 0; j < 4; ++j)
            bf[j] = *(const short8*)&Bs[(wn + j * 16 + fm) * 32 + kq * 8];
#pragma unroll
        for (int i = 0; i < 4; ++i)
#pragma unroll
            for (int j = 0; j < 4; ++j)
                acc[i][j] = __builtin_amdgcn_mfma_f32_16x16x32_bf16(af[i], bf[j], acc[i][j], 0, 0, 0);
    }

#pragma unroll
    for (int i = 0; i < 4; ++i) {
#pragma unroll
        for (int j = 0; j < 4; ++j) {
            const int col = n0 + wn + j * 16 + fm;
            const int rowb = m0 + wm + i * 16 + kq * 4;
#pragma unroll
            for (int r = 0; r < 4; ++r) {
                const int m = rowb + r;
                float v = acc[i][j][r];
                if (bias) v += bias[col];
                if (addC) v += addC[(size_t)m * N + col];
                if (Cf) Cf[(size_t)m * N + col] = v;
                if (Cb) Cb[(size_t)m * N + col] = __float2bfloat16(v);
            }
        }
    }
}

// ---------------- one-shot prep: all weight transpose-casts + straight casts ----------------
__global__ __launch_bounds__(256) void prep_kernel(
    const float* __restrict__ wq, const float* __restrict__ wk, const float* __restrict__ wv,
    const float* __restrict__ fd2, const float* __restrict__ fc1, const float* __restrict__ fc2,
    const float* __restrict__ feat,
    __hip_bfloat16* __restrict__ catW, __hip_bfloat16* __restrict__ fd2T,
    __hip_bfloat16* __restrict__ fc1T, __hip_bfloat16* __restrict__ fc2T,
    __hip_bfloat16* __restrict__ fd2c, __hip_bfloat16* __restrict__ wqc,
    __hip_bfloat16* __restrict__ featb)
{
    __shared__ float t[32][33];
    const int job = blockIdx.z;
    const int tid = threadIdx.x;

    if (job < 6) {   // transpose-cast jobs: out[C][R] = in[R][C]
        const float* in; __hip_bfloat16* outp; int R, C;
        switch (job) {
            case 0: in = wq;  outp = catW;              R = DM_; C = DM_; break;
            case 1: in = wk;  outp = catW + 256 * 256;  R = DM_; C = DM_; break;
            case 2: in = wv;  outp = catW + 512 * 256;  R = DM_; C = DM_; break;
            case 3: in = fd2; outp = fd2T;              R = DM_; C = DM_; break;
            case 4: in = fc1; outp = fc1T;              R = DP_; C = DM_; break;
            default: in = fc2; outp = fc2T;             R = DM_; C = DP_; break;
        }
        const int c0 = blockIdx.x * 32, r0 = blockIdx.y * 32;
        if (c0 >= C || r0 >= R) return;
        const int lx = tid & 31, ly = tid >> 5;   // 32 x 8
#pragma unroll
        for (int i = 0; i < 32; i += 8)
            t[ly + i][lx] = in[(size_t)(r0 + ly + i) * C + c0 + lx];
        __syncthreads();
#pragma unroll
        for (int i = 0; i < 32; i += 8) {
            const float v = t[lx][ly + i];
            outp[(size_t)(c0 + ly + i) * R + r0 + lx] = __float2bfloat16(v);
        }
    } else {         // straight casts, vectorized float4 -> 4x bf16
        const int bid = blockIdx.y * 8 + blockIdx.x;      // 0..63
        const int tId = bid * 256 + tid;                   // 0..16383
        const float* in; __hip_bfloat16* outp; int n4;
        if (job == 6)      { in = fd2;  outp = fd2c;  n4 = (DM_ * DM_) / 4; }
        else if (job == 7) { in = wq;   outp = wqc;   n4 = (DM_ * DM_) / 4; }
        else               { in = feat; outp = featb; n4 = (NPTS * DP_) / 4; }
        for (int i = tId; i < n4; i += 16384) {
            const float4 v = ((const float4*)in)[i];
            ushort4 o;
            o.x = (unsigned short)(__bfloat16_as_ushort(__float2bfloat16(v.x)));
            o.y = (unsigned short)(__bfloat16_as_ushort(__float2bfloat16(v.y)));
            o.z = (unsigned short)(__bfloat16_as_ushort(__float2bfloat16(v.z)));
            o.w = (unsigned short)(__bfloat16_as_ushort(__float2bfloat16(v.w)));
            ((ushort4*)outp)[i] = o;
        }
    }
}

// ---------------- fused attention: one WAVE per point, no LDS, register softmax ----------------
// qkv layout: row p (stride 1024): [0,256)=q, [256,512)=k, [512,768)=v, [768,1024)=qp
__global__ __launch_bounds__(256) void attn_kernel(
    const float* __restrict__ xyz, const __hip_bfloat16* __restrict__ qkv,
    const int* __restrict__ knn_idx,
    const float* __restrict__ fd1_w, const float* __restrict__ fd1_b,
    const float* __restrict__ fd2_b,
    float* __restrict__ rbar, __hip_bfloat16* __restrict__ hbarb)
{
    const int wave = threadIdx.x >> 6, l = threadIdx.x & 63;
    const int p = blockIdx.x * 4 + wave;     // global point id
    const int c0 = l * 4;                    // 4 owned dims per lane

    // own q, qp (8-byte vector loads)
    const ushort4 qu  = *(const ushort4*)(qkv + (size_t)p * 1024 + c0);
    const ushort4 qpu = *(const ushort4*)(qkv + (size_t)p * 1024 + 768 + c0);
    float q4[4], qp4[4];
    q4[0] = bf2f(qu.x); q4[1] = bf2f(qu.y); q4[2] = bf2f(qu.z); q4[3] = bf2f(qu.w);
    qp4[0] = bf2f(qpu.x); qp4[1] = bf2f(qpu.y); qp4[2] = bf2f(qpu.z); qp4[3] = bf2f(qpu.w);

    // per-lane slices of fd1 weights/biases and fd2 bias (read-mostly, L1/L2-hit)
    const float4 w0 = *(const float4*)&fd1_w[c0];
    const float4 w1 = *(const float4*)&fd1_w[DM_ + c0];
    const float4 w2 = *(const float4*)&fd1_w[2 * DM_ + c0];
    const float4 b1 = *(const float4*)&fd1_b[c0];
    const float4 f2b = *(const float4*)&fd2_b[c0];

    // neighbor ids + deltas live in lanes 0..15
    int gi = 0; float dx = 0.0f, dy = 0.0f, dz = 0.0f;
    if (l < 16) {
        gi = knn_idx[p * K_ + l];
        dx = xyz[(size_t)p * 3 + 0] - xyz[(size_t)gi * 3 + 0];
        dy = xyz[(size_t)p * 3 + 1] - xyz[(size_t)gi * 3 + 1];
        dz = xyz[(size_t)p * 3 + 2] - xyz[(size_t)gi * 3 + 2];
    }

    // qb = q . fd2_b (constant over k)
    float qb;
    {
        float tq = q4[0] * f2b.x + q4[1] * f2b.y + q4[2] * f2b.z + q4[3] * f2b.w;
#pragma unroll
        for (int off = 32; off > 0; off >>= 1) tq += __shfl_down(tq, off);
        qb = __shfl(tq, 0);
    }

    // logits: lg[k] = q.kf_k + h_k.qp + qb
    float lg[16];
#pragma unroll
    for (int k = 0; k < 16; ++k) {
        const int gik = __shfl(gi, k);
        const float d0 = __shfl(dx, k), d1 = __shfl(dy, k), d2 = __shfl(dz, k);
        const ushort4 ku = *(const ushort4*)(qkv + (size_t)gik * 1024 + 256 + c0);
        float kv[4] = {bf2f(ku.x), bf2f(ku.y), bf2f(ku.z), bf2f(ku.w)};
        float h0 = fmaxf(d0 * w0.x + d1 * w1.x + d2 * w2.x + b1.x, 0.0f);
        float h1 = fmaxf(d0 * w0.y + d1 * w1.y + d2 * w2.y + b1.y, 0.0f);
        float h2 = fmaxf(d0 * w0.z + d1 * w1.z + d2 * w2.z + b1.z, 0.0f);
        float h3 = fmaxf(d0 * w0.w + d1 * w1.w + d2 * w2.w + b1.w, 0.0f);
        float t = q4[0] * kv[0] + q4[1] * kv[1] + q4[2] * kv[2] + q4[3] * kv[3]
                + h0 * qp4[0] + h1 * qp4[1] + h2 * qp4[2] + h3 * qp4[3];
#pragma unroll
        for (int off = 32; off > 0; off >>= 1) t += __shfl_down(t, off);
        lg[k] = __shfl(t, 0);
    }

    // softmax over 16 (redundant per lane, all registers)
    float att[16];
    {
        float mx = -3.0e38f;
#pragma unroll
        for (int k = 0; k < 16; ++k) {
            att[k] = (lg[k] + qb) * (1.0f / 16.0f);   // / sqrt(DM)
            mx = fmaxf(mx, att[k]);
        }
        float s = 0.0f;
#pragma unroll
        for (int k = 0; k < 16; ++k) { att[k] = __expf(att[k] - mx); s += att[k]; }
        const float inv = 1.0f / s;
#pragma unroll
        for (int k = 0; k < 16; ++k) att[k] *= inv;
    }

    // accumulate rbar = sum att*vf, hbar = sum att*h  (h recomputed)
    float rb[4] = {0, 0, 0, 0}, hb[4] = {0, 0, 0, 0};
#pragma unroll
    for (int k = 0; k < 16; ++k) {
        const int gik = __shfl(gi, k);
        const float d0 = __shfl(dx, k), d1 = __shfl(dy, k), d2 = __shfl(dz, k);
        const ushort4 vu = *(const ushort4*)(qkv + (size_t)gik * 1024 + 512 + c0);
        const float a = att[k];
        rb[0] = fmaf(a, bf2f(vu.x), rb[0]);
        rb[1] = fmaf(a, bf2f(vu.y), rb[1]);
        rb[2] = fmaf(a, bf2f(vu.z), rb[2]);
        rb[3] = fmaf(a, bf2f(vu.w), rb[3]);
        hb[0] = fmaf(a, fmaxf(d0 * w0.x + d1 * w1.x + d2 * w2.x + b1.x, 0.0f), hb[0]);
        hb[1] = fmaf(a, fmaxf(d0 * w0.y + d1 * w1.y + d2 * w2.y + b1.y, 0.0f), hb[1]);
        hb[2] = fmaf(a, fmaxf(d0 * w0.z + d1 * w1.z + d2 * w2.z + b1.z, 0.0f), hb[2]);
        hb[3] = fmaf(a, fmaxf(d0 * w0.w + d1 * w1.w + d2 * w2.w + b1.w, 0.0f), hb[3]);
    }

    *(float4*)&rbar[(size_t)p * DM_ + c0] = (float4){rb[0], rb[1], rb[2], rb[3]};
    ushort4 ho;
    ho.x = __bfloat16_as_ushort(__float2bfloat16(hb[0]));
    ho.y = __bfloat16_as_ushort(__float2bfloat16(hb[1]));
    ho.z = __bfloat16_as_ushort(__float2bfloat16(hb[2]));
    ho.w = __bfloat16_as_ushort(__float2bfloat16(hb[3]));
    *(ushort4*)(hbarb + (size_t)p * DM_ + c0) = ho;
}

// ---------------- transpose [B*N,DP] -> [B,DP,N] ----------------
__global__ __launch_bounds__(256) void transpose_kernel(const float* __restrict__ in,
                                                        float* __restrict__ out)
{
    __shared__ float t[32][33];
    const int b = blockIdx.z;
    const int n0 = blockIdx.x * 32, d0 = blockIdx.y * 32;
    const int lx = threadIdx.x, ly = threadIdx.y;   // 32 x 8
#pragma unroll
    for (int i = 0; i < 32; i += 8)
        t[ly + i][lx] = in[(size_t)(b * N_ + n0 + ly + i) * DP_ + d0 + lx];
    __syncthreads();
#pragma unroll
    for (int i = 0; i < 32; i += 8)
        out[(size_t)(b * DP_ + d0 + ly + i) * N_ + n0 + lx] = t[lx][ly + i];
}

extern "C" void kernel_launch(void* const* d_in, const int* in_sizes, int n_in,
                              void* d_out, int out_size, void* d_ws, size_t ws_size,
                              hipStream_t stream)
{
    const float* features = (const float*)d_in[0];
    const float* xyz   = (const float*)d_in[1];
    const float* fc1_w = (const float*)d_in[2];
    const float* fc1_b = (const float*)d_in[3];
    const float* fc2_w = (const float*)d_in[4];
    const float* fc2_b = (const float*)d_in[5];
    const float* fd1_w = (const float*)d_in[6];
    const float* fd1_b = (const float*)d_in[7];
    const float* fd2_w = (const float*)d_in[8];
    const float* fd2_b = (const float*)d_in[9];
    const float* wq    = (const float*)d_in[10];
    const float* wk    = (const float*)d_in[11];
    const float* wv    = (const float*)d_in[12];
    float* out = (float*)d_out;

    char* base = (char*)d_ws;
    const size_t MB = 1024 * 1024;
    // [0,32M): part -> after mergeA dead -> rbar/hbarb/resb
    // [32M,40M): m4 -> after mergeB dead -> outc
    u64*   part  = (u64*)  (base + 0);
    float* rbar  = (float*)(base + 0);                            // 16 MB
    __hip_bfloat16* hbarb = (__hip_bfloat16*)(base + 16 * MB);    // 8 MB
    __hip_bfloat16* resb  = (__hip_bfloat16*)(base + 24 * MB);    // 8 MB
    u64*   m4    = (u64*)  (base + 32 * MB);                      // 8 MB
    float* outc  = (float*)(base + 32 * MB);                      // 8 MB (after mergeB)
    int*   idx   = (int*)  (base + 40 * MB);                      // 1 MB
    __hip_bfloat16* featb = (__hip_bfloat16*)(base + 42 * MB);    // 4 MB
    __hip_bfloat16* xb    = (__hip_bfloat16*)(base + 46 * MB);    // 8 MB
    __hip_bfloat16* qkv   = (__hip_bfloat16*)(base + 54 * MB);    // 32 MB
    char* wb = base + 86 * MB;
    __hip_bfloat16* catW = (__hip_bfloat16*)(wb + 0);             // [1024][256] = 512 KB
    __hip_bfloat16* fd2T = (__hip_bfloat16*)(wb + 512 * 1024);
    __hip_bfloat16* fc1T = (__hip_bfloat16*)(wb + 640 * 1024);
    __hip_bfloat16* fc2T = (__hip_bfloat16*)(wb + 704 * 1024);
    __hip_bfloat16* fd2c = (__hip_bfloat16*)(wb + 768 * 1024);
    __hip_bfloat16* wqc  = (__hip_bfloat16*)(wb + 896 * 1024);

    const dim3 blk(256);

    // all casts in one dispatch
    prep_kernel<<<dim3(8, 8, 9), blk, 0, stream>>>(wq, wk, wv, fd2_w, fc1_w, fc2_w, features,
                                                   catW, fd2T, fc1T, fc2T, fd2c, wqc, featb);
    // WqpT[a][b] = sum_j fd2[a][j]*wq[b][j] = (wq@fd2^T)^T  -> cat rows 768..1023
    gemm_bf16_kernel<<<dim3(2, 2), blk, 0, stream>>>(
        fd2c, wqc, nullptr, nullptr, nullptr, catW + 768 * 256, DM_, DM_, DM_);

    // KNN
    knn_part_kernel<<<dim3(N_ / 256, SEG_, B_), blk, 0, stream>>>(xyz, part);
    knn_merge4_kernel<<<dim3(256), blk, 0, stream>>>(part, m4);
    knn_mergeB_kernel<<<dim3(NPTS / 256), blk, 0, stream>>>(m4, idx);

    // x = features @ fc1_w + fc1_b
    gemm_bf16_kernel<<<dim3(DM_ / 128, NPTS / 128), blk, 0, stream>>>(
        featb, fc1T, fc1_b, nullptr, nullptr, xb, NPTS, DM_, DP_);
    // [q | k | v | qp] = x @ catW^T   (qp = x @ (wq@fd2^T) — reassociated)
    gemm_bf16_kernel<<<dim3(1024 / 128, NPTS / 128), blk, 0, stream>>>(
        xb, catW, nullptr, nullptr, nullptr, qkv, NPTS, 1024, DM_);

    // fused attention (one wave per point)
    attn_kernel<<<dim3(NPTS / 4), blk, 0, stream>>>(xyz, qkv, idx, fd1_w, fd1_b, fd2_b,
                                                    rbar, hbarb);

    // res = hbar @ fd2_w + fd2_b + rbar
    gemm_bf16_kernel<<<dim3(DM_ / 128, NPTS / 128), blk, 0, stream>>>(
        hbarb, fd2T, fd2_b, rbar, nullptr, resb, NPTS, DM_, DM_);
    // outc = res @ fc2_w + fc2_b + features (fp32)
    gemm_bf16_kernel<<<dim3(DP_ / 128, NPTS / 128), blk, 0, stream>>>(
        resb, fc2T, fc2_b, features, outc, nullptr, NPTS, DP_, DM_);

    // transpose to [B, DP, N]
    transpose_kernel<<<dim3(N_ / 32, DP_ / 32, B_), dim3(32, 8), 0, stream>>>(outc, out);

    (void)in_sizes; (void)n_in; (void)out_size; (void)ws_size;
}

// Round 5
// 354.993 us; speedup vs baseline: 11.6616x; 1.5765x over previous
//
#include <hip/hip_runtime.h>
#include <hip/hip_bf16.h>
#include <math.h>

#define B_   4
#define N_   4096
#define K_   16
#define DP_  128
#define DM_  256
#define NPTS (B_ * N_)
#define SEG_ 32
#define CAND_ (N_ / SEG_)   // 128 candidates per segment

typedef unsigned long long u64;
typedef unsigned int u32;
typedef __attribute__((ext_vector_type(8))) short short8;
typedef __attribute__((ext_vector_type(4))) float floatx4;

static __device__ __forceinline__ float bf2f(unsigned short u) {
    return __uint_as_float((unsigned)u << 16);
}

// ---------------- KNN phase 1: per (point, segment) sorted top-16 ----------------
// (d, idx) packed into ONE u32: monotonic float key, low 12 bits replaced by idx.
// Compare-exchange = v_min_u32 + v_max_u32 (2 inst, no cndmask, no AGPR demotion).
// Quantization (11 mantissa bits) can only swap neighbors whose d2 differ < 2^-12
// relative -- ~1% of points at the rank-16 boundary, output effect ~0.002-0.01.
__global__ __launch_bounds__(256, 1) void knn_part_kernel(const float* __restrict__ xyz,
                                                          u32* __restrict__ part)
{
    const int b = blockIdx.z;
    const int s = blockIdx.y;
    const int n = blockIdx.x * 256 + threadIdx.x;
    const float* xb = xyz + (size_t)b * N_ * 3;
    const float xn0 = xb[n * 3 + 0], xn1 = xb[n * 3 + 1], xn2 = xb[n * 3 + 2];
    const float sqn = xn0 * xn0 + xn1 * xn1 + xn2 * xn2;

    __shared__ float4 sc[CAND_];             // (x, y, z, sq) -> one ds_read_b128 broadcast
    if (threadIdx.x < CAND_) {
        const int m = s * CAND_ + threadIdx.x;
        const float a0 = xb[m * 3 + 0];
        const float a1 = xb[m * 3 + 1];
        const float a2 = xb[m * 3 + 2];
        sc[threadIdx.x] = make_float4(a0, a1, a2, a0 * a0 + a1 * a1 + a2 * a2);
    }
    __syncthreads();

    u32 bl[16];
#pragma unroll
    for (int i = 0; i < 16; ++i) bl[i] = 0xFFFFFFFFu;

    const u32 ibase = (u32)(s * CAND_);
    for (int mm = 0; mm < CAND_; ++mm) {
        const float4 c = sc[mm];
        // same formula as reference: sq_n + sq_m - 2*dot
        const float dot = xn0 * c.x + xn1 * c.y + xn2 * c.z;
        const float d = sqn + c.w - 2.0f * dot;
        const int ib = __float_as_int(d);
        const u32 tk = (u32)ib ^ (u32)((ib >> 31) | 0x80000000);
        u32 cand = (tk & 0xFFFFF000u) | (ibase + (u32)mm);
#pragma unroll
        for (int j = 0; j < 16; ++j) {       // 2-inst compare-exchange
            const u32 lo = min(cand, bl[j]);
            cand = max(cand, bl[j]);
            bl[j] = lo;
        }
    }

    const int p = b * N_ + n;                // global point id
#pragma unroll
    for (int j = 0; j < 16; ++j)
        part[(size_t)(s * 16 + j) * NPTS + p] = bl[j];
}

// ---------------- KNN merge stage A: 4 segments -> 1 sorted 16-list (x8 groups) ----------------
__global__ __launch_bounds__(256, 1) void knn_merge4_kernel(const u32* __restrict__ part,
                                                            u32* __restrict__ m4)
{
    const int g = blockIdx.x >> 6;                           // segment group 0..7
    const int p = (blockIdx.x & 63) * 256 + threadIdx.x;     // global point id

    u32 bl[16];
#pragma unroll
    for (int i = 0; i < 16; ++i) bl[i] = 0xFFFFFFFFu;

    for (int s = g * 4; s < g * 4 + 4; ++s) {
#pragma unroll
        for (int j = 0; j < 16; ++j) {
            u32 cand = part[(size_t)(s * 16 + j) * NPTS + p];
#pragma unroll
            for (int q = 0; q < 16; ++q) {
                const u32 lo = min(cand, bl[q]);
                cand = max(cand, bl[q]);
                bl[q] = lo;
            }
        }
    }
#pragma unroll
    for (int j = 0; j < 16; ++j)
        m4[(size_t)(g * 16 + j) * NPTS + p] = bl[j];
}

// ---------------- KNN merge stage B: 8 sorted lists -> final top-16 indices ----------------
__global__ __launch_bounds__(256, 1) void knn_mergeB_kernel(const u32* __restrict__ m4,
                                                            int* __restrict__ knn_idx)
{
    const int p = blockIdx.x * 256 + threadIdx.x;   // global point id
    const int b = p >> 12;                           // p / N_

    u32 bl[16];
#pragma unroll
    for (int i = 0; i < 16; ++i) bl[i] = 0xFFFFFFFFu;

    for (int g = 0; g < 8; ++g) {
#pragma unroll
        for (int j = 0; j < 16; ++j) {
            u32 cand = m4[(size_t)(g * 16 + j) * NPTS + p];
#pragma unroll
            for (int q = 0; q < 16; ++q) {
                const u32 lo = min(cand, bl[q]);
                cand = max(cand, bl[q]);
                bl[q] = lo;
            }
        }
    }

    int* o = knn_idx + (size_t)p * K_;
#pragma unroll
    for (int i = 0; i < 16; ++i) o[i] = b * N_ + (int)(bl[i] & 0xFFFu);
}

// ---------------- bf16 MFMA GEMM: C[M,N] = A[M,K] @ Bt[N,K]^T (+bias +addC) ----------------
__global__ __launch_bounds__(256) void gemm_bf16_kernel(
    const __hip_bfloat16* __restrict__ A,   // [M][K] bf16
    const __hip_bfloat16* __restrict__ Bt,  // [N][K] bf16
    const float* __restrict__ bias,         // [N] or null
    const float* __restrict__ addC,         // [M][N] fp32 or null
    float* __restrict__ Cf,                 // [M][N] fp32 or null
    __hip_bfloat16* __restrict__ Cb,        // [M][N] bf16 or null
    int M, int N, int K)
{
    __shared__ __align__(16) __hip_bfloat16 As[128 * 32];
    __shared__ __align__(16) __hip_bfloat16 Bs[128 * 32];
    const int tid = threadIdx.x;
    const int m0 = blockIdx.y * 128, n0 = blockIdx.x * 128;
    const int w = tid >> 6, l = tid & 63;
    const int wm = (w >> 1) * 64, wn = (w & 1) * 64;
    const int fm = l & 15, kq = l >> 4;

    floatx4 acc[4][4];
#pragma unroll
    for (int i = 0; i < 4; ++i)
#pragma unroll
        for (int j = 0; j < 4; ++j)
            acc[i][j] = (floatx4){0.0f, 0.0f, 0.0f, 0.0f};

    for (int k0 = 0; k0 < K; k0 += 32) {
        __syncthreads();
#pragma unroll
        for (int c = 0; c < 2; ++c) {        // stage A,B tiles: 2x16B each per thread
            const int li = tid + c * 256;
            const int row = li >> 2, part = li & 3;
            *(uint4*)&As[row * 32 + part * 8] =
                *(const uint4*)&A[(size_t)(m0 + row) * K + k0 + part * 8];
            *(uint4*)&Bs[row * 32 + part * 8] =
                *(const uint4*)&Bt[(size_t)(n0 + row) * K + k0 + part * 8];
        }
        __syncthreads();
        short8 af[4], bf[4];
#pragma unroll
        for (int i = 0; i < 4; ++i)
            af[i] = *(const short8*)&As[(wm + i * 16 + fm) * 32 + kq * 8];
#pragma unroll
        for (int j = 0; j < 4; ++j)
            bf[j] = *(const short8*)&Bs[(wn + j * 16 + fm) * 32 + kq * 8];
#pragma unroll
        for (int i = 0; i < 4; ++i)
#pragma unroll
            for (int j = 0; j < 4; ++j)
                acc[i][j] = __builtin_amdgcn_mfma_f32_16x16x32_bf16(af[i], bf[j], acc[i][j], 0, 0, 0);
    }

#pragma unroll
    for (int i = 0; i < 4; ++i) {
#pragma unroll
        for (int j = 0; j < 4; ++j) {
            const int col = n0 + wn + j * 16 + fm;
            const int rowb = m0 + wm + i * 16 + kq * 4;
#pragma unroll
            for (int r = 0; r < 4; ++r) {
                const int m = rowb + r;
                float v = acc[i][j][r];
                if (bias) v += bias[col];
                if (addC) v += addC[(size_t)m * N + col];
                if (Cf) Cf[(size_t)m * N + col] = v;
                if (Cb) Cb[(size_t)m * N + col] = __float2bfloat16(v);
            }
        }
    }
}

// ---------------- one-shot prep: all weight transpose-casts + straight casts ----------------
__global__ __launch_bounds__(256) void prep_kernel(
    const float* __restrict__ wq, const float* __restrict__ wk, const float* __restrict__ wv,
    const float* __restrict__ fd2, const float* __restrict__ fc1, const float* __restrict__ fc2,
    const float* __restrict__ feat,
    __hip_bfloat16* __restrict__ catW, __hip_bfloat16* __restrict__ fd2T,
    __hip_bfloat16* __restrict__ fc1T, __hip_bfloat16* __restrict__ fc2T,
    __hip_bfloat16* __restrict__ fd2c, __hip_bfloat16* __restrict__ wqc,
    __hip_bfloat16* __restrict__ featb)
{
    __shared__ float t[32][33];
    const int job = blockIdx.z;
    const int tid = threadIdx.x;

    if (job < 6) {   // transpose-cast jobs: out[C][R] = in[R][C]
        const float* in; __hip_bfloat16* outp; int R, C;
        switch (job) {
            case 0: in = wq;  outp = catW;              R = DM_; C = DM_; break;
            case 1: in = wk;  outp = catW + 256 * 256;  R = DM_; C = DM_; break;
            case 2: in = wv;  outp = catW + 512 * 256;  R = DM_; C = DM_; break;
            case 3: in = fd2; outp = fd2T;              R = DM_; C = DM_; break;
            case 4: in = fc1; outp = fc1T;              R = DP_; C = DM_; break;
            default: in = fc2; outp = fc2T;             R = DM_; C = DP_; break;
        }
        const int c0 = blockIdx.x * 32, r0 = blockIdx.y * 32;
        if (c0 >= C || r0 >= R) return;
        const int lx = tid & 31, ly = tid >> 5;   // 32 x 8
#pragma unroll
        for (int i = 0; i < 32; i += 8)
            t[ly + i][lx] = in[(size_t)(r0 + ly + i) * C + c0 + lx];
        __syncthreads();
#pragma unroll
        for (int i = 0; i < 32; i += 8) {
            const float v = t[lx][ly + i];
            outp[(size_t)(c0 + ly + i) * R + r0 + lx] = __float2bfloat16(v);
        }
    } else {         // straight casts, vectorized float4 -> 4x bf16
        const int bid = blockIdx.y * 8 + blockIdx.x;      // 0..63
        const int tId = bid * 256 + tid;                   // 0..16383
        const float* in; __hip_bfloat16* outp; int n4;
        if (job == 6)      { in = fd2;  outp = fd2c;  n4 = (DM_ * DM_) / 4; }
        else if (job == 7) { in = wq;   outp = wqc;   n4 = (DM_ * DM_) / 4; }
        else               { in = feat; outp = featb; n4 = (NPTS * DP_) / 4; }
        for (int i = tId; i < n4; i += 16384) {
            const float4 v = ((const float4*)in)[i];
            ushort4 o;
            o.x = (unsigned short)(__bfloat16_as_ushort(__float2bfloat16(v.x)));
            o.y = (unsigned short)(__bfloat16_as_ushort(__float2bfloat16(v.y)));
            o.z = (unsigned short)(__bfloat16_as_ushort(__float2bfloat16(v.z)));
            o.w = (unsigned short)(__bfloat16_as_ushort(__float2bfloat16(v.w)));
            ((ushort4*)outp)[i] = o;
        }
    }
}

// ---------------- fused attention: one WAVE per point, no LDS, register softmax ----------------
// qkv layout: row p (stride 1024): [0,256)=q, [256,512)=k, [512,768)=v, [768,1024)=qp
__global__ __launch_bounds__(256) void attn_kernel(
    const float* __restrict__ xyz, const __hip_bfloat16* __restrict__ qkv,
    const int* __restrict__ knn_idx,
    const float* __restrict__ fd1_w, const float* __restrict__ fd1_b,
    const float* __restrict__ fd2_b,
    float* __restrict__ rbar, __hip_bfloat16* __restrict__ hbarb)
{
    const int wave = threadIdx.x >> 6, l = threadIdx.x & 63;
    const int p = blockIdx.x * 4 + wave;     // global point id
    const int c0 = l * 4;                    // 4 owned dims per lane

    // own q, qp (8-byte vector loads)
    const ushort4 qu  = *(const ushort4*)(qkv + (size_t)p * 1024 + c0);
    const ushort4 qpu = *(const ushort4*)(qkv + (size_t)p * 1024 + 768 + c0);
    float q4[4], qp4[4];
    q4[0] = bf2f(qu.x); q4[1] = bf2f(qu.y); q4[2] = bf2f(qu.z); q4[3] = bf2f(qu.w);
    qp4[0] = bf2f(qpu.x); qp4[1] = bf2f(qpu.y); qp4[2] = bf2f(qpu.z); qp4[3] = bf2f(qpu.w);

    // per-lane slices of fd1 weights/biases and fd2 bias (read-mostly, L1/L2-hit)
    const float4 w0 = *(const float4*)&fd1_w[c0];
    const float4 w1 = *(const float4*)&fd1_w[DM_ + c0];
    const float4 w2 = *(const float4*)&fd1_w[2 * DM_ + c0];
    const float4 b1 = *(const float4*)&fd1_b[c0];
    const float4 f2b = *(const float4*)&fd2_b[c0];

    // neighbor ids + deltas live in lanes 0..15
    int gi = 0; float dx = 0.0f, dy = 0.0f, dz = 0.0f;
    if (l < 16) {
        gi = knn_idx[p * K_ + l];
        dx = xyz[(size_t)p * 3 + 0] - xyz[(size_t)gi * 3 + 0];
        dy = xyz[(size_t)p * 3 + 1] - xyz[(size_t)gi * 3 + 1];
        dz = xyz[(size_t)p * 3 + 2] - xyz[(size_t)gi * 3 + 2];
    }

    // qb = q . fd2_b (constant over k)
    float qb;
    {
        float tq = q4[0] * f2b.x + q4[1] * f2b.y + q4[2] * f2b.z + q4[3] * f2b.w;
#pragma unroll
        for (int off = 32; off > 0; off >>= 1) tq += __shfl_down(tq, off);
        qb = __shfl(tq, 0);
    }

    // logits: lg[k] = q.kf_k + h_k.qp + qb
    float lg[16];
#pragma unroll
    for (int k = 0; k < 16; ++k) {
        const int gik = __shfl(gi, k);
        const float d0 = __shfl(dx, k), d1 = __shfl(dy, k), d2 = __shfl(dz, k);
        const ushort4 ku = *(const ushort4*)(qkv + (size_t)gik * 1024 + 256 + c0);
        float kv[4] = {bf2f(ku.x), bf2f(ku.y), bf2f(ku.z), bf2f(ku.w)};
        float h0 = fmaxf(d0 * w0.x + d1 * w1.x + d2 * w2.x + b1.x, 0.0f);
        float h1 = fmaxf(d0 * w0.y + d1 * w1.y + d2 * w2.y + b1.y, 0.0f);
        float h2 = fmaxf(d0 * w0.z + d1 * w1.z + d2 * w2.z + b1.z, 0.0f);
        float h3 = fmaxf(d0 * w0.w + d1 * w1.w + d2 * w2.w + b1.w, 0.0f);
        float t = q4[0] * kv[0] + q4[1] * kv[1] + q4[2] * kv[2] + q4[3] * kv[3]
                + h0 * qp4[0] + h1 * qp4[1] + h2 * qp4[2] + h3 * qp4[3];
#pragma unroll
        for (int off = 32; off > 0; off >>= 1) t += __shfl_down(t, off);
        lg[k] = __shfl(t, 0);
    }

    // softmax over 16 (redundant per lane, all registers)
    float att[16];
    {
        float mx = -3.0e38f;
#pragma unroll
        for (int k = 0; k < 16; ++k) {
            att[k] = (lg[k] + qb) * (1.0f / 16.0f);   // / sqrt(DM)
            mx = fmaxf(mx, att[k]);
        }
        float s = 0.0f;
#pragma unroll
        for (int k = 0; k < 16; ++k) { att[k] = __expf(att[k] - mx); s += att[k]; }
        const float inv = 1.0f / s;
#pragma unroll
        for (int k = 0; k < 16; ++k) att[k] *= inv;
    }

    // accumulate rbar = sum att*vf, hbar = sum att*h  (h recomputed)
    float rb[4] = {0, 0, 0, 0}, hb[4] = {0, 0, 0, 0};
#pragma unroll
    for (int k = 0; k < 16; ++k) {
        const int gik = __shfl(gi, k);
        const float d0 = __shfl(dx, k), d1 = __shfl(dy, k), d2 = __shfl(dz, k);
        const ushort4 vu = *(const ushort4*)(qkv + (size_t)gik * 1024 + 512 + c0);
        const float a = att[k];
        rb[0] = fmaf(a, bf2f(vu.x), rb[0]);
        rb[1] = fmaf(a, bf2f(vu.y), rb[1]);
        rb[2] = fmaf(a, bf2f(vu.z), rb[2]);
        rb[3] = fmaf(a, bf2f(vu.w), rb[3]);
        hb[0] = fmaf(a, fmaxf(d0 * w0.x + d1 * w1.x + d2 * w2.x + b1.x, 0.0f), hb[0]);
        hb[1] = fmaf(a, fmaxf(d0 * w0.y + d1 * w1.y + d2 * w2.y + b1.y, 0.0f), hb[1]);
        hb[2] = fmaf(a, fmaxf(d0 * w0.z + d1 * w1.z + d2 * w2.z + b1.z, 0.0f), hb[2]);
        hb[3] = fmaf(a, fmaxf(d0 * w0.w + d1 * w1.w + d2 * w2.w + b1.w, 0.0f), hb[3]);
    }

    *(float4*)&rbar[(size_t)p * DM_ + c0] = (float4){rb[0], rb[1], rb[2], rb[3]};
    ushort4 ho;
    ho.x = __bfloat16_as_ushort(__float2bfloat16(hb[0]));
    ho.y = __bfloat16_as_ushort(__float2bfloat16(hb[1]));
    ho.z = __bfloat16_as_ushort(__float2bfloat16(hb[2]));
    ho.w = __bfloat16_as_ushort(__float2bfloat16(hb[3]));
    *(ushort4*)(hbarb + (size_t)p * DM_ + c0) = ho;
}

// ---------------- transpose [B*N,DP] -> [B,DP,N] ----------------
__global__ __launch_bounds__(256) void transpose_kernel(const float* __restrict__ in,
                                                        float* __restrict__ out)
{
    __shared__ float t[32][33];
    const int b = blockIdx.z;
    const int n0 = blockIdx.x * 32, d0 = blockIdx.y * 32;
    const int lx = threadIdx.x, ly = threadIdx.y;   // 32 x 8
#pragma unroll
    for (int i = 0; i < 32; i += 8)
        t[ly + i][lx] = in[(size_t)(b * N_ + n0 + ly + i) * DP_ + d0 + lx];
    __syncthreads();
#pragma unroll
    for (int i = 0; i < 32; i += 8)
        out[(size_t)(b * DP_ + d0 + ly + i) * N_ + n0 + lx] = t[lx][ly + i];
}

extern "C" void kernel_launch(void* const* d_in, const int* in_sizes, int n_in,
                              void* d_out, int out_size, void* d_ws, size_t ws_size,
                              hipStream_t stream)
{
    const float* features = (const float*)d_in[0];
    const float* xyz   = (const float*)d_in[1];
    const float* fc1_w = (const float*)d_in[2];
    const float* fc1_b = (const float*)d_in[3];
    const float* fc2_w = (const float*)d_in[4];
    const float* fc2_b = (const float*)d_in[5];
    const float* fd1_w = (const float*)d_in[6];
    const float* fd1_b = (const float*)d_in[7];
    const float* fd2_w = (const float*)d_in[8];
    const float* fd2_b = (const float*)d_in[9];
    const float* wq    = (const float*)d_in[10];
    const float* wk    = (const float*)d_in[11];
    const float* wv    = (const float*)d_in[12];
    float* out = (float*)d_out;

    char* base = (char*)d_ws;
    const size_t MB = 1024 * 1024;
    // [0,32M): part (u32, 32 segs) -> after mergeA dead -> rbar/hbarb/resb
    // [32M,40M): m4 (u32, 8 lists) -> after mergeB dead -> outc
    u32*   part  = (u32*)  (base + 0);
    float* rbar  = (float*)(base + 0);                            // 16 MB
    __hip_bfloat16* hbarb = (__hip_bfloat16*)(base + 16 * MB);    // 8 MB
    __hip_bfloat16* resb  = (__hip_bfloat16*)(base + 24 * MB);    // 8 MB
    u32*   m4    = (u32*)  (base + 32 * MB);                      // 8 MB
    float* outc  = (float*)(base + 32 * MB);                      // 8 MB (after mergeB)
    int*   idx   = (int*)  (base + 40 * MB);                      // 1 MB
    __hip_bfloat16* featb = (__hip_bfloat16*)(base + 42 * MB);    // 4 MB
    __hip_bfloat16* xb    = (__hip_bfloat16*)(base + 46 * MB);    // 8 MB
    __hip_bfloat16* qkv   = (__hip_bfloat16*)(base + 54 * MB);    // 32 MB
    char* wb = base + 86 * MB;
    __hip_bfloat16* catW = (__hip_bfloat16*)(wb + 0);             // [1024][256] = 512 KB
    __hip_bfloat16* fd2T = (__hip_bfloat16*)(wb + 512 * 1024);
    __hip_bfloat16* fc1T = (__hip_bfloat16*)(wb + 640 * 1024);
    __hip_bfloat16* fc2T = (__hip_bfloat16*)(wb + 704 * 1024);
    __hip_bfloat16* fd2c = (__hip_bfloat16*)(wb + 768 * 1024);
    __hip_bfloat16* wqc  = (__hip_bfloat16*)(wb + 896 * 1024);

    const dim3 blk(256);

    // all casts in one dispatch
    prep_kernel<<<dim3(8, 8, 9), blk, 0, stream>>>(wq, wk, wv, fd2_w, fc1_w, fc2_w, features,
                                                   catW, fd2T, fc1T, fc2T, fd2c, wqc, featb);
    // WqpT[a][b] = sum_j fd2[a][j]*wq[b][j] = (wq@fd2^T)^T  -> cat rows 768..1023
    gemm_bf16_kernel<<<dim3(2, 2), blk, 0, stream>>>(
        fd2c, wqc, nullptr, nullptr, nullptr, catW + 768 * 256, DM_, DM_, DM_);

    // KNN
    knn_part_kernel<<<dim3(N_ / 256, SEG_, B_), blk, 0, stream>>>(xyz, part);
    knn_merge4_kernel<<<dim3((SEG_ / 4) * (NPTS / 256)), blk, 0, stream>>>(part, m4);
    knn_mergeB_kernel<<<dim3(NPTS / 256), blk, 0, stream>>>(m4, idx);

    // x = features @ fc1_w + fc1_b
    gemm_bf16_kernel<<<dim3(DM_ / 128, NPTS / 128), blk, 0, stream>>>(
        featb, fc1T, fc1_b, nullptr, nullptr, xb, NPTS, DM_, DP_);
    // [q | k | v | qp] = x @ catW^T   (qp = x @ (wq@fd2^T) — reassociated)
    gemm_bf16_kernel<<<dim3(1024 / 128, NPTS / 128), blk, 0, stream>>>(
        xb, catW, nullptr, nullptr, nullptr, qkv, NPTS, 1024, DM_);

    // fused attention (one wave per point)
    attn_kernel<<<dim3(NPTS / 4), blk, 0, stream>>>(xyz, qkv, idx, fd1_w, fd1_b, fd2_b,
                                                    rbar, hbarb);

    // res = hbar @ fd2_w + fd2_b + rbar
    gemm_bf16_kernel<<<dim3(DM_ / 128, NPTS / 128), blk, 0, stream>>>(
        hbarb, fd2T, fd2_b, rbar, nullptr, resb, NPTS, DM_, DM_);
    // outc = res @ fc2_w + fc2_b + features (fp32)
    gemm_bf16_kernel<<<dim3(DP_ / 128, NPTS / 128), blk, 0, stream>>>(
        resb, fc2T, fc2_b, features, outc, nullptr, NPTS, DP_, DM_);

    // transpose to [B, DP, N]
    transpose_kernel<<<dim3(N_ / 32, DP_ / 32, B_), dim3(32, 8), 0, stream>>>(outc, out);

    (void)in_sizes; (void)n_in; (void)out_size; (void)ws_size;
}

// Round 6
// 349.066 us; speedup vs baseline: 11.8596x; 1.0170x over previous
//
#include <hip/hip_runtime.h>
#include <hip/hip_bf16.h>
#include <math.h>

#define B_   4
#define N_   4096
#define K_   16
#define DP_  128
#define DM_  256
#define NPTS (B_ * N_)
#define SEG_ 32
#define CAND_ (N_ / SEG_)   // 128 candidates per segment

typedef unsigned long long u64;
typedef unsigned int u32;
typedef __attribute__((ext_vector_type(8))) short short8;
typedef __attribute__((ext_vector_type(4))) float floatx4;

static __device__ __forceinline__ float bf2f(unsigned short u) {
    return __uint_as_float((unsigned)u << 16);
}

// 16-entry sorted-list state, kept as scalars so the asm can pin them in VGPRs.
struct Top16 {
    u32 b0, b1, b2, b3, b4, b5, b6, b7, b8, b9, bA, bB, bC, bD, bE, bF;
};
static __device__ __forceinline__ void top16_init(Top16& s) {
    s.b0 = s.b1 = s.b2 = s.b3 = s.b4 = s.b5 = s.b6 = s.b7 = 0xFFFFFFFFu;
    s.b8 = s.b9 = s.bA = s.bB = s.bC = s.bD = s.bE = s.bF = 0xFFFFFFFFu;
}
// Insertion compare-exchange chain: 32 v_min/v_max, carry alternates c<->t, no movs.
// Inline asm with "+v" pins all 16 values in arch VGPRs (rounds 2-5: compiler kept
// demoting the array to AGPRs, paying ~32 v_accvgpr moves per candidate).
static __device__ __forceinline__ void top16_insert(Top16& s, u32 cand) {
    u32 t;
    asm("v_max_u32 %[t], %[c], %[b0]\n\t"
        "v_min_u32 %[b0], %[c], %[b0]\n\t"
        "v_max_u32 %[c], %[t], %[b1]\n\t"
        "v_min_u32 %[b1], %[t], %[b1]\n\t"
        "v_max_u32 %[t], %[c], %[b2]\n\t"
        "v_min_u32 %[b2], %[c], %[b2]\n\t"
        "v_max_u32 %[c], %[t], %[b3]\n\t"
        "v_min_u32 %[b3], %[t], %[b3]\n\t"
        "v_max_u32 %[t], %[c], %[b4]\n\t"
        "v_min_u32 %[b4], %[c], %[b4]\n\t"
        "v_max_u32 %[c], %[t], %[b5]\n\t"
        "v_min_u32 %[b5], %[t], %[b5]\n\t"
        "v_max_u32 %[t], %[c], %[b6]\n\t"
        "v_min_u32 %[b6], %[c], %[b6]\n\t"
        "v_max_u32 %[c], %[t], %[b7]\n\t"
        "v_min_u32 %[b7], %[t], %[b7]\n\t"
        "v_max_u32 %[t], %[c], %[b8]\n\t"
        "v_min_u32 %[b8], %[c], %[b8]\n\t"
        "v_max_u32 %[c], %[t], %[b9]\n\t"
        "v_min_u32 %[b9], %[t], %[b9]\n\t"
        "v_max_u32 %[t], %[c], %[bA]\n\t"
        "v_min_u32 %[bA], %[c], %[bA]\n\t"
        "v_max_u32 %[c], %[t], %[bB]\n\t"
        "v_min_u32 %[bB], %[t], %[bB]\n\t"
        "v_max_u32 %[t], %[c], %[bC]\n\t"
        "v_min_u32 %[bC], %[c], %[bC]\n\t"
        "v_max_u32 %[c], %[t], %[bD]\n\t"
        "v_min_u32 %[bD], %[t], %[bD]\n\t"
        "v_max_u32 %[t], %[c], %[bE]\n\t"
        "v_min_u32 %[bE], %[c], %[bE]\n\t"
        "v_max_u32 %[c], %[t], %[bF]\n\t"
        "v_min_u32 %[bF], %[t], %[bF]\n\t"
        : [b0]"+v"(s.b0), [b1]"+v"(s.b1), [b2]"+v"(s.b2), [b3]"+v"(s.b3),
          [b4]"+v"(s.b4), [b5]"+v"(s.b5), [b6]"+v"(s.b6), [b7]"+v"(s.b7),
          [b8]"+v"(s.b8), [b9]"+v"(s.b9), [bA]"+v"(s.bA), [bB]"+v"(s.bB),
          [bC]"+v"(s.bC), [bD]"+v"(s.bD), [bE]"+v"(s.bE), [bF]"+v"(s.bF),
          [c]"+v"(cand), [t]"=&v"(t)
        :);
}
static __device__ __forceinline__ u32 top16_get(const Top16& s, int j) {
    switch (j) {
        case 0: return s.b0;  case 1: return s.b1;  case 2: return s.b2;  case 3: return s.b3;
        case 4: return s.b4;  case 5: return s.b5;  case 6: return s.b6;  case 7: return s.b7;
        case 8: return s.b8;  case 9: return s.b9;  case 10: return s.bA; case 11: return s.bB;
        case 12: return s.bC; case 13: return s.bD; case 14: return s.bE; default: return s.bF;
    }
}

// ---------------- KNN phase 1: per (point, segment) sorted top-16 ----------------
// (d, idx) packed into ONE u32: monotonic float key of d (reference formula), low 12
// bits replaced by within-batch index. Same key semantics as round 5 (passed, 0.0156).
__global__ __launch_bounds__(256, 1) void knn_part_kernel(const float* __restrict__ xyz,
                                                          u32* __restrict__ part)
{
    const int b = blockIdx.z;
    const int s = blockIdx.y;
    const int n = blockIdx.x * 256 + threadIdx.x;
    const float* xb = xyz + (size_t)b * N_ * 3;
    const float xn0 = xb[n * 3 + 0], xn1 = xb[n * 3 + 1], xn2 = xb[n * 3 + 2];
    const float sqn = xn0 * xn0 + xn1 * xn1 + xn2 * xn2;

    __shared__ float4 sc[CAND_];             // (x, y, z, sq) -> one ds_read_b128 broadcast
    if (threadIdx.x < CAND_) {
        const int m = s * CAND_ + threadIdx.x;
        const float a0 = xb[m * 3 + 0];
        const float a1 = xb[m * 3 + 1];
        const float a2 = xb[m * 3 + 2];
        sc[threadIdx.x] = make_float4(a0, a1, a2, a0 * a0 + a1 * a1 + a2 * a2);
    }
    __syncthreads();

    Top16 bl;
    top16_init(bl);

    u32 vid = (u32)(s * CAND_);
#pragma unroll 4
    for (int mm = 0; mm < CAND_; ++mm) {
        const float4 c = sc[mm];
        // same formula as reference: sq_n + sq_m - 2*dot
        const float dot = xn0 * c.x + xn1 * c.y + xn2 * c.z;
        const float d = (sqn + c.w) - 2.0f * dot;
        const int ib = __float_as_int(d);
        const u32 tk = (u32)ib ^ (u32)((ib >> 31) | 0x80000000);
        top16_insert(bl, (tk & 0xFFFFF000u) | vid);
        ++vid;
    }

    const int p = b * N_ + n;                // global point id
#pragma unroll
    for (int j = 0; j < 16; ++j)
        part[(size_t)(s * 16 + j) * NPTS + p] = top16_get(bl, j);
}

// ---------------- KNN merge stage A: 4 segments -> 1 sorted 16-list (x8 groups) ----------------
__global__ __launch_bounds__(256, 1) void knn_merge4_kernel(const u32* __restrict__ part,
                                                            u32* __restrict__ m4)
{
    const int g = blockIdx.x >> 6;                           // segment group 0..7
    const int p = (blockIdx.x & 63) * 256 + threadIdx.x;     // global point id

    Top16 bl;
    top16_init(bl);

    for (int s = g * 4; s < g * 4 + 4; ++s) {
#pragma unroll
        for (int j = 0; j < 16; ++j)
            top16_insert(bl, part[(size_t)(s * 16 + j) * NPTS + p]);
    }
#pragma unroll
    for (int j = 0; j < 16; ++j)
        m4[(size_t)(g * 16 + j) * NPTS + p] = top16_get(bl, j);
}

// ---------------- KNN merge stage B: 8 sorted lists -> final top-16 indices ----------------
__global__ __launch_bounds__(256, 1) void knn_mergeB_kernel(const u32* __restrict__ m4,
                                                            int* __restrict__ knn_idx)
{
    const int p = blockIdx.x * 256 + threadIdx.x;   // global point id
    const int b = p >> 12;                           // p / N_

    Top16 bl;
    top16_init(bl);

    for (int g = 0; g < 8; ++g) {
#pragma unroll
        for (int j = 0; j < 16; ++j)
            top16_insert(bl, m4[(size_t)(g * 16 + j) * NPTS + p]);
    }

    int* o = knn_idx + (size_t)p * K_;
#pragma unroll
    for (int i = 0; i < 16; ++i) o[i] = b * N_ + (int)(top16_get(bl, i) & 0xFFFu);
}

// ---------------- bf16 MFMA GEMM: C[M,N] = A[M,K] @ Bt[N,K]^T (+bias +addC), ldc ----------------
__global__ __launch_bounds__(256) void gemm_bf16_kernel(
    const __hip_bfloat16* __restrict__ A,   // [M][K] bf16
    const __hip_bfloat16* __restrict__ Bt,  // [N][K] bf16
    const float* __restrict__ bias,         // [N-indexed] or null
    const float* __restrict__ addC,         // fp32, row stride ldc, or null
    float* __restrict__ Cf,                 // fp32 out, row stride ldc, or null
    __hip_bfloat16* __restrict__ Cb,        // bf16 out, row stride ldc, or null
    int M, int N, int K, int ldc)
{
    __shared__ __align__(16) __hip_bfloat16 As[128 * 32];
    __shared__ __align__(16) __hip_bfloat16 Bs[128 * 32];
    const int tid = threadIdx.x;
    const int m0 = blockIdx.y * 128, n0 = blockIdx.x * 128;
    const int w = tid >> 6, l = tid & 63;
    const int wm = (w >> 1) * 64, wn = (w & 1) * 64;
    const int fm = l & 15, kq = l >> 4;

    floatx4 acc[4][4];
#pragma unroll
    for (int i = 0; i < 4; ++i)
#pragma unroll
        for (int j = 0; j < 4; ++j)
            acc[i][j] = (floatx4){0.0f, 0.0f, 0.0f, 0.0f};

    for (int k0 = 0; k0 < K; k0 += 32) {
        __syncthreads();
#pragma unroll
        for (int c = 0; c < 2; ++c) {        // stage A,B tiles: 2x16B each per thread
            const int li = tid + c * 256;
            const int row = li >> 2, part = li & 3;
            *(uint4*)&As[row * 32 + part * 8] =
                *(const uint4*)&A[(size_t)(m0 + row) * K + k0 + part * 8];
            *(uint4*)&Bs[row * 32 + part * 8] =
                *(const uint4*)&Bt[(size_t)(n0 + row) * K + k0 + part * 8];
        }
        __syncthreads();
        short8 af[4], bf[4];
#pragma unroll
        for (int i = 0; i < 4; ++i)
            af[i] = *(const short8*)&As[(wm + i * 16 + fm) * 32 + kq * 8];
#pragma unroll
        for (int j = 0; j < 4; ++j)
            bf[j] = *(const short8*)&Bs[(wn + j * 16 + fm) * 32 + kq * 8];
#pragma unroll
        for (int i = 0; i < 4; ++i)
#pragma unroll
            for (int j = 0; j < 4; ++j)
                acc[i][j] = __builtin_amdgcn_mfma_f32_16x16x32_bf16(af[i], bf[j], acc[i][j], 0, 0, 0);
    }

#pragma unroll
    for (int i = 0; i < 4; ++i) {
#pragma unroll
        for (int j = 0; j < 4; ++j) {
            const int col = n0 + wn + j * 16 + fm;
            const int rowb = m0 + wm + i * 16 + kq * 4;
#pragma unroll
            for (int r = 0; r < 4; ++r) {
                const int m = rowb + r;
                float v = acc[i][j][r];
                if (bias) v += bias[col];
                if (addC) v += addC[(size_t)m * ldc + col];
                if (Cf) Cf[(size_t)m * ldc + col] = v;
                if (Cb) Cb[(size_t)m * ldc + col] = __float2bfloat16(v);
            }
        }
    }
}

// ---------------- one-shot prep: weight transpose-casts + straight casts ----------------
__global__ __launch_bounds__(256) void prep_kernel(
    const float* __restrict__ wq, const float* __restrict__ wk, const float* __restrict__ wv,
    const float* __restrict__ fd2, const float* __restrict__ fc1, const float* __restrict__ fc2,
    const float* __restrict__ feat,
    __hip_bfloat16* __restrict__ catW, __hip_bfloat16* __restrict__ fc2T,
    __hip_bfloat16* __restrict__ bt2,
    __hip_bfloat16* __restrict__ fd2c, __hip_bfloat16* __restrict__ wqc,
    __hip_bfloat16* __restrict__ fc1c, __hip_bfloat16* __restrict__ featb)
{
    __shared__ float t[32][33];
    const int job = blockIdx.z;
    const int tid = threadIdx.x;

    if (job < 4) {   // transpose-cast: out[c][r] = in[r][c]
        const float* in; __hip_bfloat16* outp; int R, C, ldo;
        switch (job) {
            case 0: in = wq;  outp = catW;              R = DM_; C = DM_; ldo = DM_; break;
            case 1: in = wk;  outp = catW + 256 * 256;  R = DM_; C = DM_; ldo = DM_; break;
            case 2: in = wv;  outp = catW + 512 * 256;  R = DM_; C = DM_; ldo = DM_; break;
            default: in = fc2; outp = fc2T;             R = DM_; C = DP_; ldo = DM_; break;
        }
        const int c0 = blockIdx.x * 32, r0 = blockIdx.y * 32;
        if (c0 >= C || r0 >= R) return;
        const int lx = tid & 31, ly = tid >> 5;   // 32 x 8
#pragma unroll
        for (int i = 0; i < 32; i += 8)
            t[ly + i][lx] = in[(size_t)(r0 + ly + i) * C + c0 + lx];
        __syncthreads();
#pragma unroll
        for (int i = 0; i < 32; i += 8) {
            const __hip_bfloat16 v = __float2bfloat16(t[lx][ly + i]);
            outp[(size_t)(c0 + ly + i) * ldo + r0 + lx] = v;
            if (job == 3)   // fc2^T also goes into Bt2 columns [256,512)
                bt2[(size_t)(c0 + ly + i) * 512 + 256 + r0 + lx] = v;
        }
    } else {         // straight casts, vectorized float4 -> 4x bf16
        const int bid = blockIdx.y * 8 + blockIdx.x;      // 0..63
        const int tId = bid * 256 + tid;                   // 0..16383
        const float* in; __hip_bfloat16* outp; int n4;
        if (job == 4)      { in = fd2;  outp = fd2c;  n4 = (DM_ * DM_) / 4; }
        else if (job == 5) { in = wq;   outp = wqc;   n4 = (DM_ * DM_) / 4; }
        else if (job == 6) { in = fc1;  outp = fc1c;  n4 = (DP_ * DM_) / 4; }
        else               { in = feat; outp = featb; n4 = (NPTS * DP_) / 4; }
        for (int i = tId; i < n4; i += 16384) {
            const float4 v = ((const float4*)in)[i];
            ushort4 o;
            o.x = __bfloat16_as_ushort(__float2bfloat16(v.x));
            o.y = __bfloat16_as_ushort(__float2bfloat16(v.y));
            o.z = __bfloat16_as_ushort(__float2bfloat16(v.z));
            o.w = __bfloat16_as_ushort(__float2bfloat16(v.w));
            ((ushort4*)outp)[i] = o;
        }
    }
}

// ---------------- folded bias vectors ----------------
// b_all[n] = sum_j fc1_b[j] * catW[n][j]              (n < 1024)
// bias2[n] = sum_t fd2_b[t] * fc2_w[t][n] + fc2_b[n]  (n < 128)
__global__ __launch_bounds__(256) void bias_kernel(
    const float* __restrict__ fc1_b, const float* __restrict__ fd2_b,
    const float* __restrict__ fc2_w, const float* __restrict__ fc2_b,
    const __hip_bfloat16* __restrict__ catW,
    float* __restrict__ b_all, float* __restrict__ bias2)
{
    const int tid = threadIdx.x;
    if (blockIdx.x < 4) {
        const int n = blockIdx.x * 256 + tid;
        float s = 0.0f;
        for (int j = 0; j < DM_; ++j)
            s += fc1_b[j] * __bfloat162float(catW[(size_t)n * DM_ + j]);
        b_all[n] = s;
    } else if (tid < DP_) {
        float s = fc2_b[tid];
        for (int t = 0; t < DM_; ++t)
            s += fd2_b[t] * fc2_w[(size_t)t * DP_ + tid];
        bias2[tid] = s;
    }
}

// ---------------- fused attention: one WAVE per point, no LDS, register softmax ----------------
// qkv layout: row p (stride 1024): [0,256)=q, [256,512)=k, [512,768)=v, [768,1024)=qp
// outputs: ab[p][0,256) = hbar (bf16), ab[p][256,512) = rbar (bf16)
__global__ __launch_bounds__(256) void attn_kernel(
    const float* __restrict__ xyz, const __hip_bfloat16* __restrict__ qkv,
    const int* __restrict__ knn_idx,
    const float* __restrict__ fd1_w, const float* __restrict__ fd1_b,
    const float* __restrict__ fd2_b,
    __hip_bfloat16* __restrict__ ab)
{
    const int wave = threadIdx.x >> 6, l = threadIdx.x & 63;
    const int p = blockIdx.x * 4 + wave;     // global point id
    const int c0 = l * 4;                    // 4 owned dims per lane

    // own q, qp (8-byte vector loads)
    const ushort4 qu  = *(const ushort4*)(qkv + (size_t)p * 1024 + c0);
    const ushort4 qpu = *(const ushort4*)(qkv + (size_t)p * 1024 + 768 + c0);
    float q4[4], qp4[4];
    q4[0] = bf2f(qu.x); q4[1] = bf2f(qu.y); q4[2] = bf2f(qu.z); q4[3] = bf2f(qu.w);
    qp4[0] = bf2f(qpu.x); qp4[1] = bf2f(qpu.y); qp4[2] = bf2f(qpu.z); qp4[3] = bf2f(qpu.w);

    // per-lane slices of fd1 weights/biases and fd2 bias (read-mostly, L1/L2-hit)
    const float4 w0 = *(const float4*)&fd1_w[c0];
    const float4 w1 = *(const float4*)&fd1_w[DM_ + c0];
    const float4 w2 = *(const float4*)&fd1_w[2 * DM_ + c0];
    const float4 b1 = *(const float4*)&fd1_b[c0];
    const float4 f2b = *(const float4*)&fd2_b[c0];

    // neighbor ids + deltas live in lanes 0..15
    int gi = 0; float dx = 0.0f, dy = 0.0f, dz = 0.0f;
    if (l < 16) {
        gi = knn_idx[p * K_ + l];
        dx = xyz[(size_t)p * 3 + 0] - xyz[(size_t)gi * 3 + 0];
        dy = xyz[(size_t)p * 3 + 1] - xyz[(size_t)gi * 3 + 1];
        dz = xyz[(size_t)p * 3 + 2] - xyz[(size_t)gi * 3 + 2];
    }

    // qb = q . fd2_b (constant over k)
    float qb;
    {
        float tq = q4[0] * f2b.x + q4[1] * f2b.y + q4[2] * f2b.z + q4[3] * f2b.w;
#pragma unroll
        for (int off = 32; off > 0; off >>= 1) tq += __shfl_down(tq, off);
        qb = __shfl(tq, 0);
    }

    // logits: lg[k] = q.kf_k + h_k.qp + qb ; prefetch v rows into registers
    float lg[16];
    ushort4 vus[16];
#pragma unroll
    for (int k = 0; k < 16; ++k) {
        const int gik = __shfl(gi, k);
        const float d0 = __shfl(dx, k), d1 = __shfl(dy, k), d2 = __shfl(dz, k);
        const ushort4 ku = *(const ushort4*)(qkv + (size_t)gik * 1024 + 256 + c0);
        vus[k] = *(const ushort4*)(qkv + (size_t)gik * 1024 + 512 + c0);
        float h0 = fmaxf(d0 * w0.x + d1 * w1.x + d2 * w2.x + b1.x, 0.0f);
        float h1 = fmaxf(d0 * w0.y + d1 * w1.y + d2 * w2.y + b1.y, 0.0f);
        float h2 = fmaxf(d0 * w0.z + d1 * w1.z + d2 * w2.z + b1.z, 0.0f);
        float h3 = fmaxf(d0 * w0.w + d1 * w1.w + d2 * w2.w + b1.w, 0.0f);
        float t = q4[0] * bf2f(ku.x) + q4[1] * bf2f(ku.y) + q4[2] * bf2f(ku.z) + q4[3] * bf2f(ku.w)
                + h0 * qp4[0] + h1 * qp4[1] + h2 * qp4[2] + h3 * qp4[3];
#pragma unroll
        for (int off = 32; off > 0; off >>= 1) t += __shfl_down(t, off);
        lg[k] = __shfl(t, 0);
    }

    // softmax over 16 (redundant per lane, all registers)
    float att[16];
    {
        float mx = -3.0e38f;
#pragma unroll
        for (int k = 0; k < 16; ++k) {
            att[k] = (lg[k] + qb) * (1.0f / 16.0f);   // / sqrt(DM)
            mx = fmaxf(mx, att[k]);
        }
        float s = 0.0f;
#pragma unroll
        for (int k = 0; k < 16; ++k) { att[k] = __expf(att[k] - mx); s += att[k]; }
        const float inv = 1.0f / s;
#pragma unroll
        for (int k = 0; k < 16; ++k) att[k] *= inv;
    }

    // accumulate rbar = sum att*vf, hbar = sum att*h  (h recomputed)
    float rb[4] = {0, 0, 0, 0}, hb[4] = {0, 0, 0, 0};
#pragma unroll
    for (int k = 0; k < 16; ++k) {
        const float d0 = __shfl(dx, k), d1 = __shfl(dy, k), d2 = __shfl(dz, k);
        const ushort4 vu = vus[k];
        const float a = att[k];
        rb[0] = fmaf(a, bf2f(vu.x), rb[0]);
        rb[1] = fmaf(a, bf2f(vu.y), rb[1]);
        rb[2] = fmaf(a, bf2f(vu.z), rb[2]);
        rb[3] = fmaf(a, bf2f(vu.w), rb[3]);
        hb[0] = fmaf(a, fmaxf(d0 * w0.x + d1 * w1.x + d2 * w2.x + b1.x, 0.0f), hb[0]);
        hb[1] = fmaf(a, fmaxf(d0 * w0.y + d1 * w1.y + d2 * w2.y + b1.y, 0.0f), hb[1]);
        hb[2] = fmaf(a, fmaxf(d0 * w0.z + d1 * w1.z + d2 * w2.z + b1.z, 0.0f), hb[2]);
        hb[3] = fmaf(a, fmaxf(d0 * w0.w + d1 * w1.w + d2 * w2.w + b1.w, 0.0f), hb[3]);
    }

    ushort4 ho, ro;
    ho.x = __bfloat16_as_ushort(__float2bfloat16(hb[0]));
    ho.y = __bfloat16_as_ushort(__float2bfloat16(hb[1]));
    ho.z = __bfloat16_as_ushort(__float2bfloat16(hb[2]));
    ho.w = __bfloat16_as_ushort(__float2bfloat16(hb[3]));
    ro.x = __bfloat16_as_ushort(__float2bfloat16(rb[0]));
    ro.y = __bfloat16_as_ushort(__float2bfloat16(rb[1]));
    ro.z = __bfloat16_as_ushort(__float2bfloat16(rb[2]));
    ro.w = __bfloat16_as_ushort(__float2bfloat16(rb[3]));
    *(ushort4*)(ab + (size_t)p * 512 + c0) = ho;
    *(ushort4*)(ab + (size_t)p * 512 + 256 + c0) = ro;
}

// ---------------- transpose [B*N,DP] -> [B,DP,N] ----------------
__global__ __launch_bounds__(256) void transpose_kernel(const float* __restrict__ in,
                                                        float* __restrict__ out)
{
    __shared__ float t[32][33];
    const int b = blockIdx.z;
    const int n0 = blockIdx.x * 32, d0 = blockIdx.y * 32;
    const int lx = threadIdx.x, ly = threadIdx.y;   // 32 x 8
#pragma unroll
    for (int i = 0; i < 32; i += 8)
        t[ly + i][lx] = in[(size_t)(b * N_ + n0 + ly + i) * DP_ + d0 + lx];
    __syncthreads();
#pragma unroll
    for (int i = 0; i < 32; i += 8)
        out[(size_t)(b * DP_ + d0 + ly + i) * N_ + n0 + lx] = t[lx][ly + i];
}

extern "C" void kernel_launch(void* const* d_in, const int* in_sizes, int n_in,
                              void* d_out, int out_size, void* d_ws, size_t ws_size,
                              hipStream_t stream)
{
    const float* features = (const float*)d_in[0];
    const float* xyz   = (const float*)d_in[1];
    const float* fc1_w = (const float*)d_in[2];
    const float* fc1_b = (const float*)d_in[3];
    const float* fc2_w = (const float*)d_in[4];
    const float* fc2_b = (const float*)d_in[5];
    const float* fd1_w = (const float*)d_in[6];
    const float* fd1_b = (const float*)d_in[7];
    const float* fd2_w = (const float*)d_in[8];
    const float* fd2_b = (const float*)d_in[9];
    const float* wq    = (const float*)d_in[10];
    const float* wk    = (const float*)d_in[11];
    const float* wv    = (const float*)d_in[12];
    float* out = (float*)d_out;

    char* base = (char*)d_ws;
    const size_t MB = 1024 * 1024;
    // [0,32M): part (u32) -> dead after merge4 -> ab[0,16M), outc[16M,24M)
    // [32M,36M): m4 -> dead after mergeB
    u32*   part  = (u32*)  (base + 0);
    __hip_bfloat16* ab = (__hip_bfloat16*)(base + 0);             // 16 MB [hbar|rbar]
    float* outc  = (float*)(base + 16 * MB);                      // 8 MB
    u32*   m4    = (u32*)  (base + 32 * MB);                      // 4 MB
    __hip_bfloat16* qkv   = (__hip_bfloat16*)(base + 36 * MB);    // 32 MB
    __hip_bfloat16* featb = (__hip_bfloat16*)(base + 68 * MB);    // 4 MB
    int*   idx   = (int*)  (base + 72 * MB);                      // 1 MB
    char* wb = base + 73 * MB;
    __hip_bfloat16* catW  = (__hip_bfloat16*)(wb + 0);            // [1024][256] = 512 KB
    __hip_bfloat16* WallT = (__hip_bfloat16*)(wb + 512 * 1024);   // [1024][128] = 256 KB
    __hip_bfloat16* bt2   = (__hip_bfloat16*)(wb + 768 * 1024);   // [128][512]  = 128 KB
    __hip_bfloat16* fd2c  = (__hip_bfloat16*)(wb + 896 * 1024);   // 128 KB
    __hip_bfloat16* wqc   = (__hip_bfloat16*)(wb + 1024 * 1024);  // 128 KB
    __hip_bfloat16* fc1c  = (__hip_bfloat16*)(wb + 1152 * 1024);  // 64 KB
    __hip_bfloat16* fc2T  = (__hip_bfloat16*)(wb + 1216 * 1024);  // 64 KB
    float* b_all = (float*)(wb + 1280 * 1024);                    // 4 KB
    float* bias2 = (float*)(wb + 1284 * 1024);                    // 512 B

    const dim3 blk(256);

    // casts (also seeds bt2 cols [256,512) with fc2^T)
    prep_kernel<<<dim3(8, 8, 8), blk, 0, stream>>>(wq, wk, wv, fd2_w, fc1_w, fc2_w, features,
                                                   catW, fc2T, bt2, fd2c, wqc, fc1c, featb);
    // catW rows 768..1023: Wqp^T[a][b] = sum_j fd2[a][j]*wq[b][j]  (qp = x @ (wq@fd2^T))
    gemm_bf16_kernel<<<dim3(2, 2), blk, 0, stream>>>(
        fd2c, wqc, nullptr, nullptr, nullptr, catW + 768 * 256, DM_, DM_, DM_, DM_);
    // folded biases (needs full catW)
    bias_kernel<<<dim3(5), blk, 0, stream>>>(fc1_b, fd2_b, fc2_w, fc2_b, catW, b_all, bias2);
    // WallT[n][k] = sum_j catW[n][j]*fc1_w[k][j]   (fc1 folded into QKV weight)
    gemm_bf16_kernel<<<dim3(1, 8), blk, 0, stream>>>(
        catW, fc1c, nullptr, nullptr, nullptr, WallT, 1024, DP_, DM_, DP_);
    // bt2 cols [0,256): Wof^T[n][j] = sum_t fc2[t][n]*fd2[j][t]    (fd2@fc2 folded)
    gemm_bf16_kernel<<<dim3(2, 1), blk, 0, stream>>>(
        fc2T, fd2c, nullptr, nullptr, nullptr, bt2, DP_, DM_, DM_, 512);

    // KNN
    knn_part_kernel<<<dim3(N_ / 256, SEG_, B_), blk, 0, stream>>>(xyz, part);
    knn_merge4_kernel<<<dim3((SEG_ / 4) * (NPTS / 256)), blk, 0, stream>>>(part, m4);
    knn_mergeB_kernel<<<dim3(NPTS / 256), blk, 0, stream>>>(m4, idx);

    // [q | k | v | qp] = features @ WallT^T + b_all   (fc1 folded, K=128)
    gemm_bf16_kernel<<<dim3(1024 / 128, NPTS / 128), blk, 0, stream>>>(
        featb, WallT, b_all, nullptr, nullptr, qkv, NPTS, 1024, DP_, 1024);

    // fused attention (one wave per point) -> ab = [hbar | rbar]
    attn_kernel<<<dim3(NPTS / 4), blk, 0, stream>>>(xyz, qkv, idx, fd1_w, fd1_b, fd2_b, ab);

    // out = ab @ bt2^T + bias2 + features   (res and fc2 GEMMs merged, K=512)
    gemm_bf16_kernel<<<dim3(1, NPTS / 128), blk, 0, stream>>>(
        ab, bt2, bias2, features, outc, nullptr, NPTS, DP_, 512, DP_);

    // transpose to [B, DP, N]
    transpose_kernel<<<dim3(N_ / 32, DP_ / 32, B_), dim3(32, 8), 0, stream>>>(outc, out);

    (void)in_sizes; (void)n_in; (void)out_size; (void)ws_size;
}

// Round 7
// 322.891 us; speedup vs baseline: 12.8210x; 1.0811x over previous
//
#include <hip/hip_runtime.h>
#include <hip/hip_bf16.h>
#include <math.h>

#define B_   4
#define N_   4096
#define K_   16
#define DP_  128
#define DM_  256
#define NPTS (B_ * N_)
#define SEG_ 32
#define CAND_ (N_ / SEG_)   // 128 candidates per segment

typedef unsigned int u32;
typedef unsigned short u16;
typedef __attribute__((ext_vector_type(8))) short short8;
typedef __attribute__((ext_vector_type(8))) unsigned short u16x8;
typedef __attribute__((ext_vector_type(4))) float floatx4;

static __device__ __forceinline__ float bf2f(u16 u) {
    return __uint_as_float((u32)u << 16);
}

// ---- bitonic primitives on u32 registers ----
#define CEXA(x, y) { u32 _lo = min(x, y); y = max(x, y); x = _lo; }   // x<=y
#define CEXD(x, y) { u32 _hi = max(x, y); y = min(x, y); x = _hi; }   // x>=y

// full bitonic sort of 16, DESCENDING (c[0] >= ... >= c[15]); 80 CEX
static __device__ __forceinline__ void sort16_desc(u32 c[16]) {
    CEXD(c[0],c[1]);  CEXA(c[2],c[3]);  CEXD(c[4],c[5]);  CEXA(c[6],c[7]);
    CEXD(c[8],c[9]);  CEXA(c[10],c[11]); CEXD(c[12],c[13]); CEXA(c[14],c[15]);

    CEXD(c[0],c[2]);  CEXD(c[1],c[3]);  CEXA(c[4],c[6]);  CEXA(c[5],c[7]);
    CEXD(c[8],c[10]); CEXD(c[9],c[11]); CEXA(c[12],c[14]); CEXA(c[13],c[15]);
    CEXD(c[0],c[1]);  CEXD(c[2],c[3]);  CEXA(c[4],c[5]);  CEXA(c[6],c[7]);
    CEXD(c[8],c[9]);  CEXD(c[10],c[11]); CEXA(c[12],c[13]); CEXA(c[14],c[15]);

    CEXD(c[0],c[4]);  CEXD(c[1],c[5]);  CEXD(c[2],c[6]);  CEXD(c[3],c[7]);
    CEXA(c[8],c[12]); CEXA(c[9],c[13]); CEXA(c[10],c[14]); CEXA(c[11],c[15]);
    CEXD(c[0],c[2]);  CEXD(c[1],c[3]);  CEXD(c[4],c[6]);  CEXD(c[5],c[7]);
    CEXA(c[8],c[10]); CEXA(c[9],c[11]); CEXA(c[12],c[14]); CEXA(c[13],c[15]);
    CEXD(c[0],c[1]);  CEXD(c[2],c[3]);  CEXD(c[4],c[5]);  CEXD(c[6],c[7]);
    CEXA(c[8],c[9]);  CEXA(c[10],c[11]); CEXA(c[12],c[13]); CEXA(c[14],c[15]);

    CEXD(c[0],c[8]);  CEXD(c[1],c[9]);  CEXD(c[2],c[10]); CEXD(c[3],c[11]);
    CEXD(c[4],c[12]); CEXD(c[5],c[13]); CEXD(c[6],c[14]); CEXD(c[7],c[15]);
    CEXD(c[0],c[4]);  CEXD(c[1],c[5]);  CEXD(c[2],c[6]);  CEXD(c[3],c[7]);
    CEXD(c[8],c[12]); CEXD(c[9],c[13]); CEXD(c[10],c[14]); CEXD(c[11],c[15]);
    CEXD(c[0],c[2]);  CEXD(c[1],c[3]);  CEXD(c[4],c[6]);  CEXD(c[5],c[7]);
    CEXD(c[8],c[10]); CEXD(c[9],c[11]); CEXD(c[12],c[14]); CEXD(c[13],c[15]);
    CEXD(c[0],c[1]);  CEXD(c[2],c[3]);  CEXD(c[4],c[5]);  CEXD(c[6],c[7]);
    CEXD(c[8],c[9]);  CEXD(c[10],c[11]); CEXD(c[12],c[13]); CEXD(c[14],c[15]);
}

// L is bitonic -> sort ascending; 32 CEX (4 stages)
static __device__ __forceinline__ void remerge16_asc(u32 L[16]) {
    CEXA(L[0],L[8]);  CEXA(L[1],L[9]);  CEXA(L[2],L[10]); CEXA(L[3],L[11]);
    CEXA(L[4],L[12]); CEXA(L[5],L[13]); CEXA(L[6],L[14]); CEXA(L[7],L[15]);
    CEXA(L[0],L[4]);  CEXA(L[1],L[5]);  CEXA(L[2],L[6]);  CEXA(L[3],L[7]);
    CEXA(L[8],L[12]); CEXA(L[9],L[13]); CEXA(L[10],L[14]); CEXA(L[11],L[15]);
    CEXA(L[0],L[2]);  CEXA(L[1],L[3]);  CEXA(L[4],L[6]);  CEXA(L[5],L[7]);
    CEXA(L[8],L[10]); CEXA(L[9],L[11]); CEXA(L[12],L[14]); CEXA(L[13],L[15]);
    CEXA(L[0],L[1]);  CEXA(L[2],L[3]);  CEXA(L[4],L[5]);  CEXA(L[6],L[7]);
    CEXA(L[8],L[9]);  CEXA(L[10],L[11]); CEXA(L[12],L[13]); CEXA(L[14],L[15]);
}

// ---------------- KNN phase 1: bitonic-batch top-16 per (point, segment) ----------------
// u32 key = monotonic-float(d) with low 12 bits replaced by within-batch idx (round 5
// semantics, passed at 0.0156). Batch-16: sort desc (160 in), pair-min vs ascending
// list (16), 4-stage remerge (64) -> 15 inst/cand selection vs 32 for insert-chain.
__global__ __launch_bounds__(256, 1) void knn_part_kernel(const float* __restrict__ xyz,
                                                          u32* __restrict__ part)
{
    const int b = blockIdx.z;
    const int s = blockIdx.y;
    const int n = blockIdx.x * 256 + threadIdx.x;
    const float* xb = xyz + (size_t)b * N_ * 3;
    const float xn0 = xb[n * 3 + 0], xn1 = xb[n * 3 + 1], xn2 = xb[n * 3 + 2];
    const float sqn = xn0 * xn0 + xn1 * xn1 + xn2 * xn2;

    __shared__ float4 sc[CAND_];             // (x, y, z, sq) -> one ds_read_b128 broadcast
    if (threadIdx.x < CAND_) {
        const int m = s * CAND_ + threadIdx.x;
        const float a0 = xb[m * 3 + 0];
        const float a1 = xb[m * 3 + 1];
        const float a2 = xb[m * 3 + 2];
        sc[threadIdx.x] = make_float4(a0, a1, a2, a0 * a0 + a1 * a1 + a2 * a2);
    }
    __syncthreads();

    u32 L[16];
#pragma unroll
    for (int i = 0; i < 16; ++i) L[i] = 0xFFFFFFFFu;

    const u32 ibase = (u32)(s * CAND_);
    for (int m0 = 0; m0 < CAND_; m0 += 16) {
        u32 c[16];
#pragma unroll
        for (int t = 0; t < 16; ++t) {
            const float4 cc = sc[m0 + t];
            // same formula as reference: sq_n + sq_m - 2*dot
            const float dot = xn0 * cc.x + xn1 * cc.y + xn2 * cc.z;
            const float d = (sqn + cc.w) - 2.0f * dot;
            const int ib = __float_as_int(d);
            const u32 tk = (u32)ib ^ (u32)((ib >> 31) | 0x80000000);
            c[t] = (tk & 0xFFFFF000u) | (ibase + (u32)(m0 + t));
        }
        sort16_desc(c);
#pragma unroll
        for (int i = 0; i < 16; ++i) L[i] = min(L[i], c[i]);   // keep lowest 16 of union
        remerge16_asc(L);
    }

    const int p = b * N_ + n;                // global point id
#pragma unroll
    for (int j = 0; j < 16; ++j)
        part[(size_t)(s * 16 + j) * NPTS + p] = L[j];
}

// ---------------- KNN merge: 32 sorted 16-lists -> final top-16 (single stage) ----------------
// Incoming lists are sorted ascending: pair-min vs reversed list + remerge = 96 inst/list.
__global__ __launch_bounds__(64, 1) void knn_merge_kernel(const u32* __restrict__ part,
                                                          int* __restrict__ knn_idx)
{
    const int p = blockIdx.x * 64 + threadIdx.x;   // global point id
    const int b = p >> 12;                          // p / N_

    u32 L[16];
#pragma unroll
    for (int i = 0; i < 16; ++i) L[i] = 0xFFFFFFFFu;

    for (int s = 0; s < SEG_; ++s) {
        u32 seg[16];
#pragma unroll
        for (int j = 0; j < 16; ++j)
            seg[j] = part[(size_t)(s * 16 + j) * NPTS + p];
#pragma unroll
        for (int i = 0; i < 16; ++i) L[i] = min(L[i], seg[15 - i]);
        remerge16_asc(L);
    }

    int* o = knn_idx + (size_t)p * K_;
#pragma unroll
    for (int i = 0; i < 16; ++i) o[i] = b * N_ + (int)(L[i] & 0xFFFu);
}

// ---------------- bf16 MFMA GEMM: C[M,N] = A[M,K] @ Bt[N,K]^T (+bias +addC), ldc ----------------
__global__ __launch_bounds__(256) void gemm_bf16_kernel(
    const __hip_bfloat16* __restrict__ A,   // [M][K] bf16
    const __hip_bfloat16* __restrict__ Bt,  // [N][K] bf16
    const float* __restrict__ bias,         // [N-indexed] or null
    const float* __restrict__ addC,         // fp32, row stride ldc, or null
    float* __restrict__ Cf,                 // fp32 out, row stride ldc, or null
    __hip_bfloat16* __restrict__ Cb,        // bf16 out, row stride ldc, or null
    int M, int N, int K, int ldc)
{
    __shared__ __align__(16) __hip_bfloat16 As[128 * 32];
    __shared__ __align__(16) __hip_bfloat16 Bs[128 * 32];
    const int tid = threadIdx.x;
    const int m0 = blockIdx.y * 128, n0 = blockIdx.x * 128;
    const int w = tid >> 6, l = tid & 63;
    const int wm = (w >> 1) * 64, wn = (w & 1) * 64;
    const int fm = l & 15, kq = l >> 4;

    floatx4 acc[4][4];
#pragma unroll
    for (int i = 0; i < 4; ++i)
#pragma unroll
        for (int j = 0; j < 4; ++j)
            acc[i][j] = (floatx4){0.0f, 0.0f, 0.0f, 0.0f};

    for (int k0 = 0; k0 < K; k0 += 32) {
        __syncthreads();
#pragma unroll
        for (int c = 0; c < 2; ++c) {        // stage A,B tiles: 2x16B each per thread
            const int li = tid + c * 256;
            const int row = li >> 2, part = li & 3;
            *(uint4*)&As[row * 32 + part * 8] =
                *(const uint4*)&A[(size_t)(m0 + row) * K + k0 + part * 8];
            *(uint4*)&Bs[row * 32 + part * 8] =
                *(const uint4*)&Bt[(size_t)(n0 + row) * K + k0 + part * 8];
        }
        __syncthreads();
        short8 af[4], bf[4];
#pragma unroll
        for (int i = 0; i < 4; ++i)
            af[i] = *(const short8*)&As[(wm + i * 16 + fm) * 32 + kq * 8];
#pragma unroll
        for (int j = 0; j < 4; ++j)
            bf[j] = *(const short8*)&Bs[(wn + j * 16 + fm) * 32 + kq * 8];
#pragma unroll
        for (int i = 0; i < 4; ++i)
#pragma unroll
            for (int j = 0; j < 4; ++j)
                acc[i][j] = __builtin_amdgcn_mfma_f32_16x16x32_bf16(af[i], bf[j], acc[i][j], 0, 0, 0);
    }

#pragma unroll
    for (int i = 0; i < 4; ++i) {
#pragma unroll
        for (int j = 0; j < 4; ++j) {
            const int col = n0 + wn + j * 16 + fm;
            const int rowb = m0 + wm + i * 16 + kq * 4;
#pragma unroll
            for (int r = 0; r < 4; ++r) {
                const int m = rowb + r;
                float v = acc[i][j][r];
                if (bias) v += bias[col];
                if (addC) v += addC[(size_t)m * ldc + col];
                if (Cf) Cf[(size_t)m * ldc + col] = v;
                if (Cb) Cb[(size_t)m * ldc + col] = __float2bfloat16(v);
            }
        }
    }
}

// ---------------- one-shot prep: weight transpose-casts + straight casts ----------------
// k/v rows of catW are INTERLEAVED: k-col c -> row 256+8*(c/4)+(c%4); v-col c -> +4.
// Downstream (b_all, WallT fold, qkv GEMM) track this automatically via catW rows;
// attn reads one 16B kv load per lane per neighbor.
__global__ __launch_bounds__(256) void prep_kernel(
    const float* __restrict__ wq, const float* __restrict__ wk, const float* __restrict__ wv,
    const float* __restrict__ fd2, const float* __restrict__ fc1, const float* __restrict__ fc2,
    const float* __restrict__ feat,
    __hip_bfloat16* __restrict__ catW, __hip_bfloat16* __restrict__ fc2T,
    __hip_bfloat16* __restrict__ bt2,
    __hip_bfloat16* __restrict__ fd2c, __hip_bfloat16* __restrict__ wqc,
    __hip_bfloat16* __restrict__ fc1c, __hip_bfloat16* __restrict__ featb)
{
    __shared__ float t[32][33];
    const int job = blockIdx.z;
    const int tid = threadIdx.x;

    if (job < 4) {   // transpose-cast: row n(c) gets in[:,c]
        const float* in; int R, C;
        switch (job) {
            case 0: in = wq;  R = DM_; C = DM_; break;
            case 1: in = wk;  R = DM_; C = DM_; break;
            case 2: in = wv;  R = DM_; C = DM_; break;
            default: in = fc2; R = DM_; C = DP_; break;
        }
        const int c0 = blockIdx.x * 32, r0 = blockIdx.y * 32;
        if (c0 >= C || r0 >= R) return;
        const int lx = tid & 31, ly = tid >> 5;   // 32 x 8
#pragma unroll
        for (int i = 0; i < 32; i += 8)
            t[ly + i][lx] = in[(size_t)(r0 + ly + i) * C + c0 + lx];
        __syncthreads();
#pragma unroll
        for (int i = 0; i < 32; i += 8) {
            const int c = c0 + ly + i;
            const __hip_bfloat16 v = __float2bfloat16(t[lx][ly + i]);
            int n;
            switch (job) {
                case 0: n = c; break;                                 // q rows [0,256)
                case 1: n = 256 + ((c >> 2) << 3) + (c & 3); break;   // k interleaved
                case 2: n = 256 + ((c >> 2) << 3) + 4 + (c & 3); break; // v interleaved
                default: n = -1; break;
            }
            if (job < 3) {
                catW[(size_t)n * DM_ + r0 + lx] = v;
            } else {
                fc2T[(size_t)c * DM_ + r0 + lx] = v;                  // fc2^T [128][256]
                bt2[(size_t)c * 512 + 256 + r0 + lx] = v;             // bt2 cols [256,512)
            }
        }
    } else {         // straight casts, vectorized float4 -> 4x bf16
        const int bid = blockIdx.y * 8 + blockIdx.x;      // 0..63
        const int tId = bid * 256 + tid;                   // 0..16383
        const float* in; __hip_bfloat16* outp; int n4;
        if (job == 4)      { in = fd2;  outp = fd2c;  n4 = (DM_ * DM_) / 4; }
        else if (job == 5) { in = wq;   outp = wqc;   n4 = (DM_ * DM_) / 4; }
        else if (job == 6) { in = fc1;  outp = fc1c;  n4 = (DP_ * DM_) / 4; }
        else               { in = feat; outp = featb; n4 = (NPTS * DP_) / 4; }
        for (int i = tId; i < n4; i += 16384) {
            const float4 v = ((const float4*)in)[i];
            ushort4 o;
            o.x = __bfloat16_as_ushort(__float2bfloat16(v.x));
            o.y = __bfloat16_as_ushort(__float2bfloat16(v.y));
            o.z = __bfloat16_as_ushort(__float2bfloat16(v.z));
            o.w = __bfloat16_as_ushort(__float2bfloat16(v.w));
            ((ushort4*)outp)[i] = o;
        }
    }
}

// ---------------- folded bias vectors ----------------
__global__ __launch_bounds__(256) void bias_kernel(
    const float* __restrict__ fc1_b, const float* __restrict__ fd2_b,
    const float* __restrict__ fc2_w, const float* __restrict__ fc2_b,
    const __hip_bfloat16* __restrict__ catW,
    float* __restrict__ b_all, float* __restrict__ bias2)
{
    const int tid = threadIdx.x;
    if (blockIdx.x < 4) {
        const int n = blockIdx.x * 256 + tid;
        float s = 0.0f;
        for (int j = 0; j < DM_; ++j)
            s += fc1_b[j] * __bfloat162float(catW[(size_t)n * DM_ + j]);
        b_all[n] = s;
    } else if (tid < DP_) {
        float s = fc2_b[tid];
        for (int t = 0; t < DM_; ++t)
            s += fd2_b[t] * fc2_w[(size_t)t * DP_ + tid];
        bias2[tid] = s;
    }
}

// ---------------- fused attention: one WAVE per point, no LDS, register softmax ----------------
// qkv row p (stride 1024): [0,256)=q, [256,768)=interleaved {k[4c..],v[4c..]} octets,
// [768,1024)=qp.  Lane l owns dims 4l..4l+3: k+v arrive in ONE 16B load at col 256+8l.
__global__ __launch_bounds__(256) void attn_kernel(
    const float* __restrict__ xyz, const __hip_bfloat16* __restrict__ qkv,
    const int* __restrict__ knn_idx,
    const float* __restrict__ fd1_w, const float* __restrict__ fd1_b,
    const float* __restrict__ fd2_b,
    __hip_bfloat16* __restrict__ ab)
{
    const int wave = threadIdx.x >> 6, l = threadIdx.x & 63;
    const int p = blockIdx.x * 4 + wave;     // global point id
    const int c0 = l * 4;                    // 4 owned dims per lane

    const ushort4 qu  = *(const ushort4*)(qkv + (size_t)p * 1024 + c0);
    const ushort4 qpu = *(const ushort4*)(qkv + (size_t)p * 1024 + 768 + c0);
    float q4[4], qp4[4];
    q4[0] = bf2f(qu.x); q4[1] = bf2f(qu.y); q4[2] = bf2f(qu.z); q4[3] = bf2f(qu.w);
    qp4[0] = bf2f(qpu.x); qp4[1] = bf2f(qpu.y); qp4[2] = bf2f(qpu.z); qp4[3] = bf2f(qpu.w);

    const float4 w0 = *(const float4*)&fd1_w[c0];
    const float4 w1 = *(const float4*)&fd1_w[DM_ + c0];
    const float4 w2 = *(const float4*)&fd1_w[2 * DM_ + c0];
    const float4 b1 = *(const float4*)&fd1_b[c0];
    const float4 f2b = *(const float4*)&fd2_b[c0];

    int gi = 0; float dx = 0.0f, dy = 0.0f, dz = 0.0f;
    if (l < 16) {
        gi = knn_idx[p * K_ + l];
        dx = xyz[(size_t)p * 3 + 0] - xyz[(size_t)gi * 3 + 0];
        dy = xyz[(size_t)p * 3 + 1] - xyz[(size_t)gi * 3 + 1];
        dz = xyz[(size_t)p * 3 + 2] - xyz[(size_t)gi * 3 + 2];
    }

    // qb = q . fd2_b (constant over k)
    float qb;
    {
        float tq = q4[0] * f2b.x + q4[1] * f2b.y + q4[2] * f2b.z + q4[3] * f2b.w;
#pragma unroll
        for (int off = 1; off < 64; off <<= 1) tq += __shfl_xor(tq, off);
        qb = tq;
    }

    // logits: lg[k] = q.kf_k + h_k.qp + qb ; v half of each 16B load kept for phase 2
    float lg[16];
    ushort4 vus[16];
#pragma unroll
    for (int k = 0; k < 16; ++k) {
        const int gik = __shfl(gi, k);
        const float d0 = __shfl(dx, k), d1 = __shfl(dy, k), d2 = __shfl(dz, k);
        const u16x8 kv = *(const u16x8*)(qkv + (size_t)gik * 1024 + 256 + l * 8);
        vus[k] = make_ushort4(kv[4], kv[5], kv[6], kv[7]);
        float h0 = fmaxf(d0 * w0.x + d1 * w1.x + d2 * w2.x + b1.x, 0.0f);
        float h1 = fmaxf(d0 * w0.y + d1 * w1.y + d2 * w2.y + b1.y, 0.0f);
        float h2 = fmaxf(d0 * w0.z + d1 * w1.z + d2 * w2.z + b1.z, 0.0f);
        float h3 = fmaxf(d0 * w0.w + d1 * w1.w + d2 * w2.w + b1.w, 0.0f);
        float t = q4[0] * bf2f(kv[0]) + q4[1] * bf2f(kv[1])
                + q4[2] * bf2f(kv[2]) + q4[3] * bf2f(kv[3])
                + h0 * qp4[0] + h1 * qp4[1] + h2 * qp4[2] + h3 * qp4[3];
#pragma unroll
        for (int off = 1; off < 64; off <<= 1) t += __shfl_xor(t, off);
        lg[k] = t;
    }

    // softmax over 16 (redundant per lane, all registers)
    float att[16];
    {
        float mx = -3.0e38f;
#pragma unroll
        for (int k = 0; k < 16; ++k) {
            att[k] = (lg[k] + qb) * (1.0f / 16.0f);   // / sqrt(DM)
            mx = fmaxf(mx, att[k]);
        }
        float s = 0.0f;
#pragma unroll
        for (int k = 0; k < 16; ++k) { att[k] = __expf(att[k] - mx); s += att[k]; }
        const float inv = 1.0f / s;
#pragma unroll
        for (int k = 0; k < 16; ++k) att[k] *= inv;
    }

    // accumulate rbar = sum att*vf, hbar = sum att*h  (h recomputed)
    float rb[4] = {0, 0, 0, 0}, hb[4] = {0, 0, 0, 0};
#pragma unroll
    for (int k = 0; k < 16; ++k) {
        const float d0 = __shfl(dx, k), d1 = __shfl(dy, k), d2 = __shfl(dz, k);
        const ushort4 vu = vus[k];
        const float a = att[k];
        rb[0] = fmaf(a, bf2f(vu.x), rb[0]);
        rb[1] = fmaf(a, bf2f(vu.y), rb[1]);
        rb[2] = fmaf(a, bf2f(vu.z), rb[2]);
        rb[3] = fmaf(a, bf2f(vu.w), rb[3]);
        hb[0] = fmaf(a, fmaxf(d0 * w0.x + d1 * w1.x + d2 * w2.x + b1.x, 0.0f), hb[0]);
        hb[1] = fmaf(a, fmaxf(d0 * w0.y + d1 * w1.y + d2 * w2.y + b1.y, 0.0f), hb[1]);
        hb[2] = fmaf(a, fmaxf(d0 * w0.z + d1 * w1.z + d2 * w2.z + b1.z, 0.0f), hb[2]);
        hb[3] = fmaf(a, fmaxf(d0 * w0.w + d1 * w1.w + d2 * w2.w + b1.w, 0.0f), hb[3]);
    }

    ushort4 ho, ro;
    ho.x = __bfloat16_as_ushort(__float2bfloat16(hb[0]));
    ho.y = __bfloat16_as_ushort(__float2bfloat16(hb[1]));
    ho.z = __bfloat16_as_ushort(__float2bfloat16(hb[2]));
    ho.w = __bfloat16_as_ushort(__float2bfloat16(hb[3]));
    ro.x = __bfloat16_as_ushort(__float2bfloat16(rb[0]));
    ro.y = __bfloat16_as_ushort(__float2bfloat16(rb[1]));
    ro.z = __bfloat16_as_ushort(__float2bfloat16(rb[2]));
    ro.w = __bfloat16_as_ushort(__float2bfloat16(rb[3]));
    *(ushort4*)(ab + (size_t)p * 512 + c0) = ho;
    *(ushort4*)(ab + (size_t)p * 512 + 256 + c0) = ro;
}

// ---------------- transpose [B*N,DP] -> [B,DP,N] ----------------
__global__ __launch_bounds__(256) void transpose_kernel(const float* __restrict__ in,
                                                        float* __restrict__ out)
{
    __shared__ float t[32][33];
    const int b = blockIdx.z;
    const int n0 = blockIdx.x * 32, d0 = blockIdx.y * 32;
    const int lx = threadIdx.x, ly = threadIdx.y;   // 32 x 8
#pragma unroll
    for (int i = 0; i < 32; i += 8)
        t[ly + i][lx] = in[(size_t)(b * N_ + n0 + ly + i) * DP_ + d0 + lx];
    __syncthreads();
#pragma unroll
    for (int i = 0; i < 32; i += 8)
        out[(size_t)(b * DP_ + d0 + ly + i) * N_ + n0 + lx] = t[lx][ly + i];
}

extern "C" void kernel_launch(void* const* d_in, const int* in_sizes, int n_in,
                              void* d_out, int out_size, void* d_ws, size_t ws_size,
                              hipStream_t stream)
{
    const float* features = (const float*)d_in[0];
    const float* xyz   = (const float*)d_in[1];
    const float* fc1_w = (const float*)d_in[2];
    const float* fc1_b = (const float*)d_in[3];
    const float* fc2_w = (const float*)d_in[4];
    const float* fc2_b = (const float*)d_in[5];
    const float* fd1_w = (const float*)d_in[6];
    const float* fd1_b = (const float*)d_in[7];
    const float* fd2_w = (const float*)d_in[8];
    const float* fd2_b = (const float*)d_in[9];
    const float* wq    = (const float*)d_in[10];
    const float* wk    = (const float*)d_in[11];
    const float* wv    = (const float*)d_in[12];
    float* out = (float*)d_out;

    char* base = (char*)d_ws;
    const size_t MB = 1024 * 1024;
    u32*   part  = (u32*)  (base + 0);                            // 32 MB, dead after merge
    __hip_bfloat16* ab = (__hip_bfloat16*)(base + 0);             // 16 MB [hbar|rbar]
    float* outc  = (float*)(base + 16 * MB);                      // 8 MB
    __hip_bfloat16* qkv   = (__hip_bfloat16*)(base + 36 * MB);    // 32 MB
    __hip_bfloat16* featb = (__hip_bfloat16*)(base + 68 * MB);    // 4 MB
    int*   idx   = (int*)  (base + 72 * MB);                      // 1 MB
    char* wb = base + 73 * MB;
    __hip_bfloat16* catW  = (__hip_bfloat16*)(wb + 0);            // [1024][256] = 512 KB
    __hip_bfloat16* WallT = (__hip_bfloat16*)(wb + 512 * 1024);   // [1024][128] = 256 KB
    __hip_bfloat16* bt2   = (__hip_bfloat16*)(wb + 768 * 1024);   // [128][512]  = 128 KB
    __hip_bfloat16* fd2c  = (__hip_bfloat16*)(wb + 896 * 1024);   // 128 KB
    __hip_bfloat16* wqc   = (__hip_bfloat16*)(wb + 1024 * 1024);  // 128 KB
    __hip_bfloat16* fc1c  = (__hip_bfloat16*)(wb + 1152 * 1024);  // 64 KB
    __hip_bfloat16* fc2T  = (__hip_bfloat16*)(wb + 1216 * 1024);  // 64 KB
    float* b_all = (float*)(wb + 1280 * 1024);                    // 4 KB
    float* bias2 = (float*)(wb + 1284 * 1024);                    // 512 B

    const dim3 blk(256);

    // casts (also seeds bt2 cols [256,512) with fc2^T); k/v rows interleaved in catW
    prep_kernel<<<dim3(8, 8, 8), blk, 0, stream>>>(wq, wk, wv, fd2_w, fc1_w, fc2_w, features,
                                                   catW, fc2T, bt2, fd2c, wqc, fc1c, featb);
    // catW rows 768..1023: Wqp^T[a][b] = sum_j fd2[a][j]*wq[b][j]  (qp = x @ (wq@fd2^T))
    gemm_bf16_kernel<<<dim3(2, 2), blk, 0, stream>>>(
        fd2c, wqc, nullptr, nullptr, nullptr, catW + 768 * 256, DM_, DM_, DM_, DM_);
    // folded biases (needs full catW)
    bias_kernel<<<dim3(5), blk, 0, stream>>>(fc1_b, fd2_b, fc2_w, fc2_b, catW, b_all, bias2);
    // WallT[n][k] = sum_j catW[n][j]*fc1_w[k][j]   (fc1 folded into QKV weight)
    gemm_bf16_kernel<<<dim3(1, 8), blk, 0, stream>>>(
        catW, fc1c, nullptr, nullptr, nullptr, WallT, 1024, DP_, DM_, DP_);
    // bt2 cols [0,256): Wof^T[n][j] = sum_t fc2[t][n]*fd2[j][t]    (fd2@fc2 folded)
    gemm_bf16_kernel<<<dim3(2, 1), blk, 0, stream>>>(
        fc2T, fd2c, nullptr, nullptr, nullptr, bt2, DP_, DM_, DM_, 512);

    // KNN
    knn_part_kernel<<<dim3(N_ / 256, SEG_, B_), blk, 0, stream>>>(xyz, part);
    knn_merge_kernel<<<dim3(NPTS / 64), dim3(64), 0, stream>>>(part, idx);

    // [q | kv-interleaved | qp] = features @ WallT^T + b_all   (fc1 folded, K=128)
    gemm_bf16_kernel<<<dim3(1024 / 128, NPTS / 128), blk, 0, stream>>>(
        featb, WallT, b_all, nullptr, nullptr, qkv, NPTS, 1024, DP_, 1024);

    // fused attention (one wave per point) -> ab = [hbar | rbar]
    attn_kernel<<<dim3(NPTS / 4), blk, 0, stream>>>(xyz, qkv, idx, fd1_w, fd1_b, fd2_b, ab);

    // out = ab @ bt2^T + bias2 + features   (res and fc2 GEMMs merged, K=512)
    gemm_bf16_kernel<<<dim3(1, NPTS / 128), blk, 0, stream>>>(
        ab, bt2, bias2, features, outc, nullptr, NPTS, DP_, 512, DP_);

    // transpose to [B, DP, N]
    transpose_kernel<<<dim3(N_ / 32, DP_ / 32, B_), dim3(32, 8), 0, stream>>>(outc, out);

    (void)in_sizes; (void)n_in; (void)out_size; (void)ws_size;
}

// Round 9
// 299.583 us; speedup vs baseline: 13.8185x; 1.0778x over previous
//
#include <hip/hip_runtime.h>
#include <hip/hip_bf16.h>
#include <math.h>

#define B_   4
#define N_   4096
#define K_   16
#define DP_  128
#define DM_  256
#define NPTS (B_ * N_)
#define SEG_ 32
#define CAND_ (N_ / SEG_)   // 128 candidates per segment

typedef unsigned int u32;
typedef unsigned short u16;
typedef _Float16 f16;
typedef __attribute__((ext_vector_type(2))) __fp16 h2;     // matches cvt_pkrtz/fdot2 ABI
typedef __attribute__((ext_vector_type(8))) _Float16 f16x8; // MFMA operand
typedef __attribute__((ext_vector_type(4))) float floatx4;

static __device__ __forceinline__ h2 pkrtz(float a, float b) {
    return __builtin_amdgcn_cvt_pkrtz(a, b);
}
static __device__ __forceinline__ u32 asu32(h2 h) { return __builtin_bit_cast(u32, h); }
static __device__ __forceinline__ h2 ash2(u32 u) { return __builtin_bit_cast(h2, u); }

// ---- bitonic primitives on u32 registers ----
#define CEXA(x, y) { u32 _lo = min(x, y); y = max(x, y); x = _lo; }   // x<=y
#define CEXD(x, y) { u32 _hi = max(x, y); y = min(x, y); x = _hi; }   // x>=y

// full bitonic sort of 16, DESCENDING; 80 CEX
static __device__ __forceinline__ void sort16_desc(u32 c[16]) {
    CEXD(c[0],c[1]);  CEXA(c[2],c[3]);  CEXD(c[4],c[5]);  CEXA(c[6],c[7]);
    CEXD(c[8],c[9]);  CEXA(c[10],c[11]); CEXD(c[12],c[13]); CEXA(c[14],c[15]);

    CEXD(c[0],c[2]);  CEXD(c[1],c[3]);  CEXA(c[4],c[6]);  CEXA(c[5],c[7]);
    CEXD(c[8],c[10]); CEXD(c[9],c[11]); CEXA(c[12],c[14]); CEXA(c[13],c[15]);
    CEXD(c[0],c[1]);  CEXD(c[2],c[3]);  CEXA(c[4],c[5]);  CEXA(c[6],c[7]);
    CEXD(c[8],c[9]);  CEXD(c[10],c[11]); CEXA(c[12],c[13]); CEXA(c[14],c[15]);

    CEXD(c[0],c[4]);  CEXD(c[1],c[5]);  CEXD(c[2],c[6]);  CEXD(c[3],c[7]);
    CEXA(c[8],c[12]); CEXA(c[9],c[13]); CEXA(c[10],c[14]); CEXA(c[11],c[15]);
    CEXD(c[0],c[2]);  CEXD(c[1],c[3]);  CEXD(c[4],c[6]);  CEXD(c[5],c[7]);
    CEXA(c[8],c[10]); CEXA(c[9],c[11]); CEXA(c[12],c[14]); CEXA(c[13],c[15]);
    CEXD(c[0],c[1]);  CEXD(c[2],c[3]);  CEXD(c[4],c[5]);  CEXD(c[6],c[7]);
    CEXA(c[8],c[9]);  CEXA(c[10],c[11]); CEXA(c[12],c[13]); CEXA(c[14],c[15]);

    CEXD(c[0],c[8]);  CEXD(c[1],c[9]);  CEXD(c[2],c[10]); CEXD(c[3],c[11]);
    CEXD(c[4],c[12]); CEXD(c[5],c[13]); CEXD(c[6],c[14]); CEXD(c[7],c[15]);
    CEXD(c[0],c[4]);  CEXD(c[1],c[5]);  CEXD(c[2],c[6]);  CEXD(c[3],c[7]);
    CEXD(c[8],c[12]); CEXD(c[9],c[13]); CEXD(c[10],c[14]); CEXD(c[11],c[15]);
    CEXD(c[0],c[2]);  CEXD(c[1],c[3]);  CEXD(c[4],c[6]);  CEXD(c[5],c[7]);
    CEXD(c[8],c[10]); CEXD(c[9],c[11]); CEXD(c[12],c[14]); CEXD(c[13],c[15]);
    CEXD(c[0],c[1]);  CEXD(c[2],c[3]);  CEXD(c[4],c[5]);  CEXD(c[6],c[7]);
    CEXD(c[8],c[9]);  CEXD(c[10],c[11]); CEXD(c[12],c[13]); CEXD(c[14],c[15]);
}

// L is bitonic -> sort ascending; 32 CEX
static __device__ __forceinline__ void remerge16_asc(u32 L[16]) {
    CEXA(L[0],L[8]);  CEXA(L[1],L[9]);  CEXA(L[2],L[10]); CEXA(L[3],L[11]);
    CEXA(L[4],L[12]); CEXA(L[5],L[13]); CEXA(L[6],L[14]); CEXA(L[7],L[15]);
    CEXA(L[0],L[4]);  CEXA(L[1],L[5]);  CEXA(L[2],L[6]);  CEXA(L[3],L[7]);
    CEXA(L[8],L[12]); CEXA(L[9],L[13]); CEXA(L[10],L[14]); CEXA(L[11],L[15]);
    CEXA(L[0],L[2]);  CEXA(L[1],L[3]);  CEXA(L[4],L[6]);  CEXA(L[5],L[7]);
    CEXA(L[8],L[10]); CEXA(L[9],L[11]); CEXA(L[12],L[14]); CEXA(L[13],L[15]);
    CEXA(L[0],L[1]);  CEXA(L[2],L[3]);  CEXA(L[4],L[5]);  CEXA(L[6],L[7]);
    CEXA(L[8],L[9]);  CEXA(L[10],L[11]); CEXA(L[12],L[13]); CEXA(L[14],L[15]);
}

// ---------------- KNN phase 1 (unchanged from round 7) ----------------
__global__ __launch_bounds__(256, 1) void knn_part_kernel(const float* __restrict__ xyz,
                                                          u32* __restrict__ part)
{
    const int b = blockIdx.z;
    const int s = blockIdx.y;
    const int n = blockIdx.x * 256 + threadIdx.x;
    const float* xb = xyz + (size_t)b * N_ * 3;
    const float xn0 = xb[n * 3 + 0], xn1 = xb[n * 3 + 1], xn2 = xb[n * 3 + 2];
    const float sqn = xn0 * xn0 + xn1 * xn1 + xn2 * xn2;

    __shared__ float4 sc[CAND_];
    if (threadIdx.x < CAND_) {
        const int m = s * CAND_ + threadIdx.x;
        const float a0 = xb[m * 3 + 0];
        const float a1 = xb[m * 3 + 1];
        const float a2 = xb[m * 3 + 2];
        sc[threadIdx.x] = make_float4(a0, a1, a2, a0 * a0 + a1 * a1 + a2 * a2);
    }
    __syncthreads();

    u32 L[16];
#pragma unroll
    for (int i = 0; i < 16; ++i) L[i] = 0xFFFFFFFFu;

    const u32 ibase = (u32)(s * CAND_);
    for (int m0 = 0; m0 < CAND_; m0 += 16) {
        u32 c[16];
#pragma unroll
        for (int t = 0; t < 16; ++t) {
            const float4 cc = sc[m0 + t];
            const float dot = xn0 * cc.x + xn1 * cc.y + xn2 * cc.z;
            const float d = (sqn + cc.w) - 2.0f * dot;
            const int ib = __float_as_int(d);
            const u32 tk = (u32)ib ^ (u32)((ib >> 31) | 0x80000000);
            c[t] = (tk & 0xFFFFF000u) | (ibase + (u32)(m0 + t));
        }
        sort16_desc(c);
#pragma unroll
        for (int i = 0; i < 16; ++i) L[i] = min(L[i], c[i]);
        remerge16_asc(L);
    }

    const int p = b * N_ + n;
#pragma unroll
    for (int j = 0; j < 16; ++j)
        part[(size_t)(s * 16 + j) * NPTS + p] = L[j];
}

// ---------------- KNN merge (unchanged) ----------------
__global__ __launch_bounds__(64, 1) void knn_merge_kernel(const u32* __restrict__ part,
                                                          int* __restrict__ knn_idx)
{
    const int p = blockIdx.x * 64 + threadIdx.x;
    const int b = p >> 12;

    u32 L[16];
#pragma unroll
    for (int i = 0; i < 16; ++i) L[i] = 0xFFFFFFFFu;

    for (int s = 0; s < SEG_; ++s) {
        u32 seg[16];
#pragma unroll
        for (int j = 0; j < 16; ++j)
            seg[j] = part[(size_t)(s * 16 + j) * NPTS + p];
#pragma unroll
        for (int i = 0; i < 16; ++i) L[i] = min(L[i], seg[15 - i]);
        remerge16_asc(L);
    }

    int* o = knn_idx + (size_t)p * K_;
#pragma unroll
    for (int i = 0; i < 16; ++i) o[i] = b * N_ + (int)(L[i] & 0xFFFu);
}

// ---------------- f16 MFMA GEMM: C[M,N] = A[M,K] @ Bt[N,K]^T (+bias +addC) ----------------
// CT != null: store TRANSPOSED to [B][DP][N] fp32 (fused output transpose).
__global__ __launch_bounds__(256) void gemm_f16_kernel(
    const f16* __restrict__ A,     // [M][K]
    const f16* __restrict__ Bt,    // [N][K]
    const float* __restrict__ bias,
    const float* __restrict__ addC,   // fp32, row stride ldc
    float* __restrict__ CT,        // transposed fp32 out [B][DP][N], or null
    f16* __restrict__ Cb,          // f16 out, row stride ldc, or null
    int M, int N, int K, int ldc)
{
    __shared__ __align__(16) f16 As[128 * 32];
    __shared__ __align__(16) f16 Bs[128 * 32];
    const int tid = threadIdx.x;
    const int m0 = blockIdx.y * 128, n0 = blockIdx.x * 128;
    const int w = tid >> 6, l = tid & 63;
    const int wm = (w >> 1) * 64, wn = (w & 1) * 64;
    const int fm = l & 15, kq = l >> 4;

    floatx4 acc[4][4];
#pragma unroll
    for (int i = 0; i < 4; ++i)
#pragma unroll
        for (int j = 0; j < 4; ++j)
            acc[i][j] = (floatx4){0.0f, 0.0f, 0.0f, 0.0f};

    for (int k0 = 0; k0 < K; k0 += 32) {
        __syncthreads();
#pragma unroll
        for (int c = 0; c < 2; ++c) {
            const int li = tid + c * 256;
            const int row = li >> 2, part = li & 3;
            *(uint4*)&As[row * 32 + part * 8] =
                *(const uint4*)&A[(size_t)(m0 + row) * K + k0 + part * 8];
            *(uint4*)&Bs[row * 32 + part * 8] =
                *(const uint4*)&Bt[(size_t)(n0 + row) * K + k0 + part * 8];
        }
        __syncthreads();
        f16x8 af[4], bf[4];
#pragma unroll
        for (int i = 0; i < 4; ++i)
            af[i] = *(const f16x8*)&As[(wm + i * 16 + fm) * 32 + kq * 8];
#pragma unroll
        for (int j = 0; j < 4; ++j)
            bf[j] = *(const f16x8*)&Bs[(wn + j * 16 + fm) * 32 + kq * 8];
#pragma unroll
        for (int i = 0; i < 4; ++i)
#pragma unroll
            for (int j = 0; j < 4; ++j)
                acc[i][j] = __builtin_amdgcn_mfma_f32_16x16x32_f16(af[i], bf[j], acc[i][j], 0, 0, 0);
    }

#pragma unroll
    for (int i = 0; i < 4; ++i) {
#pragma unroll
        for (int j = 0; j < 4; ++j) {
            const int col = n0 + wn + j * 16 + fm;
            const int rowb = m0 + wm + i * 16 + kq * 4;
            float4 vv;
#pragma unroll
            for (int r = 0; r < 4; ++r) {
                const int m = rowb + r;
                float v = acc[i][j][r];
                if (bias) v += bias[col];
                if (addC) v += addC[(size_t)m * ldc + col];
                ((float*)&vv)[r] = v;
            }
            if (CT) {   // rows rowb..rowb+3 are consecutive n within one batch
                const int bb = rowb >> 12;
                *(float4*)&CT[(size_t)(bb * DP_ + col) * N_ + (rowb & (N_ - 1))] = vv;
            } else if (Cb) {
#pragma unroll
                for (int r = 0; r < 4; ++r)
                    Cb[(size_t)(rowb + r) * ldc + col] = (f16)((float*)&vv)[r];
            }
        }
    }
}

// ---------------- one-shot prep: weight transpose-casts + straight casts (f16) ----------------
// k/v rows of catW INTERLEAVED: k-col c -> row 256+8*(c/4)+(c%4); v-col c -> +4.
__global__ __launch_bounds__(256) void prep_kernel(
    const float* __restrict__ wq, const float* __restrict__ wk, const float* __restrict__ wv,
    const float* __restrict__ fd2, const float* __restrict__ fc1, const float* __restrict__ fc2,
    const float* __restrict__ feat,
    f16* __restrict__ catW, f16* __restrict__ fc2T, f16* __restrict__ bt2,
    f16* __restrict__ fd2c, f16* __restrict__ wqc, f16* __restrict__ fc1c,
    f16* __restrict__ featb)
{
    __shared__ float t[32][33];
    const int job = blockIdx.z;
    const int tid = threadIdx.x;

    if (job < 4) {
        const float* in; int R, C;
        switch (job) {
            case 0: in = wq;  R = DM_; C = DM_; break;
            case 1: in = wk;  R = DM_; C = DM_; break;
            case 2: in = wv;  R = DM_; C = DM_; break;
            default: in = fc2; R = DM_; C = DP_; break;
        }
        const int c0 = blockIdx.x * 32, r0 = blockIdx.y * 32;
        if (c0 >= C || r0 >= R) return;
        const int lx = tid & 31, ly = tid >> 5;
#pragma unroll
        for (int i = 0; i < 32; i += 8)
            t[ly + i][lx] = in[(size_t)(r0 + ly + i) * C + c0 + lx];
        __syncthreads();
#pragma unroll
        for (int i = 0; i < 32; i += 8) {
            const int c = c0 + ly + i;
            const f16 v = (f16)t[lx][ly + i];
            int n;
            switch (job) {
                case 0: n = c; break;
                case 1: n = 256 + ((c >> 2) << 3) + (c & 3); break;
                case 2: n = 256 + ((c >> 2) << 3) + 4 + (c & 3); break;
                default: n = -1; break;
            }
            if (job < 3) {
                catW[(size_t)n * DM_ + r0 + lx] = v;
            } else {
                fc2T[(size_t)c * DM_ + r0 + lx] = v;
                bt2[(size_t)c * 512 + 256 + r0 + lx] = v;
            }
        }
    } else {
        const int bid = blockIdx.y * 8 + blockIdx.x;
        const int tId = bid * 256 + tid;
        const float* in; f16* outp; int n4;
        if (job == 4)      { in = fd2;  outp = fd2c;  n4 = (DM_ * DM_) / 4; }
        else if (job == 5) { in = wq;   outp = wqc;   n4 = (DM_ * DM_) / 4; }
        else if (job == 6) { in = fc1;  outp = fc1c;  n4 = (DP_ * DM_) / 4; }
        else               { in = feat; outp = featb; n4 = (NPTS * DP_) / 4; }
        for (int i = tId; i < n4; i += 16384) {
            const float4 v = ((const float4*)in)[i];
            const u32 lo = asu32(pkrtz(v.x, v.y));
            const u32 hi = asu32(pkrtz(v.z, v.w));
            ((uint2*)outp)[i] = make_uint2(lo, hi);
        }
    }
}

// ---------------- folded bias vectors ----------------
__global__ __launch_bounds__(256) void bias_kernel(
    const float* __restrict__ fc1_b, const float* __restrict__ fd2_b,
    const float* __restrict__ fc2_w, const float* __restrict__ fc2_b,
    const f16* __restrict__ catW,
    float* __restrict__ b_all, float* __restrict__ bias2)
{
    const int tid = threadIdx.x;
    if (blockIdx.x < 4) {
        const int n = blockIdx.x * 256 + tid;
        float s = 0.0f;
        for (int j = 0; j < DM_; ++j)
            s += fc1_b[j] * (float)catW[(size_t)n * DM_ + j];
        b_all[n] = s;
    } else if (tid < DP_) {
        float s = fc2_b[tid];
        for (int t = 0; t < DM_; ++t)
            s += fd2_b[t] * fc2_w[(size_t)t * DP_ + tid];
        bias2[tid] = s;
    }
}

// ---------------- fused attention: one WAVE per point, f16 dot2, h cached in regs ----------------
// qkv row p (stride 1024 f16): [0,256)=q, [256,768)=interleaved {k[4c..],v[4c..]} octets,
// [768,1024)=qp.  Lane l owns dims 4l..4l+3.
__global__ __launch_bounds__(256) void attn_kernel(
    const float* __restrict__ xyz, const f16* __restrict__ qkv,
    const int* __restrict__ knn_idx,
    const float* __restrict__ fd1_w, const float* __restrict__ fd1_b,
    const float* __restrict__ fd2_b,
    f16* __restrict__ ab)
{
    const int wave = threadIdx.x >> 6, l = threadIdx.x & 63;
    const int p = blockIdx.x * 4 + wave;
    const int c0 = l * 4;

    const uint2 qu  = *(const uint2*)(qkv + (size_t)p * 1024 + c0);
    const uint2 qpu = *(const uint2*)(qkv + (size_t)p * 1024 + 768 + c0);
    const h2 q01 = ash2(qu.x), q23 = ash2(qu.y);
    const h2 qp01 = ash2(qpu.x), qp23 = ash2(qpu.y);

    const float4 w0 = *(const float4*)&fd1_w[c0];
    const float4 w1 = *(const float4*)&fd1_w[DM_ + c0];
    const float4 w2 = *(const float4*)&fd1_w[2 * DM_ + c0];
    const float4 b1 = *(const float4*)&fd1_b[c0];
    const float4 f2b = *(const float4*)&fd2_b[c0];
    const h2 f2b01 = pkrtz(f2b.x, f2b.y);
    const h2 f2b23 = pkrtz(f2b.z, f2b.w);

    int gi = 0; float dx = 0.0f, dy = 0.0f, dz = 0.0f;
    if (l < 16) {
        gi = knn_idx[p * K_ + l];
        dx = xyz[(size_t)p * 3 + 0] - xyz[(size_t)gi * 3 + 0];
        dy = xyz[(size_t)p * 3 + 1] - xyz[(size_t)gi * 3 + 1];
        dz = xyz[(size_t)p * 3 + 2] - xyz[(size_t)gi * 3 + 2];
    }

    // qb = q . fd2_b (constant over k)
    float qb;
    {
        float tq = __builtin_amdgcn_fdot2(q01, f2b01, 0.0f, false);
        tq = __builtin_amdgcn_fdot2(q23, f2b23, tq, false);
#pragma unroll
        for (int off = 1; off < 64; off <<= 1) tq += __shfl_xor(tq, off);
        qb = tq;
    }

    // phase 1: logits via f16 dot2; h packed to f16 and kept for phase 2
    float lg[16];
    u32 h01r[16], h23r[16];
#pragma unroll
    for (int k = 0; k < 16; ++k) {
        const int gik = __shfl(gi, k);
        const float d0 = __shfl(dx, k), d1 = __shfl(dy, k), d2 = __shfl(dz, k);
        const uint2 ku = *(const uint2*)(qkv + (size_t)gik * 1024 + 256 + l * 8);
        const float h0 = fmaxf(d0 * w0.x + d1 * w1.x + d2 * w2.x + b1.x, 0.0f);
        const float h1 = fmaxf(d0 * w0.y + d1 * w1.y + d2 * w2.y + b1.y, 0.0f);
        const float h2v = fmaxf(d0 * w0.z + d1 * w1.z + d2 * w2.z + b1.z, 0.0f);
        const float h3 = fmaxf(d0 * w0.w + d1 * w1.w + d2 * w2.w + b1.w, 0.0f);
        const h2 hp01 = pkrtz(h0, h1);
        const h2 hp23 = pkrtz(h2v, h3);
        h01r[k] = asu32(hp01); h23r[k] = asu32(hp23);
        float t = __builtin_amdgcn_fdot2(ash2(ku.x), q01, 0.0f, false);
        t = __builtin_amdgcn_fdot2(ash2(ku.y), q23, t, false);
        t = __builtin_amdgcn_fdot2(hp01, qp01, t, false);
        t = __builtin_amdgcn_fdot2(hp23, qp23, t, false);
#pragma unroll
        for (int off = 1; off < 64; off <<= 1) t += __shfl_xor(t, off);
        lg[k] = t;
    }

    // softmax over 16 (redundant per lane, all registers)
    float att[16];
    {
        float mx = -3.0e38f;
#pragma unroll
        for (int k = 0; k < 16; ++k) {
            att[k] = (lg[k] + qb) * (1.0f / 16.0f);
            mx = fmaxf(mx, att[k]);
        }
        float s = 0.0f;
#pragma unroll
        for (int k = 0; k < 16; ++k) { att[k] = __expf(att[k] - mx); s += att[k]; }
        const float inv = 1.0f / s;
#pragma unroll
        for (int k = 0; k < 16; ++k) att[k] *= inv;
    }

    // phase 2: rbar = sum att*v (fresh 8B v-half gathers), hbar = sum att*h (from regs)
    float rb[4] = {0, 0, 0, 0}, hb[4] = {0, 0, 0, 0};
#pragma unroll
    for (int k = 0; k < 16; ++k) {
        const int gik = __shfl(gi, k);
        const uint2 vu = *(const uint2*)(qkv + (size_t)gik * 1024 + 256 + l * 8 + 4);
        const h2 v01 = ash2(vu.x), v23 = ash2(vu.y);
        const h2 hh01 = ash2(h01r[k]), hh23 = ash2(h23r[k]);
        const float a = att[k];
        rb[0] = fmaf(a, (float)v01.x, rb[0]);
        rb[1] = fmaf(a, (float)v01.y, rb[1]);
        rb[2] = fmaf(a, (float)v23.x, rb[2]);
        rb[3] = fmaf(a, (float)v23.y, rb[3]);
        hb[0] = fmaf(a, (float)hh01.x, hb[0]);
        hb[1] = fmaf(a, (float)hh01.y, hb[1]);
        hb[2] = fmaf(a, (float)hh23.x, hb[2]);
        hb[3] = fmaf(a, (float)hh23.y, hb[3]);
    }

    const uint2 ho = make_uint2(asu32(pkrtz(hb[0], hb[1])), asu32(pkrtz(hb[2], hb[3])));
    const uint2 ro = make_uint2(asu32(pkrtz(rb[0], rb[1])), asu32(pkrtz(rb[2], rb[3])));
    *(uint2*)(ab + (size_t)p * 512 + c0) = ho;
    *(uint2*)(ab + (size_t)p * 512 + 256 + c0) = ro;
}

extern "C" void kernel_launch(void* const* d_in, const int* in_sizes, int n_in,
                              void* d_out, int out_size, void* d_ws, size_t ws_size,
                              hipStream_t stream)
{
    const float* features = (const float*)d_in[0];
    const float* xyz   = (const float*)d_in[1];
    const float* fc1_w = (const float*)d_in[2];
    const float* fc1_b = (const float*)d_in[3];
    const float* fc2_w = (const float*)d_in[4];
    const float* fc2_b = (const float*)d_in[5];
    const float* fd1_w = (const float*)d_in[6];
    const float* fd1_b = (const float*)d_in[7];
    const float* fd2_w = (const float*)d_in[8];
    const float* fd2_b = (const float*)d_in[9];
    const float* wq    = (const float*)d_in[10];
    const float* wk    = (const float*)d_in[11];
    const float* wv    = (const float*)d_in[12];
    float* out = (float*)d_out;

    char* base = (char*)d_ws;
    const size_t MB = 1024 * 1024;
    u32*  part = (u32*)(base + 0);                 // 32 MB, dead after merge
    f16*  ab   = (f16*)(base + 0);                 // 16 MB [hbar|rbar]
    f16*  qkv  = (f16*)(base + 36 * MB);           // 32 MB
    f16*  featb = (f16*)(base + 68 * MB);          // 4 MB
    int*  idx  = (int*)(base + 72 * MB);           // 1 MB
    char* wb = base + 73 * MB;
    f16* catW  = (f16*)(wb + 0);                   // [1024][256] = 512 KB
    f16* WallT = (f16*)(wb + 512 * 1024);          // [1024][128] = 256 KB
    f16* bt2   = (f16*)(wb + 768 * 1024);          // [128][512]  = 128 KB
    f16* fd2c  = (f16*)(wb + 896 * 1024);
    f16* wqc   = (f16*)(wb + 1024 * 1024);
    f16* fc1c  = (f16*)(wb + 1152 * 1024);
    f16* fc2T  = (f16*)(wb + 1216 * 1024);
    float* b_all = (float*)(wb + 1280 * 1024);
    float* bias2 = (float*)(wb + 1284 * 1024);

    const dim3 blk(256);

    // casts (also seeds bt2 cols [256,512) with fc2^T); k/v rows interleaved in catW
    prep_kernel<<<dim3(8, 8, 8), blk, 0, stream>>>(wq, wk, wv, fd2_w, fc1_w, fc2_w, features,
                                                   catW, fc2T, bt2, fd2c, wqc, fc1c, featb);
    // catW rows 768..1023: Wqp^T[a][b] = sum_j fd2[a][j]*wq[b][j]
    gemm_f16_kernel<<<dim3(2, 2), blk, 0, stream>>>(
        fd2c, wqc, nullptr, nullptr, nullptr, catW + 768 * 256, DM_, DM_, DM_, DM_);
    // folded biases
    bias_kernel<<<dim3(5), blk, 0, stream>>>(fc1_b, fd2_b, fc2_w, fc2_b, catW, b_all, bias2);
    // WallT[n][k] = sum_j catW[n][j]*fc1_w[k][j]
    gemm_f16_kernel<<<dim3(1, 8), blk, 0, stream>>>(
        catW, fc1c, nullptr, nullptr, nullptr, WallT, 1024, DP_, DM_, DP_);
    // bt2 cols [0,256): Wof^T[n][j] = sum_t fc2[t][n]*fd2[j][t]
    gemm_f16_kernel<<<dim3(2, 1), blk, 0, stream>>>(
        fc2T, fd2c, nullptr, nullptr, nullptr, bt2, DP_, DM_, DM_, 512);

    // KNN
    knn_part_kernel<<<dim3(N_ / 256, SEG_, B_), blk, 0, stream>>>(xyz, part);
    knn_merge_kernel<<<dim3(NPTS / 64), dim3(64), 0, stream>>>(part, idx);

    // [q | kv-interleaved | qp] = features @ WallT^T + b_all
    gemm_f16_kernel<<<dim3(1024 / 128, NPTS / 128), blk, 0, stream>>>(
        featb, WallT, b_all, nullptr, nullptr, qkv, NPTS, 1024, DP_, 1024);

    // fused attention -> ab = [hbar | rbar]
    attn_kernel<<<dim3(NPTS / 4), blk, 0, stream>>>(xyz, qkv, idx, fd1_w, fd1_b, fd2_b, ab);

    // out = ab @ bt2^T + bias2 + features, stored TRANSPOSED directly to d_out
    gemm_f16_kernel<<<dim3(1, NPTS / 128), blk, 0, stream>>>(
        ab, bt2, bias2, features, out, nullptr, NPTS, DP_, 512, DP_);

    (void)in_sizes; (void)n_in; (void)out_size; (void)ws_size;
}

// Round 10
// 287.909 us; speedup vs baseline: 14.3789x; 1.0405x over previous
//
#include <hip/hip_runtime.h>
#include <hip/hip_bf16.h>
#include <math.h>

#define B_   4
#define N_   4096
#define K_   16
#define DP_  128
#define DM_  256
#define NPTS (B_ * N_)
#define SEG_ 16
#define CAND_ (N_ / SEG_)   // 256 candidates per segment

typedef unsigned int u32;
typedef unsigned short u16;
typedef _Float16 f16;
typedef __attribute__((ext_vector_type(2))) __fp16 h2;     // matches cvt_pkrtz/fdot2 ABI
typedef __attribute__((ext_vector_type(8))) _Float16 f16x8; // MFMA operand
typedef __attribute__((ext_vector_type(4))) float floatx4;

static __device__ __forceinline__ h2 pkrtz(float a, float b) {
    return __builtin_amdgcn_cvt_pkrtz(a, b);
}
static __device__ __forceinline__ u32 asu32(h2 h) { return __builtin_bit_cast(u32, h); }
static __device__ __forceinline__ h2 ash2(u32 u) { return __builtin_bit_cast(h2, u); }

// ---- bitonic primitives on u32 registers ----
#define CEXA(x, y) { u32 _lo = min(x, y); y = max(x, y); x = _lo; }   // x<=y
#define CEXD(x, y) { u32 _hi = max(x, y); y = min(x, y); x = _hi; }   // x>=y

// full bitonic sort of 16, DESCENDING; 80 CEX
static __device__ __forceinline__ void sort16_desc(u32 c[16]) {
    CEXD(c[0],c[1]);  CEXA(c[2],c[3]);  CEXD(c[4],c[5]);  CEXA(c[6],c[7]);
    CEXD(c[8],c[9]);  CEXA(c[10],c[11]); CEXD(c[12],c[13]); CEXA(c[14],c[15]);

    CEXD(c[0],c[2]);  CEXD(c[1],c[3]);  CEXA(c[4],c[6]);  CEXA(c[5],c[7]);
    CEXD(c[8],c[10]); CEXD(c[9],c[11]); CEXA(c[12],c[14]); CEXA(c[13],c[15]);
    CEXD(c[0],c[1]);  CEXD(c[2],c[3]);  CEXA(c[4],c[5]);  CEXA(c[6],c[7]);
    CEXD(c[8],c[9]);  CEXD(c[10],c[11]); CEXA(c[12],c[13]); CEXA(c[14],c[15]);

    CEXD(c[0],c[4]);  CEXD(c[1],c[5]);  CEXD(c[2],c[6]);  CEXD(c[3],c[7]);
    CEXA(c[8],c[12]); CEXA(c[9],c[13]); CEXA(c[10],c[14]); CEXA(c[11],c[15]);
    CEXD(c[0],c[2]);  CEXD(c[1],c[3]);  CEXD(c[4],c[6]);  CEXD(c[5],c[7]);
    CEXA(c[8],c[10]); CEXA(c[9],c[11]); CEXA(c[12],c[14]); CEXA(c[13],c[15]);
    CEXD(c[0],c[1]);  CEXD(c[2],c[3]);  CEXD(c[4],c[5]);  CEXD(c[6],c[7]);
    CEXA(c[8],c[9]);  CEXA(c[10],c[11]); CEXA(c[12],c[13]); CEXA(c[14],c[15]);

    CEXD(c[0],c[8]);  CEXD(c[1],c[9]);  CEXD(c[2],c[10]); CEXD(c[3],c[11]);
    CEXD(c[4],c[12]); CEXD(c[5],c[13]); CEXD(c[6],c[14]); CEXD(c[7],c[15]);
    CEXD(c[0],c[4]);  CEXD(c[1],c[5]);  CEXD(c[2],c[6]);  CEXD(c[3],c[7]);
    CEXD(c[8],c[12]); CEXD(c[9],c[13]); CEXD(c[10],c[14]); CEXD(c[11],c[15]);
    CEXD(c[0],c[2]);  CEXD(c[1],c[3]);  CEXD(c[4],c[6]);  CEXD(c[5],c[7]);
    CEXD(c[8],c[10]); CEXD(c[9],c[11]); CEXD(c[12],c[14]); CEXD(c[13],c[15]);
    CEXD(c[0],c[1]);  CEXD(c[2],c[3]);  CEXD(c[4],c[5]);  CEXD(c[6],c[7]);
    CEXD(c[8],c[9]);  CEXD(c[10],c[11]); CEXD(c[12],c[13]); CEXD(c[14],c[15]);
}

// L is bitonic -> sort ascending; 32 CEX
static __device__ __forceinline__ void remerge16_asc(u32 L[16]) {
    CEXA(L[0],L[8]);  CEXA(L[1],L[9]);  CEXA(L[2],L[10]); CEXA(L[3],L[11]);
    CEXA(L[4],L[12]); CEXA(L[5],L[13]); CEXA(L[6],L[14]); CEXA(L[7],L[15]);
    CEXA(L[0],L[4]);  CEXA(L[1],L[5]);  CEXA(L[2],L[6]);  CEXA(L[3],L[7]);
    CEXA(L[8],L[12]); CEXA(L[9],L[13]); CEXA(L[10],L[14]); CEXA(L[11],L[15]);
    CEXA(L[0],L[2]);  CEXA(L[1],L[3]);  CEXA(L[4],L[6]);  CEXA(L[5],L[7]);
    CEXA(L[8],L[10]); CEXA(L[9],L[11]); CEXA(L[12],L[14]); CEXA(L[13],L[15]);
    CEXA(L[0],L[1]);  CEXA(L[2],L[3]);  CEXA(L[4],L[5]);  CEXA(L[6],L[7]);
    CEXA(L[8],L[9]);  CEXA(L[10],L[11]); CEXA(L[12],L[13]); CEXA(L[14],L[15]);
}

// ---------------- KNN phase 1: bitonic-batch top-16 per (point, segment) ----------------
__global__ __launch_bounds__(256, 1) void knn_part_kernel(const float* __restrict__ xyz,
                                                          u32* __restrict__ part)
{
    const int b = blockIdx.z;
    const int s = blockIdx.y;
    const int n = blockIdx.x * 256 + threadIdx.x;
    const float* xb = xyz + (size_t)b * N_ * 3;
    const float xn0 = xb[n * 3 + 0], xn1 = xb[n * 3 + 1], xn2 = xb[n * 3 + 2];
    const float sqn = xn0 * xn0 + xn1 * xn1 + xn2 * xn2;

    __shared__ float4 sc[CAND_];
    {
        const int m = s * CAND_ + threadIdx.x;   // CAND_ == 256 == blockDim.x
        const float a0 = xb[m * 3 + 0];
        const float a1 = xb[m * 3 + 1];
        const float a2 = xb[m * 3 + 2];
        sc[threadIdx.x] = make_float4(a0, a1, a2, a0 * a0 + a1 * a1 + a2 * a2);
    }
    __syncthreads();

    u32 L[16];
#pragma unroll
    for (int i = 0; i < 16; ++i) L[i] = 0xFFFFFFFFu;

    const u32 ibase = (u32)(s * CAND_);
    for (int m0 = 0; m0 < CAND_; m0 += 16) {
        u32 c[16];
#pragma unroll
        for (int t = 0; t < 16; ++t) {
            const float4 cc = sc[m0 + t];
            const float dot = xn0 * cc.x + xn1 * cc.y + xn2 * cc.z;
            const float d = (sqn + cc.w) - 2.0f * dot;
            const int ib = __float_as_int(d);
            const u32 tk = (u32)ib ^ (u32)((ib >> 31) | 0x80000000);
            c[t] = (tk & 0xFFFFF000u) | (ibase + (u32)(m0 + t));
        }
        sort16_desc(c);
#pragma unroll
        for (int i = 0; i < 16; ++i) L[i] = min(L[i], c[i]);
        remerge16_asc(L);
    }

    const int p = b * N_ + n;
#pragma unroll
    for (int j = 0; j < 16; ++j)
        part[(size_t)(s * 16 + j) * NPTS + p] = L[j];
}

// ---------------- KNN merge stage A: 4 segments -> 1 sorted list (x4 groups) ----------------
__global__ __launch_bounds__(256, 1) void knn_mergeA_kernel(const u32* __restrict__ part,
                                                            u32* __restrict__ m4)
{
    const int g = blockIdx.y;                                // group 0..3
    const int p = blockIdx.x * 256 + threadIdx.x;            // global point id

    u32 L[16];
#pragma unroll
    for (int i = 0; i < 16; ++i) L[i] = 0xFFFFFFFFu;

    for (int s = g * 4; s < g * 4 + 4; ++s) {
        u32 seg[16];
#pragma unroll
        for (int j = 0; j < 16; ++j)
            seg[j] = part[(size_t)(s * 16 + j) * NPTS + p];
#pragma unroll
        for (int i = 0; i < 16; ++i) L[i] = min(L[i], seg[15 - i]);
        remerge16_asc(L);
    }
#pragma unroll
    for (int j = 0; j < 16; ++j)
        m4[(size_t)(g * 16 + j) * NPTS + p] = L[j];
}

// ---------------- KNN merge stage B: 4 sorted lists -> final top-16 indices ----------------
__global__ __launch_bounds__(256, 1) void knn_mergeB_kernel(const u32* __restrict__ m4,
                                                            int* __restrict__ knn_idx)
{
    const int p = blockIdx.x * 256 + threadIdx.x;
    const int b = p >> 12;

    u32 L[16];
#pragma unroll
    for (int i = 0; i < 16; ++i) L[i] = 0xFFFFFFFFu;

    for (int g = 0; g < 4; ++g) {
        u32 seg[16];
#pragma unroll
        for (int j = 0; j < 16; ++j)
            seg[j] = m4[(size_t)(g * 16 + j) * NPTS + p];
#pragma unroll
        for (int i = 0; i < 16; ++i) L[i] = min(L[i], seg[15 - i]);
        remerge16_asc(L);
    }

    int* o = knn_idx + (size_t)p * K_;
#pragma unroll
    for (int i = 0; i < 16; ++i) o[i] = b * N_ + (int)(L[i] & 0xFFFu);
}

// ---------------- f16 MFMA GEMM: C[M,N] = A[M,K] @ Bt[N,K]^T (+bias +addC) ----------------
// CT != null: store TRANSPOSED to [B][DP][N] fp32 (fused output transpose).
__global__ __launch_bounds__(256) void gemm_f16_kernel(
    const f16* __restrict__ A,     // [M][K]
    const f16* __restrict__ Bt,    // [N][K]
    const float* __restrict__ bias,
    const float* __restrict__ addC,   // fp32, row stride ldc
    float* __restrict__ CT,        // transposed fp32 out [B][DP][N], or null
    f16* __restrict__ Cb,          // f16 out, row stride ldc, or null
    int M, int N, int K, int ldc)
{
    __shared__ __align__(16) f16 As[128 * 32];
    __shared__ __align__(16) f16 Bs[128 * 32];
    const int tid = threadIdx.x;
    const int m0 = blockIdx.y * 128, n0 = blockIdx.x * 128;
    const int w = tid >> 6, l = tid & 63;
    const int wm = (w >> 1) * 64, wn = (w & 1) * 64;
    const int fm = l & 15, kq = l >> 4;

    floatx4 acc[4][4];
#pragma unroll
    for (int i = 0; i < 4; ++i)
#pragma unroll
        for (int j = 0; j < 4; ++j)
            acc[i][j] = (floatx4){0.0f, 0.0f, 0.0f, 0.0f};

    for (int k0 = 0; k0 < K; k0 += 32) {
        __syncthreads();
#pragma unroll
        for (int c = 0; c < 2; ++c) {
            const int li = tid + c * 256;
            const int row = li >> 2, part = li & 3;
            *(uint4*)&As[row * 32 + part * 8] =
                *(const uint4*)&A[(size_t)(m0 + row) * K + k0 + part * 8];
            *(uint4*)&Bs[row * 32 + part * 8] =
                *(const uint4*)&Bt[(size_t)(n0 + row) * K + k0 + part * 8];
        }
        __syncthreads();
        f16x8 af[4], bf[4];
#pragma unroll
        for (int i = 0; i < 4; ++i)
            af[i] = *(const f16x8*)&As[(wm + i * 16 + fm) * 32 + kq * 8];
#pragma unroll
        for (int j = 0; j < 4; ++j)
            bf[j] = *(const f16x8*)&Bs[(wn + j * 16 + fm) * 32 + kq * 8];
#pragma unroll
        for (int i = 0; i < 4; ++i)
#pragma unroll
            for (int j = 0; j < 4; ++j)
                acc[i][j] = __builtin_amdgcn_mfma_f32_16x16x32_f16(af[i], bf[j], acc[i][j], 0, 0, 0);
    }

#pragma unroll
    for (int i = 0; i < 4; ++i) {
#pragma unroll
        for (int j = 0; j < 4; ++j) {
            const int col = n0 + wn + j * 16 + fm;
            const int rowb = m0 + wm + i * 16 + kq * 4;
            float4 vv;
#pragma unroll
            for (int r = 0; r < 4; ++r) {
                const int m = rowb + r;
                float v = acc[i][j][r];
                if (bias) v += bias[col];
                if (addC) v += addC[(size_t)m * ldc + col];
                ((float*)&vv)[r] = v;
            }
            if (CT) {   // rows rowb..rowb+3 are consecutive n within one batch
                const int bb = rowb >> 12;
                *(float4*)&CT[(size_t)(bb * DP_ + col) * N_ + (rowb & (N_ - 1))] = vv;
            } else if (Cb) {
#pragma unroll
                for (int r = 0; r < 4; ++r)
                    Cb[(size_t)(rowb + r) * ldc + col] = (f16)((float*)&vv)[r];
            }
        }
    }
}

// ---------------- one-shot prep: weight transpose-casts + straight casts (f16) ----------------
// k/v rows of catW INTERLEAVED: k-col c -> row 256+8*(c/4)+(c%4); v-col c -> +4.
__global__ __launch_bounds__(256) void prep_kernel(
    const float* __restrict__ wq, const float* __restrict__ wk, const float* __restrict__ wv,
    const float* __restrict__ fd2, const float* __restrict__ fc1, const float* __restrict__ fc2,
    const float* __restrict__ feat,
    f16* __restrict__ catW, f16* __restrict__ fc2T, f16* __restrict__ bt2,
    f16* __restrict__ fd2c, f16* __restrict__ wqc, f16* __restrict__ fc1c,
    f16* __restrict__ featb)
{
    __shared__ float t[32][33];
    const int job = blockIdx.z;
    const int tid = threadIdx.x;

    if (job < 4) {
        const float* in; int R, C;
        switch (job) {
            case 0: in = wq;  R = DM_; C = DM_; break;
            case 1: in = wk;  R = DM_; C = DM_; break;
            case 2: in = wv;  R = DM_; C = DM_; break;
            default: in = fc2; R = DM_; C = DP_; break;
        }
        const int c0 = blockIdx.x * 32, r0 = blockIdx.y * 32;
        if (c0 >= C || r0 >= R) return;
        const int lx = tid & 31, ly = tid >> 5;
#pragma unroll
        for (int i = 0; i < 32; i += 8)
            t[ly + i][lx] = in[(size_t)(r0 + ly + i) * C + c0 + lx];
        __syncthreads();
#pragma unroll
        for (int i = 0; i < 32; i += 8) {
            const int c = c0 + ly + i;
            const f16 v = (f16)t[lx][ly + i];
            int n;
            switch (job) {
                case 0: n = c; break;
                case 1: n = 256 + ((c >> 2) << 3) + (c & 3); break;
                case 2: n = 256 + ((c >> 2) << 3) + 4 + (c & 3); break;
                default: n = -1; break;
            }
            if (job < 3) {
                catW[(size_t)n * DM_ + r0 + lx] = v;
            } else {
                fc2T[(size_t)c * DM_ + r0 + lx] = v;
                bt2[(size_t)c * 512 + 256 + r0 + lx] = v;
            }
        }
    } else {
        const int bid = blockIdx.y * 8 + blockIdx.x;
        const int tId = bid * 256 + tid;
        const float* in; f16* outp; int n4;
        if (job == 4)      { in = fd2;  outp = fd2c;  n4 = (DM_ * DM_) / 4; }
        else if (job == 5) { in = wq;   outp = wqc;   n4 = (DM_ * DM_) / 4; }
        else if (job == 6) { in = fc1;  outp = fc1c;  n4 = (DP_ * DM_) / 4; }
        else               { in = feat; outp = featb; n4 = (NPTS * DP_) / 4; }
        for (int i = tId; i < n4; i += 16384) {
            const float4 v = ((const float4*)in)[i];
            const u32 lo = asu32(pkrtz(v.x, v.y));
            const u32 hi = asu32(pkrtz(v.z, v.w));
            ((uint2*)outp)[i] = make_uint2(lo, hi);
        }
    }
}

// ---------------- folded bias vectors ----------------
__global__ __launch_bounds__(256) void bias_kernel(
    const float* __restrict__ fc1_b, const float* __restrict__ fd2_b,
    const float* __restrict__ fc2_w, const float* __restrict__ fc2_b,
    const f16* __restrict__ catW,
    float* __restrict__ b_all, float* __restrict__ bias2)
{
    const int tid = threadIdx.x;
    if (blockIdx.x < 4) {
        const int n = blockIdx.x * 256 + tid;
        float s = 0.0f;
        for (int j = 0; j < DM_; ++j)
            s += fc1_b[j] * (float)catW[(size_t)n * DM_ + j];
        b_all[n] = s;
    } else if (tid < DP_) {
        float s = fc2_b[tid];
        for (int t = 0; t < DM_; ++t)
            s += fd2_b[t] * fc2_w[(size_t)t * DP_ + tid];
        bias2[tid] = s;
    }
}

// ---------------- fused attention: one WAVE per point, f16 dot2, single 16B k+v gather ----------------
// qkv row p (stride 1024 f16): [0,256)=q, [256,768)=interleaved {k[4c..],v[4c..]} octets,
// [768,1024)=qp.  Lane l owns dims 4l..4l+3: its k AND v halves arrive in ONE uint4.
__global__ __launch_bounds__(256) void attn_kernel(
    const float* __restrict__ xyz, const f16* __restrict__ qkv,
    const int* __restrict__ knn_idx,
    const float* __restrict__ fd1_w, const float* __restrict__ fd1_b,
    const float* __restrict__ fd2_b,
    f16* __restrict__ ab)
{
    const int wave = threadIdx.x >> 6, l = threadIdx.x & 63;
    const int p = blockIdx.x * 4 + wave;
    const int c0 = l * 4;

    const uint2 qu  = *(const uint2*)(qkv + (size_t)p * 1024 + c0);
    const uint2 qpu = *(const uint2*)(qkv + (size_t)p * 1024 + 768 + c0);
    const h2 q01 = ash2(qu.x), q23 = ash2(qu.y);
    const h2 qp01 = ash2(qpu.x), qp23 = ash2(qpu.y);

    const float4 w0 = *(const float4*)&fd1_w[c0];
    const float4 w1 = *(const float4*)&fd1_w[DM_ + c0];
    const float4 w2 = *(const float4*)&fd1_w[2 * DM_ + c0];
    const float4 b1 = *(const float4*)&fd1_b[c0];
    const float4 f2b = *(const float4*)&fd2_b[c0];
    const h2 f2b01 = pkrtz(f2b.x, f2b.y);
    const h2 f2b23 = pkrtz(f2b.z, f2b.w);

    int gi = 0; float dx = 0.0f, dy = 0.0f, dz = 0.0f;
    if (l < 16) {
        gi = knn_idx[p * K_ + l];
        dx = xyz[(size_t)p * 3 + 0] - xyz[(size_t)gi * 3 + 0];
        dy = xyz[(size_t)p * 3 + 1] - xyz[(size_t)gi * 3 + 1];
        dz = xyz[(size_t)p * 3 + 2] - xyz[(size_t)gi * 3 + 2];
    }

    // qb = q . fd2_b (constant over k)
    float qb;
    {
        float tq = __builtin_amdgcn_fdot2(q01, f2b01, 0.0f, false);
        tq = __builtin_amdgcn_fdot2(q23, f2b23, tq, false);
#pragma unroll
        for (int off = 1; off < 64; off <<= 1) tq += __shfl_xor(tq, off);
        qb = tq;
    }

    // phase 1: logits via f16 dot2; v half of the 16B load + packed h kept in regs
    float lg[16];
    u32 v01r[16], v23r[16], h01r[16], h23r[16];
#pragma unroll
    for (int k = 0; k < 16; ++k) {
        const int gik = __shfl(gi, k);
        const float d0 = __shfl(dx, k), d1 = __shfl(dy, k), d2 = __shfl(dz, k);
        const uint4 kv = *(const uint4*)(qkv + (size_t)gik * 1024 + 256 + l * 8);
        v01r[k] = kv.z; v23r[k] = kv.w;
        const float h0 = fmaxf(d0 * w0.x + d1 * w1.x + d2 * w2.x + b1.x, 0.0f);
        const float h1 = fmaxf(d0 * w0.y + d1 * w1.y + d2 * w2.y + b1.y, 0.0f);
        const float h2v = fmaxf(d0 * w0.z + d1 * w1.z + d2 * w2.z + b1.z, 0.0f);
        const float h3 = fmaxf(d0 * w0.w + d1 * w1.w + d2 * w2.w + b1.w, 0.0f);
        const h2 hp01 = pkrtz(h0, h1);
        const h2 hp23 = pkrtz(h2v, h3);
        h01r[k] = asu32(hp01); h23r[k] = asu32(hp23);
        float t = __builtin_amdgcn_fdot2(ash2(kv.x), q01, 0.0f, false);
        t = __builtin_amdgcn_fdot2(ash2(kv.y), q23, t, false);
        t = __builtin_amdgcn_fdot2(hp01, qp01, t, false);
        t = __builtin_amdgcn_fdot2(hp23, qp23, t, false);
#pragma unroll
        for (int off = 1; off < 64; off <<= 1) t += __shfl_xor(t, off);
        lg[k] = t;
    }

    // softmax over 16 (redundant per lane, all registers)
    float att[16];
    {
        float mx = -3.0e38f;
#pragma unroll
        for (int k = 0; k < 16; ++k) {
            att[k] = (lg[k] + qb) * (1.0f / 16.0f);
            mx = fmaxf(mx, att[k]);
        }
        float s = 0.0f;
#pragma unroll
        for (int k = 0; k < 16; ++k) { att[k] = __expf(att[k] - mx); s += att[k]; }
        const float inv = 1.0f / s;
#pragma unroll
        for (int k = 0; k < 16; ++k) att[k] *= inv;
    }

    // phase 2: pure VALU — rbar = sum att*v (regs), hbar = sum att*h (regs)
    float rb[4] = {0, 0, 0, 0}, hb[4] = {0, 0, 0, 0};
#pragma unroll
    for (int k = 0; k < 16; ++k) {
        const h2 v01 = ash2(v01r[k]), v23 = ash2(v23r[k]);
        const h2 hh01 = ash2(h01r[k]), hh23 = ash2(h23r[k]);
        const float a = att[k];
        rb[0] = fmaf(a, (float)v01.x, rb[0]);
        rb[1] = fmaf(a, (float)v01.y, rb[1]);
        rb[2] = fmaf(a, (float)v23.x, rb[2]);
        rb[3] = fmaf(a, (float)v23.y, rb[3]);
        hb[0] = fmaf(a, (float)hh01.x, hb[0]);
        hb[1] = fmaf(a, (float)hh01.y, hb[1]);
        hb[2] = fmaf(a, (float)hh23.x, hb[2]);
        hb[3] = fmaf(a, (float)hh23.y, hb[3]);
    }

    const uint2 ho = make_uint2(asu32(pkrtz(hb[0], hb[1])), asu32(pkrtz(hb[2], hb[3])));
    const uint2 ro = make_uint2(asu32(pkrtz(rb[0], rb[1])), asu32(pkrtz(rb[2], rb[3])));
    *(uint2*)(ab + (size_t)p * 512 + c0) = ho;
    *(uint2*)(ab + (size_t)p * 512 + 256 + c0) = ro;
}

extern "C" void kernel_launch(void* const* d_in, const int* in_sizes, int n_in,
                              void* d_out, int out_size, void* d_ws, size_t ws_size,
                              hipStream_t stream)
{
    const float* features = (const float*)d_in[0];
    const float* xyz   = (const float*)d_in[1];
    const float* fc1_w = (const float*)d_in[2];
    const float* fc1_b = (const float*)d_in[3];
    const float* fc2_w = (const float*)d_in[4];
    const float* fc2_b = (const float*)d_in[5];
    const float* fd1_w = (const float*)d_in[6];
    const float* fd1_b = (const float*)d_in[7];
    const float* fd2_w = (const float*)d_in[8];
    const float* fd2_b = (const float*)d_in[9];
    const float* wq    = (const float*)d_in[10];
    const float* wk    = (const float*)d_in[11];
    const float* wv    = (const float*)d_in[12];
    float* out = (float*)d_out;

    char* base = (char*)d_ws;
    const size_t MB = 1024 * 1024;
    u32*  part = (u32*)(base + 0);                 // 16 MB (16 segs), dead after mergeA
    f16*  ab   = (f16*)(base + 0);                 // 16 MB [hbar|rbar]
    u32*  m4   = (u32*)(base + 16 * MB);           // 4 MB (4 lists), dead after mergeB
    f16*  qkv  = (f16*)(base + 36 * MB);           // 32 MB
    f16*  featb = (f16*)(base + 68 * MB);          // 4 MB
    int*  idx  = (int*)(base + 72 * MB);           // 1 MB
    char* wb = base + 73 * MB;
    f16* catW  = (f16*)(wb + 0);                   // [1024][256] = 512 KB
    f16* WallT = (f16*)(wb + 512 * 1024);          // [1024][128] = 256 KB
    f16* bt2   = (f16*)(wb + 768 * 1024);          // [128][512]  = 128 KB
    f16* fd2c  = (f16*)(wb + 896 * 1024);
    f16* wqc   = (f16*)(wb + 1024 * 1024);
    f16* fc1c  = (f16*)(wb + 1152 * 1024);
    f16* fc2T  = (f16*)(wb + 1216 * 1024);
    float* b_all = (float*)(wb + 1280 * 1024);
    float* bias2 = (float*)(wb + 1284 * 1024);

    const dim3 blk(256);

    // casts (also seeds bt2 cols [256,512) with fc2^T); k/v rows interleaved in catW
    prep_kernel<<<dim3(8, 8, 8), blk, 0, stream>>>(wq, wk, wv, fd2_w, fc1_w, fc2_w, features,
                                                   catW, fc2T, bt2, fd2c, wqc, fc1c, featb);
    // catW rows 768..1023: Wqp^T[a][b] = sum_j fd2[a][j]*wq[b][j]
    gemm_f16_kernel<<<dim3(2, 2), blk, 0, stream>>>(
        fd2c, wqc, nullptr, nullptr, nullptr, catW + 768 * 256, DM_, DM_, DM_, DM_);
    // folded biases
    bias_kernel<<<dim3(5), blk, 0, stream>>>(fc1_b, fd2_b, fc2_w, fc2_b, catW, b_all, bias2);
    // WallT[n][k] = sum_j catW[n][j]*fc1_w[k][j]
    gemm_f16_kernel<<<dim3(1, 8), blk, 0, stream>>>(
        catW, fc1c, nullptr, nullptr, nullptr, WallT, 1024, DP_, DM_, DP_);
    // bt2 cols [0,256): Wof^T[n][j] = sum_t fc2[t][n]*fd2[j][t]
    gemm_f16_kernel<<<dim3(2, 1), blk, 0, stream>>>(
        fc2T, fd2c, nullptr, nullptr, nullptr, bt2, DP_, DM_, DM_, 512);

    // KNN: 16 segments, two-stage merge (A: 1024 waves, B: 256 waves)
    knn_part_kernel<<<dim3(N_ / 256, SEG_, B_), blk, 0, stream>>>(xyz, part);
    knn_mergeA_kernel<<<dim3(NPTS / 256, 4), blk, 0, stream>>>(part, m4);
    knn_mergeB_kernel<<<dim3(NPTS / 256), blk, 0, stream>>>(m4, idx);

    // [q | kv-interleaved | qp] = features @ WallT^T + b_all
    gemm_f16_kernel<<<dim3(1024 / 128, NPTS / 128), blk, 0, stream>>>(
        featb, WallT, b_all, nullptr, nullptr, qkv, NPTS, 1024, DP_, 1024);

    // fused attention -> ab = [hbar | rbar]
    attn_kernel<<<dim3(NPTS / 4), blk, 0, stream>>>(xyz, qkv, idx, fd1_w, fd1_b, fd2_b, ab);

    // out = ab @ bt2^T + bias2 + features, stored TRANSPOSED directly to d_out
    gemm_f16_kernel<<<dim3(1, NPTS / 128), blk, 0, stream>>>(
        ab, bt2, bias2, features, out, nullptr, NPTS, DP_, 512, DP_);

    (void)in_sizes; (void)n_in; (void)out_size; (void)ws_size;
}